// Round 1
// baseline (2255.304 us; speedup 1.0000x reference)
//
#include <hip/hip_runtime.h>
#include <hip/hip_bf16.h>
#include <math.h>

#define T_TOK 2048
#define DMODEL 1024
#define NH 16
#define HD 64
#define S_LEN 1024
#define NE 8
#define CAP 256
#define DFF 4096

// ---------------- RoPE table ----------------
__global__ void rope_table_kernel(float* __restrict__ rc, float* __restrict__ rs) {
    int s = blockIdx.x;      // 0..1023
    int i = threadIdx.x;     // 0..31
    float invf = powf(10000.0f, -(float)(2 * i) / 64.0f);
    float ang = (float)s * invf;
    rc[s * 32 + i] = cosf(ang);
    rs[s * 32 + i] = sinf(ang);
}

// ---------------- RMSNorm ----------------
__global__ __launch_bounds__(256) void rmsnorm_kernel(const float* __restrict__ x,
                                                      const float* __restrict__ g,
                                                      float* __restrict__ y) {
    __shared__ float red[256];
    int t = blockIdx.x;
    int tid = threadIdx.x;
    const float* xr = x + (size_t)t * DMODEL;
    float ss = 0.f;
    for (int d = tid; d < DMODEL; d += 256) { float v = xr[d]; ss += v * v; }
    red[tid] = ss; __syncthreads();
    for (int o = 128; o > 0; o >>= 1) { if (tid < o) red[tid] += red[tid + o]; __syncthreads(); }
    float mean = red[0] / (float)DMODEL;
    float scale = 1.0f / sqrtf(mean + 1e-6f);
    float* yr = y + (size_t)t * DMODEL;
    for (int d = tid; d < DMODEL; d += 256) yr[d] = g[d] * xr[d] * scale;
}

// ---------------- generic tiled f32 GEMM: C = A@B (+R), batched by z ----------------
template <int RES>
__global__ __launch_bounds__(256) void gemm_f32(const float* __restrict__ A,
                                                const float* __restrict__ B,
                                                const float* __restrict__ Rr,
                                                float* __restrict__ C,
                                                int M, int N, int K,
                                                long long sA, long long sB, long long sC) {
    __shared__ float As[16][64];
    __shared__ float Bs[16][64];
    A += (long long)blockIdx.z * sA;
    B += (long long)blockIdx.z * sB;
    C += (long long)blockIdx.z * sC;
    int bx = blockIdx.x * 64, by = blockIdx.y * 64;
    int tid = threadIdx.x, tx = tid & 15, ty = tid >> 4;
    float acc[4][4] = {};
    for (int k0 = 0; k0 < K; k0 += 16) {
        #pragma unroll
        for (int i = 0; i < 4; i++) {
            int idx = tid + i * 256;
            int m = idx >> 4, kk = idx & 15;
            As[kk][m] = A[(size_t)(by + m) * K + k0 + kk];
            int kb = idx >> 6, n = idx & 63;
            Bs[kb][n] = B[(size_t)(k0 + kb) * N + bx + n];
        }
        __syncthreads();
        #pragma unroll
        for (int kk = 0; kk < 16; kk++) {
            float a[4], bb[4];
            #pragma unroll
            for (int i = 0; i < 4; i++) a[i] = As[kk][ty * 4 + i];
            #pragma unroll
            for (int j = 0; j < 4; j++) bb[j] = Bs[kk][tx * 4 + j];
            #pragma unroll
            for (int i = 0; i < 4; i++)
                #pragma unroll
                for (int j = 0; j < 4; j++) acc[i][j] += a[i] * bb[j];
        }
        __syncthreads();
    }
    #pragma unroll
    for (int i = 0; i < 4; i++)
        #pragma unroll
        for (int j = 0; j < 4; j++) {
            size_t idx = (size_t)(by + ty * 4 + i) * N + bx + tx * 4 + j;
            float r = RES ? Rr[idx] : 0.f;
            C[idx] = acc[i][j] + r;
        }
}

// ---------------- RoPE apply (in-place on q or k, layout (T, H*HD)) ----------------
__global__ __launch_bounds__(512) void rope_apply_kernel(float* __restrict__ q,
                                                         const float* __restrict__ rc,
                                                         const float* __restrict__ rs) {
    int t = blockIdx.x;
    int s = t & (S_LEN - 1);
    int tid = threadIdx.x;             // 512 = 16 heads * 32
    int hh = tid >> 5, i = tid & 31;
    size_t base = (size_t)t * DMODEL + hh * 64;
    float a = q[base + i], b = q[base + i + 32];
    float c = rc[s * 32 + i], sn = rs[s * 32 + i];
    q[base + i] = a * c - b * sn;
    q[base + i + 32] = b * c + a * sn;
}

// ---------------- fused attention: 8 q-rows per block ----------------
__global__ __launch_bounds__(256) void attn_kernel(const float* __restrict__ q,
                                                   const float* __restrict__ k,
                                                   const float* __restrict__ v,
                                                   const int* __restrict__ gtm,
                                                   float* __restrict__ o) {
    __shared__ float qs[8][64];
    __shared__ float sc[8][1024];
    __shared__ float red[256];
    __shared__ float pacc[4][8][64];
    __shared__ int gqr[8];
    int blk = blockIdx.x;              // b*16*128 + h*128 + qt
    int qt = blk & 127;
    int h = (blk >> 7) & 15;
    int b = blk >> 11;
    int q0 = qt * 8;
    int tid = threadIdx.x;

    for (int idx = tid; idx < 512; idx += 256) {
        int r = idx >> 6, d = idx & 63;
        qs[r][d] = q[((size_t)(b * S_LEN + q0 + r)) * DMODEL + h * 64 + d];
    }
    if (tid < 8) gqr[tid] = gtm[b * S_LEN + q0 + tid];
    __syncthreads();

    // phase 1: scores
    for (int jj = 0; jj < 4; jj++) {
        int j = jj * 256 + tid;
        const float* kr = k + ((size_t)(b * S_LEN + j)) * DMODEL + h * 64;
        float acc[8] = {0, 0, 0, 0, 0, 0, 0, 0};
        for (int d = 0; d < 64; d++) {
            float kv = kr[d];
            #pragma unroll
            for (int r = 0; r < 8; r++) acc[r] += qs[r][d] * kv;
        }
        int gk = gtm[b * S_LEN + j];
        #pragma unroll
        for (int r = 0; r < 8; r++) {
            int i = q0 + r;
            bool allowed = (gqr[r] != 0) || (gk != 0) || ((j <= i) && (i - j < 256));
            sc[r][j] = allowed ? acc[r] * 0.125f : -INFINITY;
        }
    }
    __syncthreads();

    // phase 2: softmax per row
    for (int r = 0; r < 8; r++) {
        float m = -INFINITY;
        for (int jj = 0; jj < 4; jj++) m = fmaxf(m, sc[r][jj * 256 + tid]);
        red[tid] = m; __syncthreads();
        for (int o2 = 128; o2 > 0; o2 >>= 1) { if (tid < o2) red[tid] = fmaxf(red[tid], red[tid + o2]); __syncthreads(); }
        float rowm = red[0]; __syncthreads();
        float s = 0.f;
        for (int jj = 0; jj < 4; jj++) {
            int j = jj * 256 + tid;
            float e2 = __expf(sc[r][j] - rowm);
            sc[r][j] = e2; s += e2;
        }
        red[tid] = s; __syncthreads();
        for (int o2 = 128; o2 > 0; o2 >>= 1) { if (tid < o2) red[tid] += red[tid + o2]; __syncthreads(); }
        float inv = 1.0f / red[0]; __syncthreads();
        for (int jj = 0; jj < 4; jj++) sc[r][jj * 256 + tid] *= inv;
        __syncthreads();
    }

    // phase 3: PV
    int dd = tid & 63, jg = tid >> 6;
    float acc[8] = {0, 0, 0, 0, 0, 0, 0, 0};
    for (int j = jg; j < 1024; j += 4) {
        float vv = v[((size_t)(b * S_LEN + j)) * DMODEL + h * 64 + dd];
        #pragma unroll
        for (int r = 0; r < 8; r++) acc[r] += sc[r][j] * vv;
    }
    #pragma unroll
    for (int r = 0; r < 8; r++) pacc[jg][r][dd] = acc[r];
    __syncthreads();
    for (int idx = tid; idx < 512; idx += 256) {
        int r = idx >> 6, d2 = idx & 63;
        float s = pacc[0][r][d2] + pacc[1][r][d2] + pacc[2][r][d2] + pacc[3][r][d2];
        o[((size_t)(b * S_LEN + q0 + r)) * DMODEL + h * 64 + d2] = s;
    }
}

// ---------------- gate: softmax over E=8, top-2, per-expert sums ----------------
__global__ __launch_bounds__(64) void gate_kernel(const float* __restrict__ hn,
                                                  const float* __restrict__ Wgate,
                                                  float* __restrict__ wfull,
                                                  float* __restrict__ gate_sum) {
    int t = blockIdx.x;
    int lane = threadIdx.x; // 64
    const float* xr = hn + (size_t)t * DMODEL;
    float logits[8];
    #pragma unroll
    for (int e = 0; e < 8; e++) {
        float p = 0.f;
        for (int d = lane; d < DMODEL; d += 64) p += xr[d] * Wgate[d * 8 + e];
        for (int o = 32; o > 0; o >>= 1) p += __shfl_down(p, o);
        logits[e] = p;
    }
    if (lane == 0) {
        float mx = logits[0];
        #pragma unroll
        for (int e = 1; e < 8; e++) mx = fmaxf(mx, logits[e]);
        float pr[8]; float s = 0.f;
        #pragma unroll
        for (int e = 0; e < 8; e++) { pr[e] = __expf(logits[e] - mx); s += pr[e]; }
        float inv = 1.0f / s;
        int e1 = 0; float v1 = -1.f;
        #pragma unroll
        for (int e = 0; e < 8; e++) {
            pr[e] *= inv;
            atomicAdd(&gate_sum[e], pr[e]);
            if (pr[e] > v1) { v1 = pr[e]; e1 = e; }
        }
        int e2 = -1; float v2 = -1.f;
        #pragma unroll
        for (int e = 0; e < 8; e++) {
            if (e == e1) continue;
            if (pr[e] > v2) { v2 = pr[e]; e2 = e; }
        }
        wfull[t * 8 + e1] = v1;
        wfull[t * 8 + e2] = v2;
    }
}

// ---------------- per-expert top-CAP via bitonic sort (desc by w, asc by idx) ----------------
__global__ __launch_bounds__(1024) void expert_select_kernel(const float* __restrict__ wfull,
                                                             float* __restrict__ sw,
                                                             int* __restrict__ sidx,
                                                             int* __restrict__ slot) {
    __shared__ unsigned long long keys[2048];
    int e = blockIdx.x;
    int t = threadIdx.x;
    for (int i = t; i < 2048; i += 1024) {
        float w = wfull[i * 8 + e];
        unsigned int wb = __float_as_uint(w); // w >= 0 so uint order == float order
        keys[i] = ((unsigned long long)wb << 32) | (unsigned long long)(0xFFFFFFFFu - (unsigned int)i);
    }
    __syncthreads();
    for (int k = 2; k <= 2048; k <<= 1) {
        for (int j = k >> 1; j > 0; j >>= 1) {
            for (int i = t; i < 2048; i += 1024) {
                int ixj = i ^ j;
                if (ixj > i) {
                    bool desc = ((i & k) == 0);
                    unsigned long long a = keys[i], b = keys[ixj];
                    if ((a < b) == desc) { keys[i] = b; keys[ixj] = a; }
                }
            }
            __syncthreads();
        }
    }
    if (t < CAP) {
        unsigned long long kk = keys[t];
        float w = __uint_as_float((unsigned int)(kk >> 32));
        int idx = (int)(0xFFFFFFFFu - (unsigned int)(kk & 0xFFFFFFFFu));
        sw[e * CAP + t] = w;
        sidx[e * CAP + t] = idx;
        if (w > 0.f) slot[idx * 8 + e] = t;
    }
}

// ---------------- gather tokens per (expert, slot) ----------------
__global__ __launch_bounds__(256) void gather_tok_kernel(const float* __restrict__ hn,
                                                         const int* __restrict__ sidx,
                                                         const float* __restrict__ sw,
                                                         float* __restrict__ tok) {
    int ec = blockIdx.x; // e*CAP + c
    int tid = threadIdx.x;
    float w = sw[ec];
    int src = sidx[ec];
    const float* s = hn + (size_t)src * DMODEL;
    float* d = tok + (size_t)ec * DMODEL;
    for (int i = tid; i < DMODEL; i += 256) d[i] = (w > 0.f) ? s[i] : 0.f;
}

// ---------------- MoE W1 with fused SwiGLU: act = h1 * silu(h2) ----------------
__global__ __launch_bounds__(256) void gemm_w1_silu(const float* __restrict__ tok,
                                                    const float* __restrict__ W1,
                                                    float* __restrict__ act) {
    __shared__ float As[16][64];
    __shared__ float B1s[16][64];
    __shared__ float B2s[16][64];
    int e = blockIdx.z;
    const float* A = tok + (size_t)e * CAP * DMODEL;
    const float* B = W1 + (size_t)e * DMODEL * (2 * DFF);
    float* Cc = act + (size_t)e * CAP * DFF;
    int bx = blockIdx.x * 64, by = blockIdx.y * 64;
    int tid = threadIdx.x, tx = tid & 15, ty = tid >> 4;
    float a1[4][4] = {}, a2[4][4] = {};
    for (int k0 = 0; k0 < DMODEL; k0 += 16) {
        #pragma unroll
        for (int i = 0; i < 4; i++) {
            int idx = tid + i * 256;
            int m = idx >> 4, kk = idx & 15;
            As[kk][m] = A[(size_t)(by + m) * DMODEL + k0 + kk];
            int kb = idx >> 6, n = idx & 63;
            B1s[kb][n] = B[(size_t)(k0 + kb) * (2 * DFF) + bx + n];
            B2s[kb][n] = B[(size_t)(k0 + kb) * (2 * DFF) + DFF + bx + n];
        }
        __syncthreads();
        #pragma unroll
        for (int kk = 0; kk < 16; kk++) {
            float a[4], b1[4], b2[4];
            #pragma unroll
            for (int i = 0; i < 4; i++) a[i] = As[kk][ty * 4 + i];
            #pragma unroll
            for (int j = 0; j < 4; j++) { b1[j] = B1s[kk][tx * 4 + j]; b2[j] = B2s[kk][tx * 4 + j]; }
            #pragma unroll
            for (int i = 0; i < 4; i++)
                #pragma unroll
                for (int j = 0; j < 4; j++) { a1[i][j] += a[i] * b1[j]; a2[i][j] += a[i] * b2[j]; }
        }
        __syncthreads();
    }
    #pragma unroll
    for (int i = 0; i < 4; i++)
        #pragma unroll
        for (int j = 0; j < 4; j++) {
            float h1 = a1[i][j], h2 = a2[i][j];
            float sil = h2 / (1.0f + __expf(-h2));
            Cc[(size_t)(by + ty * 4 + i) * DFF + bx + tx * 4 + j] = h1 * sil;
        }
}

// ---------------- final combine: out = h + sum_e w*out_e ; aux loss ----------------
__global__ __launch_bounds__(256) void combine_kernel(const float* __restrict__ h,
                                                      const float* __restrict__ out_e,
                                                      const int* __restrict__ slot,
                                                      const float* __restrict__ wfull,
                                                      const float* __restrict__ gate_sum,
                                                      float* __restrict__ out) {
    int t = blockIdx.x;
    int tid = threadIdx.x;
    for (int d = tid; d < DMODEL; d += 256) {
        float acc = h[(size_t)t * DMODEL + d];
        #pragma unroll
        for (int e = 0; e < 8; e++) {
            int c = slot[t * 8 + e];
            if (c >= 0) acc += wfull[t * 8 + e] * out_e[((size_t)(e * CAP + c)) * DMODEL + d];
        }
        out[(size_t)t * DMODEL + d] = acc;
    }
    if (t == 0 && tid == 0) {
        float a = 0.f;
        #pragma unroll
        for (int e = 0; e < 8; e++) { float m = gate_sum[e] / (float)T_TOK; a += m * m; }
        out[(size_t)T_TOK * DMODEL] = 8.0f * a;
    }
}

extern "C" void kernel_launch(void* const* d_in, const int* in_sizes, int n_in,
                              void* d_out, int out_size, void* d_ws, size_t ws_size,
                              hipStream_t stream) {
    const float* x     = (const float*)d_in[0];
    // d_in[1] = mask (recomputed analytically, unused)
    const int*   gtm   = (const int*)d_in[2];
    const float* Wq    = (const float*)d_in[3];
    const float* Wk    = (const float*)d_in[4];
    const float* Wv    = (const float*)d_in[5];
    const float* Wo    = (const float*)d_in[6];
    const float* g1    = (const float*)d_in[7];
    const float* g2    = (const float*)d_in[8];
    const float* Wgate = (const float*)d_in[9];
    const float* W1    = (const float*)d_in[10];
    const float* W2    = (const float*)d_in[11];
    float* out = (float*)d_out;

    // workspace layout
    float* ws = (float*)d_ws;
    size_t off = 0;
    float* xn    = ws + off; off += (size_t)T_TOK * DMODEL;
    float* qb    = ws + off; off += (size_t)T_TOK * DMODEL;
    float* kb    = ws + off; off += (size_t)T_TOK * DMODEL;
    float* vb    = ws + off; off += (size_t)T_TOK * DMODEL;
    float* attno = ws + off; off += (size_t)T_TOK * DMODEL;
    float* hb    = ws + off; off += (size_t)T_TOK * DMODEL;
    float* hnb   = ws + off; off += (size_t)T_TOK * DMODEL;
    float* tok   = ws + off; off += (size_t)NE * CAP * DMODEL;
    float* oute  = ws + off; off += (size_t)NE * CAP * DMODEL;
    float* act   = ws + off; off += (size_t)NE * CAP * DFF;
    float* ropec = ws + off; off += (size_t)S_LEN * 32;
    float* ropes = ws + off; off += (size_t)S_LEN * 32;
    float* wfull = ws + off; off += (size_t)T_TOK * NE;
    float* gsum  = ws + off; off += 8;
    float* sw    = ws + off; off += (size_t)NE * CAP;
    int*   slot  = (int*)(ws + off); off += (size_t)T_TOK * NE;
    int*   sidx  = (int*)(ws + off); off += (size_t)NE * CAP;

    rope_table_kernel<<<S_LEN, 32, 0, stream>>>(ropec, ropes);
    rmsnorm_kernel<<<T_TOK, 256, 0, stream>>>(x, g1, xn);

    // QKV projections
    gemm_f32<0><<<dim3(16, 32, 1), 256, 0, stream>>>(xn, Wq, nullptr, qb, T_TOK, DMODEL, DMODEL, 0, 0, 0);
    gemm_f32<0><<<dim3(16, 32, 1), 256, 0, stream>>>(xn, Wk, nullptr, kb, T_TOK, DMODEL, DMODEL, 0, 0, 0);
    gemm_f32<0><<<dim3(16, 32, 1), 256, 0, stream>>>(xn, Wv, nullptr, vb, T_TOK, DMODEL, DMODEL, 0, 0, 0);

    rope_apply_kernel<<<T_TOK, 512, 0, stream>>>(qb, ropec, ropes);
    rope_apply_kernel<<<T_TOK, 512, 0, stream>>>(kb, ropec, ropes);

    attn_kernel<<<2 * 16 * 128, 256, 0, stream>>>(qb, kb, vb, gtm, attno);

    // h = x + attno @ Wo
    gemm_f32<1><<<dim3(16, 32, 1), 256, 0, stream>>>(attno, Wo, x, hb, T_TOK, DMODEL, DMODEL, 0, 0, 0);
    rmsnorm_kernel<<<T_TOK, 256, 0, stream>>>(hb, g2, hnb);

    hipMemsetAsync(wfull, 0, (size_t)T_TOK * NE * 4, stream);
    hipMemsetAsync(slot, 0xFF, (size_t)T_TOK * NE * 4, stream);
    hipMemsetAsync(gsum, 0, 8 * 4, stream);

    gate_kernel<<<T_TOK, 64, 0, stream>>>(hnb, Wgate, wfull, gsum);
    expert_select_kernel<<<NE, 1024, 0, stream>>>(wfull, sw, sidx, slot);
    gather_tok_kernel<<<NE * CAP, 256, 0, stream>>>(hnb, sidx, sw, tok);

    gemm_w1_silu<<<dim3(DFF / 64, CAP / 64, NE), 256, 0, stream>>>(tok, W1, act);
    gemm_f32<0><<<dim3(DMODEL / 64, CAP / 64, NE), 256, 0, stream>>>(
        act, W2, nullptr, oute, CAP, DMODEL, DFF,
        (long long)CAP * DFF, (long long)DFF * DMODEL, (long long)CAP * DMODEL);

    combine_kernel<<<T_TOK, 256, 0, stream>>>(hb, oute, slot, wfull, gsum, out);
}

// Round 2
// 1565.997 us; speedup vs baseline: 1.4402x; 1.4402x over previous
//
#include <hip/hip_runtime.h>
#include <hip/hip_bf16.h>
#include <math.h>

#define T_TOK 2048
#define DMODEL 1024
#define NH 16
#define HD 64
#define S_LEN 1024
#define NE 8
#define CAP 256
#define DFF 4096

typedef __attribute__((ext_vector_type(8))) short bf16x8;
typedef __attribute__((ext_vector_type(4))) float f32x4;

__device__ inline unsigned short f2bf(float f) {
    union { float f; unsigned int u; } x; x.f = f;
    unsigned int u = x.u;
    unsigned int r = (u + 0x7FFFu + ((u >> 16) & 1u)) >> 16;
    return (unsigned short)r;
}

__device__ inline void gload16(const void* g, void* l) {
    __builtin_amdgcn_global_load_lds(
        (const __attribute__((address_space(1))) unsigned int*)g,
        (__attribute__((address_space(3))) unsigned int*)l, 16, 0, 0);
}

// ---------------- RoPE table ----------------
__global__ void rope_table_kernel(float* __restrict__ rc, float* __restrict__ rs) {
    int s = blockIdx.x;
    int i = threadIdx.x;
    float invf = powf(10000.0f, -(float)(2 * i) / 64.0f);
    float ang = (float)s * invf;
    rc[s * 32 + i] = cosf(ang);
    rs[s * 32 + i] = sinf(ang);
}

// ---------------- RMSNorm (OUTBF: 1 -> bf16 out, 0 -> f32 out) ----------------
template <int OUTBF>
__global__ __launch_bounds__(256) void rmsnorm_kernel(const float* __restrict__ x,
                                                      const float* __restrict__ g,
                                                      void* __restrict__ yv) {
    __shared__ float red[256];
    int t = blockIdx.x;
    int tid = threadIdx.x;
    const float* xr = x + (size_t)t * DMODEL;
    float ss = 0.f;
    for (int d = tid; d < DMODEL; d += 256) { float v = xr[d]; ss += v * v; }
    red[tid] = ss; __syncthreads();
    for (int o = 128; o > 0; o >>= 1) { if (tid < o) red[tid] += red[tid + o]; __syncthreads(); }
    float scale = 1.0f / sqrtf(red[0] / (float)DMODEL + 1e-6f);
    if (OUTBF) {
        unsigned short* yr = (unsigned short*)yv + (size_t)t * DMODEL;
        for (int d = tid; d < DMODEL; d += 256) yr[d] = f2bf(g[d] * xr[d] * scale);
    } else {
        float* yr = (float*)yv + (size_t)t * DMODEL;
        for (int d = tid; d < DMODEL; d += 256) yr[d] = g[d] * xr[d] * scale;
    }
}

// ---------------- transpose+convert: dst_bf16(C,R) = src_f32(R,C)^T ----------------
__global__ __launch_bounds__(256) void transpose_bf16(const float* __restrict__ src,
                                                      unsigned short* __restrict__ dst,
                                                      int ldS, int ldD,
                                                      long long sS, long long sD) {
    __shared__ float tile[32][33];
    src += (long long)blockIdx.z * sS;
    dst += (long long)blockIdx.z * sD;
    int c0 = blockIdx.x * 32, r0 = blockIdx.y * 32;
    int tx = threadIdx.x & 31, ty = threadIdx.x >> 5;
    #pragma unroll
    for (int j = 0; j < 4; j++)
        tile[ty + j * 8][tx] = src[(size_t)(r0 + ty + j * 8) * ldS + c0 + tx];
    __syncthreads();
    #pragma unroll
    for (int j = 0; j < 4; j++)
        dst[(size_t)(c0 + ty + j * 8) * ldD + r0 + tx] = f2bf(tile[tx][ty + j * 8]);
}

// ---------------- bf16 MFMA GEMM: C(f32) = A(M,K)bf16 @ BT(N,K)bf16^T ----------------
// RES: 0 none, 1 add Rr(f32), 2 accumulate into existing C
template <int BN, int RES>
__global__ __launch_bounds__(256) void gemm_mfma(const unsigned short* __restrict__ A,
                                                 const unsigned short* __restrict__ BT,
                                                 const float* __restrict__ Rr,
                                                 float* __restrict__ C,
                                                 int K, int lda, int ldc,
                                                 long long sA, long long sB, long long sC) {
    constexpr int BM = 128, BK = 64;
    constexpr int NF = BN / 32;
    __shared__ unsigned short As[BM * BK];
    __shared__ unsigned short Bs[BN * BK];
    A += (long long)blockIdx.z * sA;
    BT += (long long)blockIdx.z * sB;
    C += (long long)blockIdx.z * sC;
    const int tid = threadIdx.x;
    const int lane = tid & 63;
    const int wid = tid >> 6;
    const int wr = wid >> 1, wc = wid & 1;
    const int bx = blockIdx.x * BN, by = blockIdx.y * BM;

    f32x4 acc[4][NF] = {};

    for (int k0 = 0; k0 < K; k0 += BK) {
        #pragma unroll
        for (int i = 0; i < (BM * 8) / 256; i++) {
            int c = i * 256 + tid;
            int row = c >> 3, slot = c & 7;
            int gs = slot ^ (row & 7);
            gload16(A + (size_t)(by + row) * lda + k0 + gs * 8, &As[c * 8]);
        }
        #pragma unroll
        for (int i = 0; i < (BN * 8) / 256; i++) {
            int c = i * 256 + tid;
            int row = c >> 3, slot = c & 7;
            int gs = slot ^ (row & 7);
            gload16(BT + (size_t)(bx + row) * K + k0 + gs * 8, &Bs[c * 8]);
        }
        __syncthreads();
        #pragma unroll
        for (int ks = 0; ks < 2; ks++) {
            bf16x8 af[4], bfr[NF];
            #pragma unroll
            for (int m = 0; m < 4; m++) {
                int row = wr * 64 + m * 16 + (lane & 15);
                int slot = (ks * 4 + (lane >> 4)) ^ (row & 7);
                af[m] = *(const bf16x8*)&As[row * 64 + slot * 8];
            }
            #pragma unroll
            for (int n = 0; n < NF; n++) {
                int row = wc * (BN / 2) + n * 16 + (lane & 15);
                int slot = (ks * 4 + (lane >> 4)) ^ (row & 7);
                bfr[n] = *(const bf16x8*)&Bs[row * 64 + slot * 8];
            }
            #pragma unroll
            for (int m = 0; m < 4; m++)
                #pragma unroll
                for (int n = 0; n < NF; n++)
                    acc[m][n] = __builtin_amdgcn_mfma_f32_16x16x32_bf16(af[m], bfr[n], acc[m][n], 0, 0, 0);
        }
        __syncthreads();
    }
    #pragma unroll
    for (int m = 0; m < 4; m++) {
        int row0 = by + wr * 64 + m * 16 + (lane >> 4) * 4;
        #pragma unroll
        for (int n = 0; n < NF; n++) {
            int col = bx + wc * (BN / 2) + n * 16 + (lane & 15);
            #pragma unroll
            for (int r = 0; r < 4; r++) {
                size_t idx = (size_t)(row0 + r) * ldc + col;
                float v = acc[m][n][r];
                if (RES == 1) v += Rr[idx];
                if (RES == 2) v += C[idx];
                C[idx] = v;
            }
        }
    }
}

// ---------------- W1 GEMM with fused SwiGLU, bf16 out ----------------
// BT layout per expert: [2][1024][1024] (part0=h1 rows, part1=h2 rows), N-chunk=1024
__global__ __launch_bounds__(256) void gemm_w1_swiglu(const unsigned short* __restrict__ A,
                                                      const unsigned short* __restrict__ BT,
                                                      unsigned short* __restrict__ C,
                                                      long long sA, long long sB, long long sC) {
    constexpr int BM = 128, BK = 64, BN = 64, NF = 2, K = 1024, LDC = 4096;
    __shared__ unsigned short As[BM * BK];
    __shared__ unsigned short B1s[BN * BK];
    __shared__ unsigned short B2s[BN * BK];
    A += (long long)blockIdx.z * sA;
    BT += (long long)blockIdx.z * sB;
    C += (long long)blockIdx.z * sC;
    const int tid = threadIdx.x;
    const int lane = tid & 63;
    const int wid = tid >> 6;
    const int wr = wid >> 1, wc = wid & 1;
    const int bx = blockIdx.x * BN, by = blockIdx.y * BM;

    f32x4 acc1[4][NF] = {};
    f32x4 acc2[4][NF] = {};

    for (int k0 = 0; k0 < K; k0 += BK) {
        #pragma unroll
        for (int i = 0; i < 4; i++) {
            int c = i * 256 + tid;
            int row = c >> 3, slot = c & 7;
            int gs = slot ^ (row & 7);
            gload16(A + (size_t)(by + row) * K + k0 + gs * 8, &As[c * 8]);
        }
        #pragma unroll
        for (int i = 0; i < 2; i++) {
            int c = i * 256 + tid;
            int row = c >> 3, slot = c & 7;
            int gs = slot ^ (row & 7);
            gload16(BT + (size_t)(bx + row) * K + k0 + gs * 8, &B1s[c * 8]);
            gload16(BT + 1048576 + (size_t)(bx + row) * K + k0 + gs * 8, &B2s[c * 8]);
        }
        __syncthreads();
        #pragma unroll
        for (int ks = 0; ks < 2; ks++) {
            bf16x8 af[4], b1[NF], b2[NF];
            #pragma unroll
            for (int m = 0; m < 4; m++) {
                int row = wr * 64 + m * 16 + (lane & 15);
                int slot = (ks * 4 + (lane >> 4)) ^ (row & 7);
                af[m] = *(const bf16x8*)&As[row * 64 + slot * 8];
            }
            #pragma unroll
            for (int n = 0; n < NF; n++) {
                int row = wc * 32 + n * 16 + (lane & 15);
                int slot = (ks * 4 + (lane >> 4)) ^ (row & 7);
                b1[n] = *(const bf16x8*)&B1s[row * 64 + slot * 8];
                b2[n] = *(const bf16x8*)&B2s[row * 64 + slot * 8];
            }
            #pragma unroll
            for (int m = 0; m < 4; m++)
                #pragma unroll
                for (int n = 0; n < NF; n++) {
                    acc1[m][n] = __builtin_amdgcn_mfma_f32_16x16x32_bf16(af[m], b1[n], acc1[m][n], 0, 0, 0);
                    acc2[m][n] = __builtin_amdgcn_mfma_f32_16x16x32_bf16(af[m], b2[n], acc2[m][n], 0, 0, 0);
                }
        }
        __syncthreads();
    }
    #pragma unroll
    for (int m = 0; m < 4; m++) {
        int row0 = by + wr * 64 + m * 16 + (lane >> 4) * 4;
        #pragma unroll
        for (int n = 0; n < NF; n++) {
            int col = bx + wc * 32 + n * 16 + (lane & 15);
            #pragma unroll
            for (int r = 0; r < 4; r++) {
                float h1 = acc1[m][n][r], h2 = acc2[m][n][r];
                float sil = h2 / (1.0f + __expf(-h2));
                C[(size_t)(row0 + r) * LDC + col] = f2bf(h1 * sil);
            }
        }
    }
}

// ---------------- RoPE apply to q and k inside qkv (T, 3072) ----------------
__global__ __launch_bounds__(512) void rope_apply_kernel(float* __restrict__ qkv,
                                                         const float* __restrict__ rc,
                                                         const float* __restrict__ rs) {
    int t = blockIdx.x;
    int s = t & (S_LEN - 1);
    int hh = threadIdx.x >> 5, i = threadIdx.x & 31;
    float c = rc[s * 32 + i], sn = rs[s * 32 + i];
    size_t base = (size_t)t * 3072 + hh * 64;
    float a = qkv[base + i], b = qkv[base + i + 32];
    qkv[base + i] = a * c - b * sn;
    qkv[base + i + 32] = b * c + a * sn;
    float ak = qkv[base + 1024 + i], bk = qkv[base + 1024 + i + 32];
    qkv[base + 1024 + i] = ak * c - bk * sn;
    qkv[base + 1024 + i + 32] = bk * c + ak * sn;
}

// ---------------- fused attention (f32 compute, bf16 out) ----------------
__global__ __launch_bounds__(256) void attn_kernel(const float* __restrict__ qkv,
                                                   const int* __restrict__ gtm,
                                                   unsigned short* __restrict__ o) {
    __shared__ float qs[8][64];
    __shared__ float sc[8][1024];
    __shared__ float pacc[4][8][64];
    __shared__ int gqr[8];
    int blk = blockIdx.x;
    int qt = blk & 127;
    int h = (blk >> 7) & 15;
    int b = blk >> 11;
    int q0 = qt * 8;
    int tid = threadIdx.x;

    for (int idx = tid; idx < 512; idx += 256) {
        int r = idx >> 6, d = idx & 63;
        qs[r][d] = qkv[(size_t)(b * S_LEN + q0 + r) * 3072 + h * 64 + d];
    }
    if (tid < 8) gqr[tid] = gtm[b * S_LEN + q0 + tid];
    __syncthreads();

    // phase 1: scores (float4 K loads, q broadcast from LDS)
    for (int jj = 0; jj < 4; jj++) {
        int j = jj * 256 + tid;
        const float4* kr = (const float4*)(qkv + (size_t)(b * S_LEN + j) * 3072 + 1024 + h * 64);
        float acc[8] = {};
        #pragma unroll
        for (int d4 = 0; d4 < 16; d4++) {
            float4 kv = kr[d4];
            #pragma unroll
            for (int r = 0; r < 8; r++) {
                float4 qv = *(const float4*)&qs[r][d4 * 4];
                acc[r] += qv.x * kv.x + qv.y * kv.y + qv.z * kv.z + qv.w * kv.w;
            }
        }
        int gk = gtm[b * S_LEN + j];
        #pragma unroll
        for (int r = 0; r < 8; r++) {
            int i = q0 + r;
            bool allowed = (gqr[r] != 0) || (gk != 0) || ((j <= i) && (i - j < 256));
            sc[r][j] = allowed ? acc[r] * 0.125f : -INFINITY;
        }
    }
    __syncthreads();

    // phase 2: parallel softmax — row = tid>>5, 32 lanes per row, no barriers
    {
        int r = tid >> 5, ln = tid & 31;
        float m = -INFINITY;
        for (int j = ln; j < 1024; j += 32) m = fmaxf(m, sc[r][j]);
        #pragma unroll
        for (int o2 = 16; o2 > 0; o2 >>= 1) m = fmaxf(m, __shfl_xor(m, o2, 64));
        float s = 0.f;
        for (int j = ln; j < 1024; j += 32) {
            float e = __expf(sc[r][j] - m);
            sc[r][j] = e; s += e;
        }
        #pragma unroll
        for (int o2 = 16; o2 > 0; o2 >>= 1) s += __shfl_xor(s, o2, 64);
        float inv = 1.0f / s;
        for (int j = ln; j < 1024; j += 32) sc[r][j] *= inv;
    }
    __syncthreads();

    // phase 3: PV — wave jg handles j = jg*4 + 16k, float4 over sc
    int dd = tid & 63, jg = tid >> 6;
    float acc[8] = {};
    for (int j0 = jg * 4; j0 < 1024; j0 += 16) {
        float vv[4];
        #pragma unroll
        for (int u = 0; u < 4; u++)
            vv[u] = qkv[(size_t)(b * S_LEN + j0 + u) * 3072 + 2048 + h * 64 + dd];
        #pragma unroll
        for (int r = 0; r < 8; r++) {
            float4 p = *(const float4*)&sc[r][j0];
            acc[r] += p.x * vv[0] + p.y * vv[1] + p.z * vv[2] + p.w * vv[3];
        }
    }
    #pragma unroll
    for (int r = 0; r < 8; r++) pacc[jg][r][dd] = acc[r];
    __syncthreads();
    for (int idx = tid; idx < 512; idx += 256) {
        int r = idx >> 6, d2 = idx & 63;
        float s = pacc[0][r][d2] + pacc[1][r][d2] + pacc[2][r][d2] + pacc[3][r][d2];
        o[(size_t)(b * S_LEN + q0 + r) * DMODEL + h * 64 + d2] = f2bf(s);
    }
}

// ---------------- gate ----------------
__global__ __launch_bounds__(64) void gate_kernel(const float* __restrict__ hn,
                                                  const float* __restrict__ Wgate,
                                                  float* __restrict__ wfull,
                                                  float* __restrict__ gate_sum) {
    int t = blockIdx.x;
    int lane = threadIdx.x;
    const float* xr = hn + (size_t)t * DMODEL;
    float logits[8];
    #pragma unroll
    for (int e = 0; e < 8; e++) {
        float p = 0.f;
        for (int d = lane; d < DMODEL; d += 64) p += xr[d] * Wgate[d * 8 + e];
        for (int o = 32; o > 0; o >>= 1) p += __shfl_down(p, o);
        logits[e] = p;
    }
    if (lane == 0) {
        float mx = logits[0];
        #pragma unroll
        for (int e = 1; e < 8; e++) mx = fmaxf(mx, logits[e]);
        float pr[8]; float s = 0.f;
        #pragma unroll
        for (int e = 0; e < 8; e++) { pr[e] = __expf(logits[e] - mx); s += pr[e]; }
        float inv = 1.0f / s;
        int e1 = 0; float v1 = -1.f;
        #pragma unroll
        for (int e = 0; e < 8; e++) {
            pr[e] *= inv;
            atomicAdd(&gate_sum[e], pr[e]);
            if (pr[e] > v1) { v1 = pr[e]; e1 = e; }
        }
        int e2 = -1; float v2 = -1.f;
        #pragma unroll
        for (int e = 0; e < 8; e++) {
            if (e == e1) continue;
            if (pr[e] > v2) { v2 = pr[e]; e2 = e; }
        }
        wfull[t * 8 + e1] = v1;
        wfull[t * 8 + e2] = v2;
    }
}

// ---------------- per-expert top-CAP via bitonic sort ----------------
__global__ __launch_bounds__(1024) void expert_select_kernel(const float* __restrict__ wfull,
                                                             float* __restrict__ sw,
                                                             int* __restrict__ sidx,
                                                             int* __restrict__ slot) {
    __shared__ unsigned long long keys[2048];
    int e = blockIdx.x;
    int t = threadIdx.x;
    for (int i = t; i < 2048; i += 1024) {
        float w = wfull[i * 8 + e];
        unsigned int wb = __float_as_uint(w);
        keys[i] = ((unsigned long long)wb << 32) | (unsigned long long)(0xFFFFFFFFu - (unsigned int)i);
    }
    __syncthreads();
    for (int k = 2; k <= 2048; k <<= 1) {
        for (int j = k >> 1; j > 0; j >>= 1) {
            for (int i = t; i < 2048; i += 1024) {
                int ixj = i ^ j;
                if (ixj > i) {
                    bool desc = ((i & k) == 0);
                    unsigned long long a = keys[i], b = keys[ixj];
                    if ((a < b) == desc) { keys[i] = b; keys[ixj] = a; }
                }
            }
            __syncthreads();
        }
    }
    if (t < CAP) {
        unsigned long long kk = keys[t];
        float w = __uint_as_float((unsigned int)(kk >> 32));
        int idx = (int)(0xFFFFFFFFu - (unsigned int)(kk & 0xFFFFFFFFu));
        sw[e * CAP + t] = w;
        sidx[e * CAP + t] = idx;
        if (w > 0.f) slot[idx * 8 + e] = t;
    }
}

// ---------------- gather tokens -> bf16 ----------------
__global__ __launch_bounds__(256) void gather_tok_kernel(const float* __restrict__ hn,
                                                         const int* __restrict__ sidx,
                                                         const float* __restrict__ sw,
                                                         unsigned short* __restrict__ tok) {
    int ec = blockIdx.x;
    int tid = threadIdx.x;
    float w = sw[ec];
    int src = sidx[ec];
    const float* s = hn + (size_t)src * DMODEL;
    unsigned short* d = tok + (size_t)ec * DMODEL;
    for (int i = tid; i < DMODEL; i += 256) d[i] = (w > 0.f) ? f2bf(s[i]) : 0;
}

// ---------------- final combine ----------------
__global__ __launch_bounds__(256) void combine_kernel(const float* __restrict__ h,
                                                      const float* __restrict__ out_e,
                                                      const int* __restrict__ slot,
                                                      const float* __restrict__ wfull,
                                                      const float* __restrict__ gate_sum,
                                                      float* __restrict__ out) {
    int t = blockIdx.x;
    int tid = threadIdx.x;
    for (int d = tid; d < DMODEL; d += 256) {
        float acc = h[(size_t)t * DMODEL + d];
        #pragma unroll
        for (int e = 0; e < 8; e++) {
            int c = slot[t * 8 + e];
            if (c >= 0) acc += wfull[t * 8 + e] * out_e[((size_t)(e * CAP + c)) * DMODEL + d];
        }
        out[(size_t)t * DMODEL + d] = acc;
    }
    if (t == 0 && tid == 0) {
        float a = 0.f;
        #pragma unroll
        for (int e = 0; e < 8; e++) { float m = gate_sum[e] / (float)T_TOK; a += m * m; }
        out[(size_t)T_TOK * DMODEL] = 8.0f * a;
    }
}

extern "C" void kernel_launch(void* const* d_in, const int* in_sizes, int n_in,
                              void* d_out, int out_size, void* d_ws, size_t ws_size,
                              hipStream_t stream) {
    const float* x     = (const float*)d_in[0];
    const int*   gtm   = (const int*)d_in[2];
    const float* Wq    = (const float*)d_in[3];
    const float* Wk    = (const float*)d_in[4];
    const float* Wv    = (const float*)d_in[5];
    const float* Wo    = (const float*)d_in[6];
    const float* g1    = (const float*)d_in[7];
    const float* g2    = (const float*)d_in[8];
    const float* Wgate = (const float*)d_in[9];
    const float* W1    = (const float*)d_in[10];
    const float* W2    = (const float*)d_in[11];
    float* out = (float*)d_out;

    char* ws = (char*)d_ws;
    // layout (bytes), peak ~97 MB
    unsigned short* WT32  = (unsigned short*)(ws + 0);          // 33554432 B (W1/W2 transpose chunks)
    char* unionA          = ws + 33554432;                      // 16777216 B
    unsigned short* WqkvT = (unsigned short*)(unionA + 0);      // 6291456
    unsigned short* WoT   = (unsigned short*)(unionA + 6291456);// 2097152
    unsigned short* xn    = (unsigned short*)(unionA + 8388608);// 4194304
    unsigned short* attno = (unsigned short*)(unionA + 12582912);//4194304
    unsigned short* act   = (unsigned short*)(unionA + 0);      // 16777216 (phase B, overlays phase A)
    float* qkvb  = (float*)(ws + 50331648);                     // 25165824
    float* oute  = (float*)(ws + 50331648);                     // 8388608 (overlays qkvb)
    float* hb    = (float*)(ws + 75497472);                     // 8388608
    float* hnb   = (float*)(ws + 83886080);                     // 8388608
    unsigned short* tok = (unsigned short*)(ws + 92274688);     // 4194304
    float* ropec = (float*)(ws + 96468992);                     // 131072
    float* ropes = (float*)(ws + 96600064);                     // 131072
    float* wfull = (float*)(ws + 96731136);                     // 65536
    int*   slot  = (int*)(ws + 96796672);                       // 65536
    float* sw    = (float*)(ws + 96862208);                     // 8192
    int*   sidx  = (int*)(ws + 96870400);                       // 8192
    float* gsum  = (float*)(ws + 96878592);                     // 32

    rope_table_kernel<<<S_LEN, 32, 0, stream>>>(ropec, ropes);
    rmsnorm_kernel<1><<<T_TOK, 256, 0, stream>>>(x, g1, xn);

    // weight transposes (f32 (K,N) -> bf16 (N,K))
    transpose_bf16<<<dim3(32, 32, 1), 256, 0, stream>>>(Wq, WqkvT, 1024, 1024, 0, 0);
    transpose_bf16<<<dim3(32, 32, 1), 256, 0, stream>>>(Wk, WqkvT + 1024 * 1024, 1024, 1024, 0, 0);
    transpose_bf16<<<dim3(32, 32, 1), 256, 0, stream>>>(Wv, WqkvT + 2048 * 1024, 1024, 1024, 0, 0);
    transpose_bf16<<<dim3(32, 32, 1), 256, 0, stream>>>(Wo, WoT, 1024, 1024, 0, 0);

    // QKV: qkvb(2048,3072) = xn @ [Wq|Wk|Wv]
    gemm_mfma<128, 0><<<dim3(24, 16, 1), 256, 0, stream>>>(
        xn, WqkvT, nullptr, qkvb, 1024, 1024, 3072, 0, 0, 0);

    rope_apply_kernel<<<T_TOK, 512, 0, stream>>>(qkvb, ropec, ropes);
    attn_kernel<<<2 * 16 * 128, 256, 0, stream>>>(qkvb, gtm, attno);

    // h = x + attno @ Wo
    gemm_mfma<128, 1><<<dim3(8, 16, 1), 256, 0, stream>>>(
        attno, WoT, x, hb, 1024, 1024, 1024, 0, 0, 0);
    rmsnorm_kernel<0><<<T_TOK, 256, 0, stream>>>(hb, g2, hnb);

    hipMemsetAsync(wfull, 0, (size_t)T_TOK * NE * 4, stream);
    hipMemsetAsync(slot, 0xFF, (size_t)T_TOK * NE * 4, stream);
    hipMemsetAsync(gsum, 0, 8 * 4, stream);

    gate_kernel<<<T_TOK, 64, 0, stream>>>(hnb, Wgate, wfull, gsum);
    expert_select_kernel<<<NE, 1024, 0, stream>>>(wfull, sw, sidx, slot);
    gather_tok_kernel<<<NE * CAP, 256, 0, stream>>>(hnb, sidx, sw, tok);

    // MoE W1 + SwiGLU, chunked over DFF in 4 pieces of 1024 cols
    for (int c = 0; c < 4; c++) {
        // h1 part: W1 cols [c*1024, +1024) ; h2 part: cols [4096 + c*1024, +1024)
        transpose_bf16<<<dim3(32, 32, 8), 256, 0, stream>>>(
            W1 + (size_t)c * 1024, WT32, 8192, 1024,
            (long long)1024 * 8192, (long long)2 * 1024 * 1024);
        transpose_bf16<<<dim3(32, 32, 8), 256, 0, stream>>>(
            W1 + 4096 + (size_t)c * 1024, WT32 + 1024 * 1024, 8192, 1024,
            (long long)1024 * 8192, (long long)2 * 1024 * 1024);
        gemm_w1_swiglu<<<dim3(16, 2, 8), 256, 0, stream>>>(
            tok, WT32, act + (size_t)c * 1024,
            (long long)CAP * 1024, (long long)2 * 1024 * 1024, (long long)CAP * 4096);
    }

    // MoE W2, split-K in 2 chunks of 2048
    for (int c = 0; c < 2; c++) {
        transpose_bf16<<<dim3(32, 64, 8), 256, 0, stream>>>(
            W2 + (size_t)c * 2048 * 1024, WT32, 1024, 2048,
            (long long)4096 * 1024, (long long)1024 * 2048);
        if (c == 0)
            gemm_mfma<64, 0><<<dim3(16, 2, 8), 256, 0, stream>>>(
                act, WT32, nullptr, oute, 2048, 4096, 1024,
                (long long)CAP * 4096, (long long)1024 * 2048, (long long)CAP * 1024);
        else
            gemm_mfma<64, 2><<<dim3(16, 2, 8), 256, 0, stream>>>(
                act + 2048, WT32, nullptr, oute, 2048, 4096, 1024,
                (long long)CAP * 4096, (long long)1024 * 2048, (long long)CAP * 1024);
    }

    combine_kernel<<<T_TOK, 256, 0, stream>>>(hb, oute, slot, wfull, gsum, out);
}

// Round 4
// 754.913 us; speedup vs baseline: 2.9875x; 2.0744x over previous
//
#include <hip/hip_runtime.h>
#include <hip/hip_bf16.h>
#include <math.h>

#define T_TOK 2048
#define DMODEL 1024
#define NH 16
#define HD 64
#define S_LEN 1024
#define NE 8
#define CAP 256
#define DFF 4096

typedef __attribute__((ext_vector_type(8))) short bf16x8;
typedef __attribute__((ext_vector_type(4))) float f32x4;

__device__ inline unsigned short f2bf(float f) {
    union { float f; unsigned int u; } x; x.f = f;
    unsigned int u = x.u;
    unsigned int r = (u + 0x7FFFu + ((u >> 16) & 1u)) >> 16;
    return (unsigned short)r;
}

__device__ inline float bf2f(unsigned short h) {
    union { unsigned int u; float f; } x; x.u = (unsigned int)h << 16; return x.f;
}

__device__ inline void gload16(const void* g, void* l) {
    __builtin_amdgcn_global_load_lds(
        (const __attribute__((address_space(1))) unsigned int*)g,
        (__attribute__((address_space(3))) unsigned int*)l, 16, 0, 0);
}

// ---------------- RoPE table ----------------
__global__ void rope_table_kernel(float* __restrict__ rc, float* __restrict__ rs) {
    int s = blockIdx.x;
    int i = threadIdx.x;
    float invf = powf(10000.0f, -(float)(2 * i) / 64.0f);
    float ang = (float)s * invf;
    rc[s * 32 + i] = cosf(ang);
    rs[s * 32 + i] = sinf(ang);
}

// ---------------- RMSNorm (OUTBF: 1 -> bf16 out, 0 -> f32 out) ----------------
template <int OUTBF>
__global__ __launch_bounds__(256) void rmsnorm_kernel(const float* __restrict__ x,
                                                      const float* __restrict__ g,
                                                      void* __restrict__ yv) {
    __shared__ float red[256];
    int t = blockIdx.x;
    int tid = threadIdx.x;
    const float* xr = x + (size_t)t * DMODEL;
    float ss = 0.f;
    for (int d = tid; d < DMODEL; d += 256) { float v = xr[d]; ss += v * v; }
    red[tid] = ss; __syncthreads();
    for (int o = 128; o > 0; o >>= 1) { if (tid < o) red[tid] += red[tid + o]; __syncthreads(); }
    float scale = 1.0f / sqrtf(red[0] / (float)DMODEL + 1e-6f);
    if (OUTBF) {
        unsigned short* yr = (unsigned short*)yv + (size_t)t * DMODEL;
        for (int d = tid; d < DMODEL; d += 256) yr[d] = f2bf(g[d] * xr[d] * scale);
    } else {
        float* yr = (float*)yv + (size_t)t * DMODEL;
        for (int d = tid; d < DMODEL; d += 256) yr[d] = g[d] * xr[d] * scale;
    }
}

// ---------------- transpose+convert: dst_bf16(C,R) = src_f32(R,C)^T ----------------
__global__ __launch_bounds__(256) void transpose_bf16(const float* __restrict__ src,
                                                      unsigned short* __restrict__ dst,
                                                      int ldS, int ldD,
                                                      long long sS, long long sD) {
    __shared__ float tile[32][33];
    src += (long long)blockIdx.z * sS;
    dst += (long long)blockIdx.z * sD;
    int c0 = blockIdx.x * 32, r0 = blockIdx.y * 32;
    int tx = threadIdx.x & 31, ty = threadIdx.x >> 5;
    #pragma unroll
    for (int j = 0; j < 4; j++)
        tile[ty + j * 8][tx] = src[(size_t)(r0 + ty + j * 8) * ldS + c0 + tx];
    __syncthreads();
    #pragma unroll
    for (int j = 0; j < 4; j++)
        dst[(size_t)(c0 + ty + j * 8) * ldD + r0 + tx] = f2bf(tile[tx][ty + j * 8]);
}

// ---------------- bf16 MFMA GEMM: C(f32) = A(M,K)bf16 @ BT(N,K)bf16^T ----------------
template <int BN, int RES>
__global__ __launch_bounds__(256) void gemm_mfma(const unsigned short* __restrict__ A,
                                                 const unsigned short* __restrict__ BT,
                                                 const float* __restrict__ Rr,
                                                 float* __restrict__ C,
                                                 int K, int lda, int ldc,
                                                 long long sA, long long sB, long long sC) {
    constexpr int BM = 128, BK = 64;
    constexpr int NF = BN / 32;
    __shared__ unsigned short As[BM * BK];
    __shared__ unsigned short Bs[BN * BK];
    A += (long long)blockIdx.z * sA;
    BT += (long long)blockIdx.z * sB;
    C += (long long)blockIdx.z * sC;
    const int tid = threadIdx.x;
    const int lane = tid & 63;
    const int wid = tid >> 6;
    const int wr = wid >> 1, wc = wid & 1;
    const int bx = blockIdx.x * BN, by = blockIdx.y * BM;

    f32x4 acc[4][NF] = {};

    for (int k0 = 0; k0 < K; k0 += BK) {
        #pragma unroll
        for (int i = 0; i < (BM * 8) / 256; i++) {
            int c = i * 256 + tid;
            int row = c >> 3, slot = c & 7;
            int gs = slot ^ (row & 7);
            gload16(A + (size_t)(by + row) * lda + k0 + gs * 8, &As[c * 8]);
        }
        #pragma unroll
        for (int i = 0; i < (BN * 8) / 256; i++) {
            int c = i * 256 + tid;
            int row = c >> 3, slot = c & 7;
            int gs = slot ^ (row & 7);
            gload16(BT + (size_t)(bx + row) * K + k0 + gs * 8, &Bs[c * 8]);
        }
        __syncthreads();
        #pragma unroll
        for (int ks = 0; ks < 2; ks++) {
            bf16x8 af[4], bfr[NF];
            #pragma unroll
            for (int m = 0; m < 4; m++) {
                int row = wr * 64 + m * 16 + (lane & 15);
                int slot = (ks * 4 + (lane >> 4)) ^ (row & 7);
                af[m] = *(const bf16x8*)&As[row * 64 + slot * 8];
            }
            #pragma unroll
            for (int n = 0; n < NF; n++) {
                int row = wc * (BN / 2) + n * 16 + (lane & 15);
                int slot = (ks * 4 + (lane >> 4)) ^ (row & 7);
                bfr[n] = *(const bf16x8*)&Bs[row * 64 + slot * 8];
            }
            #pragma unroll
            for (int m = 0; m < 4; m++)
                #pragma unroll
                for (int n = 0; n < NF; n++)
                    acc[m][n] = __builtin_amdgcn_mfma_f32_16x16x32_bf16(af[m], bfr[n], acc[m][n], 0, 0, 0);
        }
        __syncthreads();
    }
    #pragma unroll
    for (int m = 0; m < 4; m++) {
        int row0 = by + wr * 64 + m * 16 + (lane >> 4) * 4;
        #pragma unroll
        for (int n = 0; n < NF; n++) {
            int col = bx + wc * (BN / 2) + n * 16 + (lane & 15);
            #pragma unroll
            for (int r = 0; r < 4; r++) {
                size_t idx = (size_t)(row0 + r) * ldc + col;
                float v = acc[m][n][r];
                if (RES == 1) v += Rr[idx];
                if (RES == 2) v += C[idx];
                C[idx] = v;
            }
        }
    }
}

// ---------------- W1 GEMM with fused SwiGLU, bf16 out ----------------
__global__ __launch_bounds__(256) void gemm_w1_swiglu(const unsigned short* __restrict__ A,
                                                      const unsigned short* __restrict__ BT,
                                                      unsigned short* __restrict__ C,
                                                      long long sA, long long sB, long long sC) {
    constexpr int BM = 128, BK = 64, BN = 64, NF = 2, K = 1024, LDC = 4096;
    __shared__ unsigned short As[BM * BK];
    __shared__ unsigned short B1s[BN * BK];
    __shared__ unsigned short B2s[BN * BK];
    A += (long long)blockIdx.z * sA;
    BT += (long long)blockIdx.z * sB;
    C += (long long)blockIdx.z * sC;
    const int tid = threadIdx.x;
    const int lane = tid & 63;
    const int wid = tid >> 6;
    const int wr = wid >> 1, wc = wid & 1;
    const int bx = blockIdx.x * BN, by = blockIdx.y * BM;

    f32x4 acc1[4][NF] = {};
    f32x4 acc2[4][NF] = {};

    for (int k0 = 0; k0 < K; k0 += BK) {
        #pragma unroll
        for (int i = 0; i < 4; i++) {
            int c = i * 256 + tid;
            int row = c >> 3, slot = c & 7;
            int gs = slot ^ (row & 7);
            gload16(A + (size_t)(by + row) * K + k0 + gs * 8, &As[c * 8]);
        }
        #pragma unroll
        for (int i = 0; i < 2; i++) {
            int c = i * 256 + tid;
            int row = c >> 3, slot = c & 7;
            int gs = slot ^ (row & 7);
            gload16(BT + (size_t)(bx + row) * K + k0 + gs * 8, &B1s[c * 8]);
            gload16(BT + 1048576 + (size_t)(bx + row) * K + k0 + gs * 8, &B2s[c * 8]);
        }
        __syncthreads();
        #pragma unroll
        for (int ks = 0; ks < 2; ks++) {
            bf16x8 af[4], b1[NF], b2[NF];
            #pragma unroll
            for (int m = 0; m < 4; m++) {
                int row = wr * 64 + m * 16 + (lane & 15);
                int slot = (ks * 4 + (lane >> 4)) ^ (row & 7);
                af[m] = *(const bf16x8*)&As[row * 64 + slot * 8];
            }
            #pragma unroll
            for (int n = 0; n < NF; n++) {
                int row = wc * 32 + n * 16 + (lane & 15);
                int slot = (ks * 4 + (lane >> 4)) ^ (row & 7);
                b1[n] = *(const bf16x8*)&B1s[row * 64 + slot * 8];
                b2[n] = *(const bf16x8*)&B2s[row * 64 + slot * 8];
            }
            #pragma unroll
            for (int m = 0; m < 4; m++)
                #pragma unroll
                for (int n = 0; n < NF; n++) {
                    acc1[m][n] = __builtin_amdgcn_mfma_f32_16x16x32_bf16(af[m], b1[n], acc1[m][n], 0, 0, 0);
                    acc2[m][n] = __builtin_amdgcn_mfma_f32_16x16x32_bf16(af[m], b2[n], acc2[m][n], 0, 0, 0);
                }
        }
        __syncthreads();
    }
    #pragma unroll
    for (int m = 0; m < 4; m++) {
        int row0 = by + wr * 64 + m * 16 + (lane >> 4) * 4;
        #pragma unroll
        for (int n = 0; n < NF; n++) {
            int col = bx + wc * 32 + n * 16 + (lane & 15);
            #pragma unroll
            for (int r = 0; r < 4; r++) {
                float h1 = acc1[m][n][r], h2 = acc2[m][n][r];
                float sil = h2 / (1.0f + __expf(-h2));
                C[(size_t)(row0 + r) * LDC + col] = f2bf(h1 * sil);
            }
        }
    }
}

// ---------------- RoPE + convert to hi/lo bf16 pairs, head-major ----------------
__global__ __launch_bounds__(512) void rope_cvt_kernel(const float* __restrict__ qkv,
                                                       const float* __restrict__ rc,
                                                       const float* __restrict__ rs,
                                                       unsigned short* __restrict__ Qh,
                                                       unsigned short* __restrict__ Ql,
                                                       unsigned short* __restrict__ Kh,
                                                       unsigned short* __restrict__ Kl) {
    int t = blockIdx.x;
    int b = t >> 10, s = t & 1023;
    int hh = threadIdx.x >> 5, i = threadIdx.x & 31;
    float c = rc[s * 32 + i], sn = rs[s * 32 + i];
    size_t base = (size_t)t * 3072 + hh * 64;
    float qa = qkv[base + i], qb_ = qkv[base + i + 32];
    float ka = qkv[base + 1024 + i], kb_ = qkv[base + 1024 + i + 32];
    size_t ob = ((size_t)(b * 16 + hh) * 1024 + s) * 64;
    float q0 = (qa * c - qb_ * sn) * 0.125f;
    float q1 = (qb_ * c + qa * sn) * 0.125f;
    float k0 = ka * c - kb_ * sn;
    float k1 = kb_ * c + ka * sn;
    unsigned short h0, h1;
    h0 = f2bf(q0); Qh[ob + i] = h0;      Ql[ob + i] = f2bf(q0 - bf2f(h0));
    h1 = f2bf(q1); Qh[ob + i + 32] = h1; Ql[ob + i + 32] = f2bf(q1 - bf2f(h1));
    h0 = f2bf(k0); Kh[ob + i] = h0;      Kl[ob + i] = f2bf(k0 - bf2f(h0));
    h1 = f2bf(k1); Kh[ob + i + 32] = h1; Kl[ob + i + 32] = f2bf(k1 - bf2f(h1));
}

// ---------------- V transpose+convert: qkv f32 -> Vtb bf16 [bh][d][s] ----------------
__global__ __launch_bounds__(256) void vt_cvt_kernel(const float* __restrict__ qkv,
                                                     unsigned short* __restrict__ Vtb) {
    __shared__ float tile[32][65];
    int st = blockIdx.x;
    int bh = blockIdx.y;
    int b = bh >> 4, h = bh & 15;
    int tid = threadIdx.x;
    int s0 = st * 32;
    int sr = tid >> 3, c8 = (tid & 7) * 8;
    const float* src = qkv + (size_t)(b * 1024 + s0 + sr) * 3072 + 2048 + h * 64 + c8;
    #pragma unroll
    for (int u = 0; u < 8; u++) tile[sr][c8 + u] = src[u];
    __syncthreads();
    int d = tid & 63, sj = (tid >> 6) * 8;
    unsigned short tmp[8];
    #pragma unroll
    for (int u = 0; u < 8; u++) tmp[u] = f2bf(tile[sj + u][d]);
    *(uint4*)(Vtb + ((size_t)bh * 64 + d) * 1024 + s0 + sj) = *(uint4*)tmp;
}

// ---------------- flash-style MFMA attention with hi/lo QK^T ----------------
__global__ __launch_bounds__(256) void attn_mfma_kernel(const unsigned short* __restrict__ Qh,
                                                        const unsigned short* __restrict__ Ql,
                                                        const unsigned short* __restrict__ Kh,
                                                        const unsigned short* __restrict__ Kl,
                                                        const unsigned short* __restrict__ Vtb,
                                                        const int* __restrict__ gtm,
                                                        unsigned short* __restrict__ o) {
    __shared__ unsigned short Ksh[64 * 64];
    __shared__ unsigned short Ksl[64 * 64];
    __shared__ unsigned short Vs[64 * 64];
    __shared__ unsigned short Pl[4][32 * 64];
    const int qt = blockIdx.x, h = blockIdx.y, b = blockIdx.z;
    const int bh = b * 16 + h;
    const int tid = threadIdx.x, l = tid & 63, w = tid >> 6;
    const int q0 = qt * 128 + w * 32;
    const unsigned short* Qhb = Qh + (size_t)bh * 1024 * 64;
    const unsigned short* Qlb = Ql + (size_t)bh * 1024 * 64;
    const unsigned short* Khb = Kh + (size_t)bh * 1024 * 64;
    const unsigned short* Klb = Kl + (size_t)bh * 1024 * 64;
    const unsigned short* Vbh = Vtb + (size_t)bh * 64 * 1024;
    const int* gb = gtm + b * 1024;

    bf16x8 afh[2][2], afl[2][2];
    #pragma unroll
    for (int m = 0; m < 2; m++)
        #pragma unroll
        for (int ks = 0; ks < 2; ks++) {
            size_t off = (size_t)(q0 + m * 16 + (l & 15)) * 64 + ks * 32 + (l >> 4) * 8;
            afh[m][ks] = *(const bf16x8*)(Qhb + off);
            afl[m][ks] = *(const bf16x8*)(Qlb + off);
        }

    int gqm[2];
    #pragma unroll
    for (int m = 0; m < 2; m++) {
        int bits = 0;
        #pragma unroll
        for (int r = 0; r < 4; r++)
            bits |= (gb[q0 + m * 16 + (l >> 4) * 4 + r] ? 1 : 0) << r;
        gqm[m] = bits;
    }

    f32x4 acc_o[2][4] = {};
    float m_run[2][4], l_run[2][4];
    #pragma unroll
    for (int m = 0; m < 2; m++)
        #pragma unroll
        for (int r = 0; r < 4; r++) { m_run[m][r] = -1e30f; l_run[m][r] = 0.f; }

    for (int jt = 0; jt < 16; jt++) {
        const int j0 = jt * 64;
        #pragma unroll
        for (int i = 0; i < 2; i++) {
            int c = i * 256 + tid, row = c >> 3, sl = c & 7, gs = sl ^ (row & 7);
            gload16(Khb + (size_t)(j0 + row) * 64 + gs * 8, &Ksh[c * 8]);
            gload16(Klb + (size_t)(j0 + row) * 64 + gs * 8, &Ksl[c * 8]);
            gload16(Vbh + (size_t)row * 1024 + j0 + gs * 8, &Vs[c * 8]);
        }
        __syncthreads();

        // S = Qh·Kh + Ql·Kh + Qh·Kl  (f32-grade scores): 48 mfma
        f32x4 sv[2][4] = {};
        #pragma unroll
        for (int n = 0; n < 4; n++) {
            #pragma unroll
            for (int ks = 0; ks < 2; ks++) {
                int row = n * 16 + (l & 15);
                int sl = (ks * 4 + (l >> 4)) ^ (row & 7);
                bf16x8 khf = *(const bf16x8*)&Ksh[row * 64 + sl * 8];
                bf16x8 klf = *(const bf16x8*)&Ksl[row * 64 + sl * 8];
                #pragma unroll
                for (int m = 0; m < 2; m++) {
                    sv[m][n] = __builtin_amdgcn_mfma_f32_16x16x32_bf16(afl[m][ks], khf, sv[m][n], 0, 0, 0);
                    sv[m][n] = __builtin_amdgcn_mfma_f32_16x16x32_bf16(afh[m][ks], klf, sv[m][n], 0, 0, 0);
                    sv[m][n] = __builtin_amdgcn_mfma_f32_16x16x32_bf16(afh[m][ks], khf, sv[m][n], 0, 0, 0);
                }
            }
        }

        int gk[4];
        #pragma unroll
        for (int n = 0; n < 4; n++) gk[n] = gb[j0 + n * 16 + (l & 15)];

        #pragma unroll
        for (int m = 0; m < 2; m++)
            #pragma unroll
            for (int n = 0; n < 4; n++)
                #pragma unroll
                for (int r = 0; r < 4; r++) {
                    int q = q0 + m * 16 + (l >> 4) * 4 + r;
                    int k = j0 + n * 16 + (l & 15);
                    bool allowed = ((gqm[m] >> r) & 1) || gk[n] || ((k <= q) && (q - k < 256));
                    if (!allowed) sv[m][n][r] = -1e30f;
                }

        // online softmax
        #pragma unroll
        for (int m = 0; m < 2; m++) {
            float tm[4], corr[4], rsum[4];
            #pragma unroll
            for (int r = 0; r < 4; r++)
                tm[r] = fmaxf(fmaxf(sv[m][0][r], sv[m][1][r]), fmaxf(sv[m][2][r], sv[m][3][r]));
            #pragma unroll
            for (int wd = 1; wd <= 8; wd <<= 1)
                #pragma unroll
                for (int r = 0; r < 4; r++) tm[r] = fmaxf(tm[r], __shfl_xor(tm[r], wd, 64));
            #pragma unroll
            for (int r = 0; r < 4; r++) {
                float mn = fmaxf(m_run[m][r], tm[r]);
                corr[r] = __expf(m_run[m][r] - mn);
                m_run[m][r] = mn;
                rsum[r] = 0.f;
            }
            #pragma unroll
            for (int n = 0; n < 4; n++)
                #pragma unroll
                for (int r = 0; r < 4; r++) {
                    float p = __expf(sv[m][n][r] - m_run[m][r]);
                    sv[m][n][r] = p;
                    rsum[r] += p;
                }
            #pragma unroll
            for (int wd = 1; wd <= 8; wd <<= 1)
                #pragma unroll
                for (int r = 0; r < 4; r++) rsum[r] += __shfl_xor(rsum[r], wd, 64);
            #pragma unroll
            for (int r = 0; r < 4; r++) l_run[m][r] = l_run[m][r] * corr[r] + rsum[r];
            #pragma unroll
            for (int nd = 0; nd < 4; nd++)
                #pragma unroll
                for (int r = 0; r < 4; r++) acc_o[m][nd][r] *= corr[r];
            #pragma unroll
            for (int n = 0; n < 4; n++)
                #pragma unroll
                for (int r = 0; r < 4; r++) {
                    int qr = m * 16 + (l >> 4) * 4 + r;
                    int kc = n * 16 + (l & 15);
                    int byte = (qr * 128 + kc * 2) ^ ((qr & 7) << 4);
                    Pl[w][byte >> 1] = f2bf(sv[m][n][r]);
                }
        }

        asm volatile("s_waitcnt lgkmcnt(0)" ::: "memory");
        __builtin_amdgcn_sched_barrier(0);

        // O += P V : 16 mfma
        #pragma unroll
        for (int ks = 0; ks < 2; ks++) {
            bf16x8 pa[2];
            #pragma unroll
            for (int m = 0; m < 2; m++) {
                int row = m * 16 + (l & 15);
                int sl = (ks * 4 + (l >> 4)) ^ (row & 7);
                pa[m] = *(const bf16x8*)&Pl[w][row * 64 + sl * 8];
            }
            #pragma unroll
            for (int nd = 0; nd < 4; nd++) {
                int row = nd * 16 + (l & 15);
                int sl = (ks * 4 + (l >> 4)) ^ (row & 7);
                bf16x8 vf = *(const bf16x8*)&Vs[row * 64 + sl * 8];
                #pragma unroll
                for (int m = 0; m < 2; m++)
                    acc_o[m][nd] = __builtin_amdgcn_mfma_f32_16x16x32_bf16(pa[m], vf, acc_o[m][nd], 0, 0, 0);
            }
        }
        __syncthreads();
    }

    #pragma unroll
    for (int m = 0; m < 2; m++)
        #pragma unroll
        for (int r = 0; r < 4; r++) {
            float inv = 1.0f / l_run[m][r];
            int t_ = b * 1024 + q0 + m * 16 + (l >> 4) * 4 + r;
            #pragma unroll
            for (int nd = 0; nd < 4; nd++) {
                int col = h * 64 + nd * 16 + (l & 15);
                o[(size_t)t_ * 1024 + col] = f2bf(acc_o[m][nd][r] * inv);
            }
        }
}

// ---------------- gate ----------------
__global__ __launch_bounds__(64) void gate_kernel(const float* __restrict__ hn,
                                                  const float* __restrict__ Wgate,
                                                  float* __restrict__ wfull,
                                                  float* __restrict__ gate_sum) {
    int t = blockIdx.x;
    int lane = threadIdx.x;
    const float* xr = hn + (size_t)t * DMODEL;
    float logits[8];
    #pragma unroll
    for (int e = 0; e < 8; e++) {
        float p = 0.f;
        for (int d = lane; d < DMODEL; d += 64) p += xr[d] * Wgate[d * 8 + e];
        for (int o = 32; o > 0; o >>= 1) p += __shfl_down(p, o);
        logits[e] = p;
    }
    if (lane == 0) {
        float mx = logits[0];
        #pragma unroll
        for (int e = 1; e < 8; e++) mx = fmaxf(mx, logits[e]);
        float pr[8]; float s = 0.f;
        #pragma unroll
        for (int e = 0; e < 8; e++) { pr[e] = __expf(logits[e] - mx); s += pr[e]; }
        float inv = 1.0f / s;
        int e1 = 0; float v1 = -1.f;
        #pragma unroll
        for (int e = 0; e < 8; e++) {
            pr[e] *= inv;
            atomicAdd(&gate_sum[e], pr[e]);
            if (pr[e] > v1) { v1 = pr[e]; e1 = e; }
        }
        int e2 = -1; float v2 = -1.f;
        #pragma unroll
        for (int e = 0; e < 8; e++) {
            if (e == e1) continue;
            if (pr[e] > v2) { v2 = pr[e]; e2 = e; }
        }
        wfull[t * 8 + e1] = v1;
        wfull[t * 8 + e2] = v2;
    }
}

// ---------------- per-expert top-CAP via bitonic sort ----------------
__global__ __launch_bounds__(1024) void expert_select_kernel(const float* __restrict__ wfull,
                                                             float* __restrict__ sw,
                                                             int* __restrict__ sidx,
                                                             int* __restrict__ slot) {
    __shared__ unsigned long long keys[2048];
    int e = blockIdx.x;
    int t = threadIdx.x;
    for (int i = t; i < 2048; i += 1024) {
        float w = wfull[i * 8 + e];
        unsigned int wb = __float_as_uint(w);
        keys[i] = ((unsigned long long)wb << 32) | (unsigned long long)(0xFFFFFFFFu - (unsigned int)i);
    }
    __syncthreads();
    for (int k = 2; k <= 2048; k <<= 1) {
        for (int j = k >> 1; j > 0; j >>= 1) {
            for (int i = t; i < 2048; i += 1024) {
                int ixj = i ^ j;
                if (ixj > i) {
                    bool desc = ((i & k) == 0);
                    unsigned long long a = keys[i], b = keys[ixj];
                    if ((a < b) == desc) { keys[i] = b; keys[ixj] = a; }
                }
            }
            __syncthreads();
        }
    }
    if (t < CAP) {
        unsigned long long kk = keys[t];
        float w = __uint_as_float((unsigned int)(kk >> 32));
        int idx = (int)(0xFFFFFFFFu - (unsigned int)(kk & 0xFFFFFFFFu));
        sw[e * CAP + t] = w;
        sidx[e * CAP + t] = idx;
        if (w > 0.f) slot[idx * 8 + e] = t;
    }
}

// ---------------- gather tokens -> bf16 ----------------
__global__ __launch_bounds__(256) void gather_tok_kernel(const float* __restrict__ hn,
                                                         const int* __restrict__ sidx,
                                                         const float* __restrict__ sw,
                                                         unsigned short* __restrict__ tok) {
    int ec = blockIdx.x;
    int tid = threadIdx.x;
    float w = sw[ec];
    int src = sidx[ec];
    const float* s = hn + (size_t)src * DMODEL;
    unsigned short* d = tok + (size_t)ec * DMODEL;
    for (int i = tid; i < DMODEL; i += 256) d[i] = (w > 0.f) ? f2bf(s[i]) : 0;
}

// ---------------- final combine ----------------
__global__ __launch_bounds__(256) void combine_kernel(const float* __restrict__ h,
                                                      const float* __restrict__ out_e,
                                                      const int* __restrict__ slot,
                                                      const float* __restrict__ wfull,
                                                      const float* __restrict__ gate_sum,
                                                      float* __restrict__ out) {
    int t = blockIdx.x;
    int tid = threadIdx.x;
    for (int d = tid; d < DMODEL; d += 256) {
        float acc = h[(size_t)t * DMODEL + d];
        #pragma unroll
        for (int e = 0; e < 8; e++) {
            int c = slot[t * 8 + e];
            if (c >= 0) acc += wfull[t * 8 + e] * out_e[((size_t)(e * CAP + c)) * DMODEL + d];
        }
        out[(size_t)t * DMODEL + d] = acc;
    }
    if (t == 0 && tid == 0) {
        float a = 0.f;
        #pragma unroll
        for (int e = 0; e < 8; e++) { float m = gate_sum[e] / (float)T_TOK; a += m * m; }
        out[(size_t)T_TOK * DMODEL] = 8.0f * a;
    }
}

extern "C" void kernel_launch(void* const* d_in, const int* in_sizes, int n_in,
                              void* d_out, int out_size, void* d_ws, size_t ws_size,
                              hipStream_t stream) {
    const float* x     = (const float*)d_in[0];
    const int*   gtm   = (const int*)d_in[2];
    const float* Wq    = (const float*)d_in[3];
    const float* Wk    = (const float*)d_in[4];
    const float* Wv    = (const float*)d_in[5];
    const float* Wo    = (const float*)d_in[6];
    const float* g1    = (const float*)d_in[7];
    const float* g2    = (const float*)d_in[8];
    const float* Wgate = (const float*)d_in[9];
    const float* W1    = (const float*)d_in[10];
    const float* W2    = (const float*)d_in[11];
    float* out = (float*)d_out;

    char* ws = (char*)d_ws;
    // [0, 32M): attn-phase Q/K hi-lo + V^T; overlaid by WT32 during MoE phase
    unsigned short* WT32 = (unsigned short*)(ws + 0);
    unsigned short* Qh   = (unsigned short*)(ws + 0);           // 4.2 MB
    unsigned short* Ql   = (unsigned short*)(ws + 4194304);     // 4.2 MB
    unsigned short* Kh   = (unsigned short*)(ws + 8388608);     // 4.2 MB
    unsigned short* Kl   = (unsigned short*)(ws + 12582912);    // 4.2 MB
    unsigned short* Vtb  = (unsigned short*)(ws + 16777216);    // 4.2 MB
    unsigned short* WqkvT = (unsigned short*)(ws + 33554432);   // 6.3 MB
    unsigned short* WoT   = (unsigned short*)(ws + 39845888);   // 2.1 MB
    unsigned short* xn    = (unsigned short*)(ws + 41943040);   // 4.2 MB
    unsigned short* attno = (unsigned short*)(ws + 46137344);   // 4.2 MB
    float* qkvb  = (float*)(ws + 50331648);                     // 25.2 MB
    float* oute  = (float*)(ws + 50331648);                     // 8.4 MB (MoE phase, qkvb dead)
    unsigned short* act = (unsigned short*)(ws + 33554432);     // 16.8 MB (MoE phase, weights/xn/attno dead)
    float* hb    = (float*)(ws + 75497472);                     // 8.4 MB
    float* hnb   = (float*)(ws + 83886080);                     // 8.4 MB
    unsigned short* tok = (unsigned short*)(ws + 92274688);     // 4.2 MB
    float* ropec = (float*)(ws + 96468992);
    float* ropes = (float*)(ws + 96600064);
    float* wfull = (float*)(ws + 96731136);
    int*   slot  = (int*)(ws + 96796672);
    float* sw    = (float*)(ws + 96862208);
    int*   sidx  = (int*)(ws + 96870400);
    float* gsum  = (float*)(ws + 96878592);

    rope_table_kernel<<<S_LEN, 32, 0, stream>>>(ropec, ropes);
    rmsnorm_kernel<1><<<T_TOK, 256, 0, stream>>>(x, g1, xn);

    transpose_bf16<<<dim3(32, 32, 1), 256, 0, stream>>>(Wq, WqkvT, 1024, 1024, 0, 0);
    transpose_bf16<<<dim3(32, 32, 1), 256, 0, stream>>>(Wk, WqkvT + 1024 * 1024, 1024, 1024, 0, 0);
    transpose_bf16<<<dim3(32, 32, 1), 256, 0, stream>>>(Wv, WqkvT + 2048 * 1024, 1024, 1024, 0, 0);
    transpose_bf16<<<dim3(32, 32, 1), 256, 0, stream>>>(Wo, WoT, 1024, 1024, 0, 0);

    // QKV: qkvb(2048,3072) = xn @ [Wq|Wk|Wv]
    gemm_mfma<128, 0><<<dim3(24, 16, 1), 256, 0, stream>>>(
        xn, WqkvT, nullptr, qkvb, 1024, 1024, 3072, 0, 0, 0);

    rope_cvt_kernel<<<T_TOK, 512, 0, stream>>>(qkvb, ropec, ropes, Qh, Ql, Kh, Kl);
    vt_cvt_kernel<<<dim3(32, 32, 1), 256, 0, stream>>>(qkvb, Vtb);

    attn_mfma_kernel<<<dim3(8, 16, 2), 256, 0, stream>>>(Qh, Ql, Kh, Kl, Vtb, gtm, attno);

    // h = x + attno @ Wo
    gemm_mfma<128, 1><<<dim3(8, 16, 1), 256, 0, stream>>>(
        attno, WoT, x, hb, 1024, 1024, 1024, 0, 0, 0);
    rmsnorm_kernel<0><<<T_TOK, 256, 0, stream>>>(hb, g2, hnb);

    hipMemsetAsync(wfull, 0, (size_t)T_TOK * NE * 4, stream);
    hipMemsetAsync(slot, 0xFF, (size_t)T_TOK * NE * 4, stream);
    hipMemsetAsync(gsum, 0, 8 * 4, stream);

    gate_kernel<<<T_TOK, 64, 0, stream>>>(hnb, Wgate, wfull, gsum);
    expert_select_kernel<<<NE, 1024, 0, stream>>>(wfull, sw, sidx, slot);
    gather_tok_kernel<<<NE * CAP, 256, 0, stream>>>(hnb, sidx, sw, tok);

    // MoE W1 + SwiGLU, chunked over DFF in 4 pieces of 1024 cols
    for (int c = 0; c < 4; c++) {
        transpose_bf16<<<dim3(32, 32, 8), 256, 0, stream>>>(
            W1 + (size_t)c * 1024, WT32, 8192, 1024,
            (long long)1024 * 8192, (long long)2 * 1024 * 1024);
        transpose_bf16<<<dim3(32, 32, 8), 256, 0, stream>>>(
            W1 + 4096 + (size_t)c * 1024, WT32 + 1024 * 1024, 8192, 1024,
            (long long)1024 * 8192, (long long)2 * 1024 * 1024);
        gemm_w1_swiglu<<<dim3(16, 2, 8), 256, 0, stream>>>(
            tok, WT32, act + (size_t)c * 1024,
            (long long)CAP * 1024, (long long)2 * 1024 * 1024, (long long)CAP * 4096);
    }

    // MoE W2, split-K in 2 chunks of 2048
    for (int c = 0; c < 2; c++) {
        transpose_bf16<<<dim3(32, 64, 8), 256, 0, stream>>>(
            W2 + (size_t)c * 2048 * 1024, WT32, 1024, 2048,
            (long long)4096 * 1024, (long long)1024 * 2048);
        if (c == 0)
            gemm_mfma<64, 0><<<dim3(16, 2, 8), 256, 0, stream>>>(
                act, WT32, nullptr, oute, 2048, 4096, 1024,
                (long long)CAP * 4096, (long long)1024 * 2048, (long long)CAP * 1024);
        else
            gemm_mfma<64, 2><<<dim3(16, 2, 8), 256, 0, stream>>>(
                act + 2048, WT32, nullptr, oute, 2048, 4096, 1024,
                (long long)CAP * 4096, (long long)1024 * 2048, (long long)CAP * 1024);
    }

    combine_kernel<<<T_TOK, 256, 0, stream>>>(hb, oute, slot, wfull, gsum, out);
}

// Round 5
// 539.425 us; speedup vs baseline: 4.1809x; 1.3995x over previous
//
#include <hip/hip_runtime.h>
#include <hip/hip_bf16.h>
#include <math.h>

#define T_TOK 2048
#define DMODEL 1024
#define NH 16
#define HD 64
#define S_LEN 1024
#define NE 8
#define CAP 256
#define DFF 4096

typedef __attribute__((ext_vector_type(8))) short bf16x8;
typedef __attribute__((ext_vector_type(4))) float f32x4;

__device__ inline unsigned short f2bf(float f) {
    union { float f; unsigned int u; } x; x.f = f;
    unsigned int u = x.u;
    unsigned int r = (u + 0x7FFFu + ((u >> 16) & 1u)) >> 16;
    return (unsigned short)r;
}

__device__ inline float bf2f(unsigned short h) {
    union { unsigned int u; float f; } x; x.u = (unsigned int)h << 16; return x.f;
}

__device__ inline void gload16(const void* g, void* l) {
    __builtin_amdgcn_global_load_lds(
        (const __attribute__((address_space(1))) unsigned int*)g,
        (__attribute__((address_space(3))) unsigned int*)l, 16, 0, 0);
}

// ---------------- RoPE table ----------------
__global__ void rope_table_kernel(float* __restrict__ rc, float* __restrict__ rs) {
    int s = blockIdx.x;
    int i = threadIdx.x;
    float invf = powf(10000.0f, -(float)(2 * i) / 64.0f);
    float ang = (float)s * invf;
    rc[s * 32 + i] = cosf(ang);
    rs[s * 32 + i] = sinf(ang);
}

// ---------------- RMSNorm (OUTBF: 1 -> bf16 out, 0 -> f32 out) ----------------
template <int OUTBF>
__global__ __launch_bounds__(256) void rmsnorm_kernel(const float* __restrict__ x,
                                                      const float* __restrict__ g,
                                                      void* __restrict__ yv) {
    __shared__ float red[256];
    int t = blockIdx.x;
    int tid = threadIdx.x;
    const float* xr = x + (size_t)t * DMODEL;
    float ss = 0.f;
    for (int d = tid; d < DMODEL; d += 256) { float v = xr[d]; ss += v * v; }
    red[tid] = ss; __syncthreads();
    for (int o = 128; o > 0; o >>= 1) { if (tid < o) red[tid] += red[tid + o]; __syncthreads(); }
    float scale = 1.0f / sqrtf(red[0] / (float)DMODEL + 1e-6f);
    if (OUTBF) {
        unsigned short* yr = (unsigned short*)yv + (size_t)t * DMODEL;
        for (int d = tid; d < DMODEL; d += 256) yr[d] = f2bf(g[d] * xr[d] * scale);
    } else {
        float* yr = (float*)yv + (size_t)t * DMODEL;
        for (int d = tid; d < DMODEL; d += 256) yr[d] = g[d] * xr[d] * scale;
    }
}

// ---------------- transpose+convert v2: dst_bf16(C,R) = src_f32(R,C)^T ----------------
// 64x64 tiles, float4 loads, 16B bf16 stores
__global__ __launch_bounds__(256) void transpose_bf16(const float* __restrict__ src,
                                                      unsigned short* __restrict__ dst,
                                                      int ldS, int ldD,
                                                      long long sS, long long sD) {
    __shared__ float tile[64][65];
    src += (long long)blockIdx.z * sS;
    dst += (long long)blockIdx.z * sD;
    int c0 = blockIdx.x * 64, r0 = blockIdx.y * 64;
    int tr = threadIdx.x >> 4;           // 0..15
    int tc4 = (threadIdx.x & 15) * 4;    // 0..60
    #pragma unroll
    for (int j = 0; j < 4; j++) {
        float4 v = *(const float4*)&src[(size_t)(r0 + tr + j * 16) * ldS + c0 + tc4];
        tile[tr + j * 16][tc4 + 0] = v.x;
        tile[tr + j * 16][tc4 + 1] = v.y;
        tile[tr + j * 16][tc4 + 2] = v.z;
        tile[tr + j * 16][tc4 + 3] = v.w;
    }
    __syncthreads();
    int oc = threadIdx.x >> 3;           // 0..31 (output row = source col)
    int or8 = (threadIdx.x & 7) * 8;     // 0..56
    #pragma unroll
    for (int j = 0; j < 2; j++) {
        int c = oc + j * 32;
        unsigned short tmp[8];
        #pragma unroll
        for (int u = 0; u < 8; u++) tmp[u] = f2bf(tile[or8 + u][c]);
        *(uint4*)&dst[(size_t)(c0 + c) * ldD + r0 + or8] = *(uint4*)tmp;
    }
}

// ---------------- bf16 MFMA GEMM: C(f32) = A(M,K)bf16 @ BT(N,K)bf16^T ----------------
template <int BN, int RES>
__global__ __launch_bounds__(256) void gemm_mfma(const unsigned short* __restrict__ A,
                                                 const unsigned short* __restrict__ BT,
                                                 const float* __restrict__ Rr,
                                                 float* __restrict__ C,
                                                 int K, int lda, int ldc,
                                                 long long sA, long long sB, long long sC) {
    constexpr int BM = 128, BK = 64;
    constexpr int NF = BN / 32;
    __shared__ unsigned short As[BM * BK];
    __shared__ unsigned short Bs[BN * BK];
    A += (long long)blockIdx.z * sA;
    BT += (long long)blockIdx.z * sB;
    C += (long long)blockIdx.z * sC;
    const int tid = threadIdx.x;
    const int lane = tid & 63;
    const int wid = tid >> 6;
    const int wr = wid >> 1, wc = wid & 1;
    const int bx = blockIdx.x * BN, by = blockIdx.y * BM;

    f32x4 acc[4][NF] = {};

    for (int k0 = 0; k0 < K; k0 += BK) {
        #pragma unroll
        for (int i = 0; i < (BM * 8) / 256; i++) {
            int c = i * 256 + tid;
            int row = c >> 3, slot = c & 7;
            int gs = slot ^ (row & 7);
            gload16(A + (size_t)(by + row) * lda + k0 + gs * 8, &As[c * 8]);
        }
        #pragma unroll
        for (int i = 0; i < (BN * 8) / 256; i++) {
            int c = i * 256 + tid;
            int row = c >> 3, slot = c & 7;
            int gs = slot ^ (row & 7);
            gload16(BT + (size_t)(bx + row) * K + k0 + gs * 8, &Bs[c * 8]);
        }
        __syncthreads();
        #pragma unroll
        for (int ks = 0; ks < 2; ks++) {
            bf16x8 af[4], bfr[NF];
            #pragma unroll
            for (int m = 0; m < 4; m++) {
                int row = wr * 64 + m * 16 + (lane & 15);
                int slot = (ks * 4 + (lane >> 4)) ^ (row & 7);
                af[m] = *(const bf16x8*)&As[row * 64 + slot * 8];
            }
            #pragma unroll
            for (int n = 0; n < NF; n++) {
                int row = wc * (BN / 2) + n * 16 + (lane & 15);
                int slot = (ks * 4 + (lane >> 4)) ^ (row & 7);
                bfr[n] = *(const bf16x8*)&Bs[row * 64 + slot * 8];
            }
            #pragma unroll
            for (int m = 0; m < 4; m++)
                #pragma unroll
                for (int n = 0; n < NF; n++)
                    acc[m][n] = __builtin_amdgcn_mfma_f32_16x16x32_bf16(af[m], bfr[n], acc[m][n], 0, 0, 0);
        }
        __syncthreads();
    }
    #pragma unroll
    for (int m = 0; m < 4; m++) {
        int row0 = by + wr * 64 + m * 16 + (lane >> 4) * 4;
        #pragma unroll
        for (int n = 0; n < NF; n++) {
            int col = bx + wc * (BN / 2) + n * 16 + (lane & 15);
            #pragma unroll
            for (int r = 0; r < 4; r++) {
                size_t idx = (size_t)(row0 + r) * ldc + col;
                float v = acc[m][n][r];
                if (RES == 1) v += Rr[idx];
                if (RES == 2) v += C[idx];
                C[idx] = v;
            }
        }
    }
}

// ---------------- W1 GEMM with fused SwiGLU, bf16 out ----------------
__global__ __launch_bounds__(256) void gemm_w1_swiglu(const unsigned short* __restrict__ A,
                                                      const unsigned short* __restrict__ BT,
                                                      unsigned short* __restrict__ C,
                                                      long long sA, long long sB, long long sC) {
    constexpr int BM = 128, BK = 64, BN = 64, NF = 2, K = 1024, LDC = 4096;
    __shared__ unsigned short As[BM * BK];
    __shared__ unsigned short B1s[BN * BK];
    __shared__ unsigned short B2s[BN * BK];
    A += (long long)blockIdx.z * sA;
    BT += (long long)blockIdx.z * sB;
    C += (long long)blockIdx.z * sC;
    const int tid = threadIdx.x;
    const int lane = tid & 63;
    const int wid = tid >> 6;
    const int wr = wid >> 1, wc = wid & 1;
    const int bx = blockIdx.x * BN, by = blockIdx.y * BM;

    f32x4 acc1[4][NF] = {};
    f32x4 acc2[4][NF] = {};

    for (int k0 = 0; k0 < K; k0 += BK) {
        #pragma unroll
        for (int i = 0; i < 4; i++) {
            int c = i * 256 + tid;
            int row = c >> 3, slot = c & 7;
            int gs = slot ^ (row & 7);
            gload16(A + (size_t)(by + row) * K + k0 + gs * 8, &As[c * 8]);
        }
        #pragma unroll
        for (int i = 0; i < 2; i++) {
            int c = i * 256 + tid;
            int row = c >> 3, slot = c & 7;
            int gs = slot ^ (row & 7);
            gload16(BT + (size_t)(bx + row) * K + k0 + gs * 8, &B1s[c * 8]);
            gload16(BT + 1048576 + (size_t)(bx + row) * K + k0 + gs * 8, &B2s[c * 8]);
        }
        __syncthreads();
        #pragma unroll
        for (int ks = 0; ks < 2; ks++) {
            bf16x8 af[4], b1[NF], b2[NF];
            #pragma unroll
            for (int m = 0; m < 4; m++) {
                int row = wr * 64 + m * 16 + (lane & 15);
                int slot = (ks * 4 + (lane >> 4)) ^ (row & 7);
                af[m] = *(const bf16x8*)&As[row * 64 + slot * 8];
            }
            #pragma unroll
            for (int n = 0; n < NF; n++) {
                int row = wc * 32 + n * 16 + (lane & 15);
                int slot = (ks * 4 + (lane >> 4)) ^ (row & 7);
                b1[n] = *(const bf16x8*)&B1s[row * 64 + slot * 8];
                b2[n] = *(const bf16x8*)&B2s[row * 64 + slot * 8];
            }
            #pragma unroll
            for (int m = 0; m < 4; m++)
                #pragma unroll
                for (int n = 0; n < NF; n++) {
                    acc1[m][n] = __builtin_amdgcn_mfma_f32_16x16x32_bf16(af[m], b1[n], acc1[m][n], 0, 0, 0);
                    acc2[m][n] = __builtin_amdgcn_mfma_f32_16x16x32_bf16(af[m], b2[n], acc2[m][n], 0, 0, 0);
                }
        }
        __syncthreads();
    }
    #pragma unroll
    for (int m = 0; m < 4; m++) {
        int row0 = by + wr * 64 + m * 16 + (lane >> 4) * 4;
        #pragma unroll
        for (int n = 0; n < NF; n++) {
            int col = bx + wc * 32 + n * 16 + (lane & 15);
            #pragma unroll
            for (int r = 0; r < 4; r++) {
                float h1 = acc1[m][n][r], h2 = acc2[m][n][r];
                float sil = h2 / (1.0f + __expf(-h2));
                C[(size_t)(row0 + r) * LDC + col] = f2bf(h1 * sil);
            }
        }
    }
}

// ---------------- RoPE + convert to hi/lo bf16 pairs, head-major ----------------
__global__ __launch_bounds__(512) void rope_cvt_kernel(const float* __restrict__ qkv,
                                                       const float* __restrict__ rc,
                                                       const float* __restrict__ rs,
                                                       unsigned short* __restrict__ Qh,
                                                       unsigned short* __restrict__ Ql,
                                                       unsigned short* __restrict__ Kh,
                                                       unsigned short* __restrict__ Kl) {
    int t = blockIdx.x;
    int b = t >> 10, s = t & 1023;
    int hh = threadIdx.x >> 5, i = threadIdx.x & 31;
    float c = rc[s * 32 + i], sn = rs[s * 32 + i];
    size_t base = (size_t)t * 3072 + hh * 64;
    float qa = qkv[base + i], qb_ = qkv[base + i + 32];
    float ka = qkv[base + 1024 + i], kb_ = qkv[base + 1024 + i + 32];
    size_t ob = ((size_t)(b * 16 + hh) * 1024 + s) * 64;
    float q0 = (qa * c - qb_ * sn) * 0.125f;
    float q1 = (qb_ * c + qa * sn) * 0.125f;
    float k0 = ka * c - kb_ * sn;
    float k1 = kb_ * c + ka * sn;
    unsigned short h0, h1;
    h0 = f2bf(q0); Qh[ob + i] = h0;      Ql[ob + i] = f2bf(q0 - bf2f(h0));
    h1 = f2bf(q1); Qh[ob + i + 32] = h1; Ql[ob + i + 32] = f2bf(q1 - bf2f(h1));
    h0 = f2bf(k0); Kh[ob + i] = h0;      Kl[ob + i] = f2bf(k0 - bf2f(h0));
    h1 = f2bf(k1); Kh[ob + i + 32] = h1; Kl[ob + i + 32] = f2bf(k1 - bf2f(h1));
}

// ---------------- V transpose+convert: qkv f32 -> Vtb bf16 [bh][d][s] ----------------
__global__ __launch_bounds__(256) void vt_cvt_kernel(const float* __restrict__ qkv,
                                                     unsigned short* __restrict__ Vtb) {
    __shared__ float tile[32][65];
    int st = blockIdx.x;
    int bh = blockIdx.y;
    int b = bh >> 4, h = bh & 15;
    int tid = threadIdx.x;
    int s0 = st * 32;
    int sr = tid >> 3, c8 = (tid & 7) * 8;
    const float* src = qkv + (size_t)(b * 1024 + s0 + sr) * 3072 + 2048 + h * 64 + c8;
    #pragma unroll
    for (int u = 0; u < 8; u++) tile[sr][c8 + u] = src[u];
    __syncthreads();
    int d = tid & 63, sj = (tid >> 6) * 8;
    unsigned short tmp[8];
    #pragma unroll
    for (int u = 0; u < 8; u++) tmp[u] = f2bf(tile[sj + u][d]);
    *(uint4*)(Vtb + ((size_t)bh * 64 + d) * 1024 + s0 + sj) = *(uint4*)tmp;
}

// ---------------- flash-style MFMA attention with hi/lo QK^T ----------------
__global__ __launch_bounds__(256) void attn_mfma_kernel(const unsigned short* __restrict__ Qh,
                                                        const unsigned short* __restrict__ Ql,
                                                        const unsigned short* __restrict__ Kh,
                                                        const unsigned short* __restrict__ Kl,
                                                        const unsigned short* __restrict__ Vtb,
                                                        const int* __restrict__ gtm,
                                                        unsigned short* __restrict__ o) {
    __shared__ unsigned short Ksh[64 * 64];
    __shared__ unsigned short Ksl[64 * 64];
    __shared__ unsigned short Vs[64 * 64];
    __shared__ unsigned short Pl[4][32 * 64];
    const int qt = blockIdx.x, h = blockIdx.y, b = blockIdx.z;
    const int bh = b * 16 + h;
    const int tid = threadIdx.x, l = tid & 63, w = tid >> 6;
    const int q0 = qt * 128 + w * 32;
    const unsigned short* Qhb = Qh + (size_t)bh * 1024 * 64;
    const unsigned short* Qlb = Ql + (size_t)bh * 1024 * 64;
    const unsigned short* Khb = Kh + (size_t)bh * 1024 * 64;
    const unsigned short* Klb = Kl + (size_t)bh * 1024 * 64;
    const unsigned short* Vbh = Vtb + (size_t)bh * 64 * 1024;
    const int* gb = gtm + b * 1024;

    bf16x8 afh[2][2], afl[2][2];
    #pragma unroll
    for (int m = 0; m < 2; m++)
        #pragma unroll
        for (int ks = 0; ks < 2; ks++) {
            size_t off = (size_t)(q0 + m * 16 + (l & 15)) * 64 + ks * 32 + (l >> 4) * 8;
            afh[m][ks] = *(const bf16x8*)(Qhb + off);
            afl[m][ks] = *(const bf16x8*)(Qlb + off);
        }

    int gqm[2];
    #pragma unroll
    for (int m = 0; m < 2; m++) {
        int bits = 0;
        #pragma unroll
        for (int r = 0; r < 4; r++)
            bits |= (gb[q0 + m * 16 + (l >> 4) * 4 + r] ? 1 : 0) << r;
        gqm[m] = bits;
    }

    f32x4 acc_o[2][4] = {};
    float m_run[2][4], l_run[2][4];
    #pragma unroll
    for (int m = 0; m < 2; m++)
        #pragma unroll
        for (int r = 0; r < 4; r++) { m_run[m][r] = -1e30f; l_run[m][r] = 0.f; }

    for (int jt = 0; jt < 16; jt++) {
        const int j0 = jt * 64;
        #pragma unroll
        for (int i = 0; i < 2; i++) {
            int c = i * 256 + tid, row = c >> 3, sl = c & 7, gs = sl ^ (row & 7);
            gload16(Khb + (size_t)(j0 + row) * 64 + gs * 8, &Ksh[c * 8]);
            gload16(Klb + (size_t)(j0 + row) * 64 + gs * 8, &Ksl[c * 8]);
            gload16(Vbh + (size_t)row * 1024 + j0 + gs * 8, &Vs[c * 8]);
        }
        __syncthreads();

        // S = Qh·Kh + Ql·Kh + Qh·Kl  (f32-grade scores): 48 mfma
        f32x4 sv[2][4] = {};
        #pragma unroll
        for (int n = 0; n < 4; n++) {
            #pragma unroll
            for (int ks = 0; ks < 2; ks++) {
                int row = n * 16 + (l & 15);
                int sl = (ks * 4 + (l >> 4)) ^ (row & 7);
                bf16x8 khf = *(const bf16x8*)&Ksh[row * 64 + sl * 8];
                bf16x8 klf = *(const bf16x8*)&Ksl[row * 64 + sl * 8];
                #pragma unroll
                for (int m = 0; m < 2; m++) {
                    sv[m][n] = __builtin_amdgcn_mfma_f32_16x16x32_bf16(afl[m][ks], khf, sv[m][n], 0, 0, 0);
                    sv[m][n] = __builtin_amdgcn_mfma_f32_16x16x32_bf16(afh[m][ks], klf, sv[m][n], 0, 0, 0);
                    sv[m][n] = __builtin_amdgcn_mfma_f32_16x16x32_bf16(afh[m][ks], khf, sv[m][n], 0, 0, 0);
                }
            }
        }

        int gk[4];
        #pragma unroll
        for (int n = 0; n < 4; n++) gk[n] = gb[j0 + n * 16 + (l & 15)];

        #pragma unroll
        for (int m = 0; m < 2; m++)
            #pragma unroll
            for (int n = 0; n < 4; n++)
                #pragma unroll
                for (int r = 0; r < 4; r++) {
                    int q = q0 + m * 16 + (l >> 4) * 4 + r;
                    int k = j0 + n * 16 + (l & 15);
                    bool allowed = ((gqm[m] >> r) & 1) || gk[n] || ((k <= q) && (q - k < 256));
                    if (!allowed) sv[m][n][r] = -1e30f;
                }

        // online softmax
        #pragma unroll
        for (int m = 0; m < 2; m++) {
            float tm[4], corr[4], rsum[4];
            #pragma unroll
            for (int r = 0; r < 4; r++)
                tm[r] = fmaxf(fmaxf(sv[m][0][r], sv[m][1][r]), fmaxf(sv[m][2][r], sv[m][3][r]));
            #pragma unroll
            for (int wd = 1; wd <= 8; wd <<= 1)
                #pragma unroll
                for (int r = 0; r < 4; r++) tm[r] = fmaxf(tm[r], __shfl_xor(tm[r], wd, 64));
            #pragma unroll
            for (int r = 0; r < 4; r++) {
                float mn = fmaxf(m_run[m][r], tm[r]);
                corr[r] = __expf(m_run[m][r] - mn);
                m_run[m][r] = mn;
                rsum[r] = 0.f;
            }
            #pragma unroll
            for (int n = 0; n < 4; n++)
                #pragma unroll
                for (int r = 0; r < 4; r++) {
                    float p = __expf(sv[m][n][r] - m_run[m][r]);
                    sv[m][n][r] = p;
                    rsum[r] += p;
                }
            #pragma unroll
            for (int wd = 1; wd <= 8; wd <<= 1)
                #pragma unroll
                for (int r = 0; r < 4; r++) rsum[r] += __shfl_xor(rsum[r], wd, 64);
            #pragma unroll
            for (int r = 0; r < 4; r++) l_run[m][r] = l_run[m][r] * corr[r] + rsum[r];
            #pragma unroll
            for (int nd = 0; nd < 4; nd++)
                #pragma unroll
                for (int r = 0; r < 4; r++) acc_o[m][nd][r] *= corr[r];
            #pragma unroll
            for (int n = 0; n < 4; n++)
                #pragma unroll
                for (int r = 0; r < 4; r++) {
                    int qr = m * 16 + (l >> 4) * 4 + r;
                    int kc = n * 16 + (l & 15);
                    int byte = (qr * 128 + kc * 2) ^ ((qr & 7) << 4);
                    Pl[w][byte >> 1] = f2bf(sv[m][n][r]);
                }
        }

        asm volatile("s_waitcnt lgkmcnt(0)" ::: "memory");
        __builtin_amdgcn_sched_barrier(0);

        // O += P V : 16 mfma
        #pragma unroll
        for (int ks = 0; ks < 2; ks++) {
            bf16x8 pa[2];
            #pragma unroll
            for (int m = 0; m < 2; m++) {
                int row = m * 16 + (l & 15);
                int sl = (ks * 4 + (l >> 4)) ^ (row & 7);
                pa[m] = *(const bf16x8*)&Pl[w][row * 64 + sl * 8];
            }
            #pragma unroll
            for (int nd = 0; nd < 4; nd++) {
                int row = nd * 16 + (l & 15);
                int sl = (ks * 4 + (l >> 4)) ^ (row & 7);
                bf16x8 vf = *(const bf16x8*)&Vs[row * 64 + sl * 8];
                #pragma unroll
                for (int m = 0; m < 2; m++)
                    acc_o[m][nd] = __builtin_amdgcn_mfma_f32_16x16x32_bf16(pa[m], vf, acc_o[m][nd], 0, 0, 0);
            }
        }
        __syncthreads();
    }

    #pragma unroll
    for (int m = 0; m < 2; m++)
        #pragma unroll
        for (int r = 0; r < 4; r++) {
            float inv = 1.0f / l_run[m][r];
            int t_ = b * 1024 + q0 + m * 16 + (l >> 4) * 4 + r;
            #pragma unroll
            for (int nd = 0; nd < 4; nd++) {
                int col = h * 64 + nd * 16 + (l & 15);
                o[(size_t)t_ * 1024 + col] = f2bf(acc_o[m][nd][r] * inv);
            }
        }
}

// ---------------- gate v2: one wave per token, register-only ----------------
// lane l: e = l&7, g = l>>3; Wgate access Wgate[l + 64*kk] is fully coalesced
__global__ __launch_bounds__(256) void gate_kernel(const float* __restrict__ hn,
                                                   const float* __restrict__ Wgate,
                                                   float* __restrict__ wfull,
                                                   float* __restrict__ gate_sum) {
    int tid = threadIdx.x;
    int w = tid >> 6, l = tid & 63;
    int t = blockIdx.x * 4 + w;
    int e = l & 7, g = l >> 3;
    const float* xr = hn + (size_t)t * DMODEL;
    const float* wp = Wgate + l;
    float acc = 0.f;
    #pragma unroll 8
    for (int kk = 0; kk < 128; kk++)
        acc += xr[g + 8 * kk] * wp[64 * kk];
    // reduce over g (lanes sharing l&7)
    #pragma unroll
    for (int o = 8; o < 64; o <<= 1) acc += __shfl_xor(acc, o, 64);
    // softmax over e within each 8-lane group
    float m = acc;
    #pragma unroll
    for (int o = 1; o < 8; o <<= 1) m = fmaxf(m, __shfl_xor(m, o, 64));
    float p = __expf(acc - m);
    float s = p;
    #pragma unroll
    for (int o = 1; o < 8; o <<= 1) s += __shfl_xor(s, o, 64);
    float pr = p / s;
    if (l < 8) atomicAdd(&gate_sum[e], pr);
    // top-2 with tie -> lower e (jax top_k semantics)
    unsigned long long key = ((unsigned long long)__float_as_uint(pr) << 32) | (unsigned)(7 - e);
    unsigned long long k1 = key;
    #pragma unroll
    for (int o = 1; o < 8; o <<= 1) { unsigned long long t2 = __shfl_xor(k1, o, 64); if (t2 > k1) k1 = t2; }
    int e1 = 7 - (int)(k1 & 7);
    float v1 = __uint_as_float((unsigned)(k1 >> 32));
    unsigned long long key2 = (e == e1) ? 0ull : key;
    unsigned long long k2 = key2;
    #pragma unroll
    for (int o = 1; o < 8; o <<= 1) { unsigned long long t2 = __shfl_xor(k2, o, 64); if (t2 > k2) k2 = t2; }
    int e2 = 7 - (int)(k2 & 7);
    float v2 = __uint_as_float((unsigned)(k2 >> 32));
    if (l == 0) {
        wfull[t * 8 + e1] = v1;
        wfull[t * 8 + e2] = v2;
    }
}

// ---------------- per-expert top-CAP via bitonic sort ----------------
__global__ __launch_bounds__(1024) void expert_select_kernel(const float* __restrict__ wfull,
                                                             float* __restrict__ sw,
                                                             int* __restrict__ sidx,
                                                             int* __restrict__ slot) {
    __shared__ unsigned long long keys[2048];
    int e = blockIdx.x;
    int t = threadIdx.x;
    for (int i = t; i < 2048; i += 1024) {
        float w = wfull[i * 8 + e];
        unsigned int wb = __float_as_uint(w);
        keys[i] = ((unsigned long long)wb << 32) | (unsigned long long)(0xFFFFFFFFu - (unsigned int)i);
    }
    __syncthreads();
    for (int k = 2; k <= 2048; k <<= 1) {
        for (int j = k >> 1; j > 0; j >>= 1) {
            for (int i = t; i < 2048; i += 1024) {
                int ixj = i ^ j;
                if (ixj > i) {
                    bool desc = ((i & k) == 0);
                    unsigned long long a = keys[i], b = keys[ixj];
                    if ((a < b) == desc) { keys[i] = b; keys[ixj] = a; }
                }
            }
            __syncthreads();
        }
    }
    if (t < CAP) {
        unsigned long long kk = keys[t];
        float w = __uint_as_float((unsigned int)(kk >> 32));
        int idx = (int)(0xFFFFFFFFu - (unsigned int)(kk & 0xFFFFFFFFu));
        sw[e * CAP + t] = w;
        sidx[e * CAP + t] = idx;
        if (w > 0.f) slot[idx * 8 + e] = t;
    }
}

// ---------------- gather tokens -> bf16 ----------------
__global__ __launch_bounds__(256) void gather_tok_kernel(const float* __restrict__ hn,
                                                         const int* __restrict__ sidx,
                                                         const float* __restrict__ sw,
                                                         unsigned short* __restrict__ tok) {
    int ec = blockIdx.x;
    int tid = threadIdx.x;
    float w = sw[ec];
    int src = sidx[ec];
    const float* s = hn + (size_t)src * DMODEL;
    unsigned short* d = tok + (size_t)ec * DMODEL;
    for (int i = tid; i < DMODEL; i += 256) d[i] = (w > 0.f) ? f2bf(s[i]) : 0;
}

// ---------------- final combine ----------------
__global__ __launch_bounds__(256) void combine_kernel(const float* __restrict__ h,
                                                      const float* __restrict__ out_e,
                                                      const int* __restrict__ slot,
                                                      const float* __restrict__ wfull,
                                                      const float* __restrict__ gate_sum,
                                                      float* __restrict__ out) {
    int t = blockIdx.x;
    int tid = threadIdx.x;
    for (int d = tid; d < DMODEL; d += 256) {
        float acc = h[(size_t)t * DMODEL + d];
        #pragma unroll
        for (int e = 0; e < 8; e++) {
            int c = slot[t * 8 + e];
            if (c >= 0) acc += wfull[t * 8 + e] * out_e[((size_t)(e * CAP + c)) * DMODEL + d];
        }
        out[(size_t)t * DMODEL + d] = acc;
    }
    if (t == 0 && tid == 0) {
        float a = 0.f;
        #pragma unroll
        for (int e = 0; e < 8; e++) { float m = gate_sum[e] / (float)T_TOK; a += m * m; }
        out[(size_t)T_TOK * DMODEL] = 8.0f * a;
    }
}

extern "C" void kernel_launch(void* const* d_in, const int* in_sizes, int n_in,
                              void* d_out, int out_size, void* d_ws, size_t ws_size,
                              hipStream_t stream) {
    const float* x     = (const float*)d_in[0];
    const int*   gtm   = (const int*)d_in[2];
    const float* Wq    = (const float*)d_in[3];
    const float* Wk    = (const float*)d_in[4];
    const float* Wv    = (const float*)d_in[5];
    const float* Wo    = (const float*)d_in[6];
    const float* g1    = (const float*)d_in[7];
    const float* g2    = (const float*)d_in[8];
    const float* Wgate = (const float*)d_in[9];
    const float* W1    = (const float*)d_in[10];
    const float* W2    = (const float*)d_in[11];
    float* out = (float*)d_out;

    char* ws = (char*)d_ws;
    unsigned short* WT32 = (unsigned short*)(ws + 0);
    unsigned short* Qh   = (unsigned short*)(ws + 0);           // 4.2 MB
    unsigned short* Ql   = (unsigned short*)(ws + 4194304);     // 4.2 MB
    unsigned short* Kh   = (unsigned short*)(ws + 8388608);     // 4.2 MB
    unsigned short* Kl   = (unsigned short*)(ws + 12582912);    // 4.2 MB
    unsigned short* Vtb  = (unsigned short*)(ws + 16777216);    // 4.2 MB
    unsigned short* WqkvT = (unsigned short*)(ws + 33554432);   // 6.3 MB
    unsigned short* WoT   = (unsigned short*)(ws + 39845888);   // 2.1 MB
    unsigned short* xn    = (unsigned short*)(ws + 41943040);   // 4.2 MB
    unsigned short* attno = (unsigned short*)(ws + 46137344);   // 4.2 MB
    float* qkvb  = (float*)(ws + 50331648);                     // 25.2 MB
    float* oute  = (float*)(ws + 50331648);                     // 8.4 MB (MoE phase, qkvb dead)
    unsigned short* act = (unsigned short*)(ws + 33554432);     // 16.8 MB (MoE phase)
    float* hb    = (float*)(ws + 75497472);                     // 8.4 MB
    float* hnb   = (float*)(ws + 83886080);                     // 8.4 MB
    unsigned short* tok = (unsigned short*)(ws + 92274688);     // 4.2 MB
    float* ropec = (float*)(ws + 96468992);
    float* ropes = (float*)(ws + 96600064);
    float* wfull = (float*)(ws + 96731136);
    int*   slot  = (int*)(ws + 96796672);
    float* sw    = (float*)(ws + 96862208);
    int*   sidx  = (int*)(ws + 96870400);
    float* gsum  = (float*)(ws + 96878592);

    rope_table_kernel<<<S_LEN, 32, 0, stream>>>(ropec, ropes);
    rmsnorm_kernel<1><<<T_TOK, 256, 0, stream>>>(x, g1, xn);

    transpose_bf16<<<dim3(16, 16, 1), 256, 0, stream>>>(Wq, WqkvT, 1024, 1024, 0, 0);
    transpose_bf16<<<dim3(16, 16, 1), 256, 0, stream>>>(Wk, WqkvT + 1024 * 1024, 1024, 1024, 0, 0);
    transpose_bf16<<<dim3(16, 16, 1), 256, 0, stream>>>(Wv, WqkvT + 2048 * 1024, 1024, 1024, 0, 0);
    transpose_bf16<<<dim3(16, 16, 1), 256, 0, stream>>>(Wo, WoT, 1024, 1024, 0, 0);

    // QKV: qkvb(2048,3072) = xn @ [Wq|Wk|Wv]
    gemm_mfma<128, 0><<<dim3(24, 16, 1), 256, 0, stream>>>(
        xn, WqkvT, nullptr, qkvb, 1024, 1024, 3072, 0, 0, 0);

    rope_cvt_kernel<<<T_TOK, 512, 0, stream>>>(qkvb, ropec, ropes, Qh, Ql, Kh, Kl);
    vt_cvt_kernel<<<dim3(32, 32, 1), 256, 0, stream>>>(qkvb, Vtb);

    attn_mfma_kernel<<<dim3(8, 16, 2), 256, 0, stream>>>(Qh, Ql, Kh, Kl, Vtb, gtm, attno);

    // h = x + attno @ Wo
    gemm_mfma<128, 1><<<dim3(8, 16, 1), 256, 0, stream>>>(
        attno, WoT, x, hb, 1024, 1024, 1024, 0, 0, 0);
    rmsnorm_kernel<0><<<T_TOK, 256, 0, stream>>>(hb, g2, hnb);

    hipMemsetAsync(wfull, 0, (size_t)T_TOK * NE * 4, stream);
    hipMemsetAsync(slot, 0xFF, (size_t)T_TOK * NE * 4, stream);
    hipMemsetAsync(gsum, 0, 8 * 4, stream);

    gate_kernel<<<T_TOK / 4, 256, 0, stream>>>(hnb, Wgate, wfull, gsum);
    expert_select_kernel<<<NE, 1024, 0, stream>>>(wfull, sw, sidx, slot);
    gather_tok_kernel<<<NE * CAP, 256, 0, stream>>>(hnb, sidx, sw, tok);

    // MoE W1 + SwiGLU, chunked over DFF in 4 pieces of 1024 cols
    for (int c = 0; c < 4; c++) {
        transpose_bf16<<<dim3(16, 16, 8), 256, 0, stream>>>(
            W1 + (size_t)c * 1024, WT32, 8192, 1024,
            (long long)1024 * 8192, (long long)2 * 1024 * 1024);
        transpose_bf16<<<dim3(16, 16, 8), 256, 0, stream>>>(
            W1 + 4096 + (size_t)c * 1024, WT32 + 1024 * 1024, 8192, 1024,
            (long long)1024 * 8192, (long long)2 * 1024 * 1024);
        gemm_w1_swiglu<<<dim3(16, 2, 8), 256, 0, stream>>>(
            tok, WT32, act + (size_t)c * 1024,
            (long long)CAP * 1024, (long long)2 * 1024 * 1024, (long long)CAP * 4096);
    }

    // MoE W2, split-K in 2 chunks of 2048
    for (int c = 0; c < 2; c++) {
        transpose_bf16<<<dim3(16, 32, 8), 256, 0, stream>>>(
            W2 + (size_t)c * 2048 * 1024, WT32, 1024, 2048,
            (long long)4096 * 1024, (long long)1024 * 2048);
        if (c == 0)
            gemm_mfma<64, 0><<<dim3(16, 2, 8), 256, 0, stream>>>(
                act, WT32, nullptr, oute, 2048, 4096, 1024,
                (long long)CAP * 4096, (long long)1024 * 2048, (long long)CAP * 1024);
        else
            gemm_mfma<64, 2><<<dim3(16, 2, 8), 256, 0, stream>>>(
                act + 2048, WT32, nullptr, oute, 2048, 4096, 1024,
                (long long)CAP * 4096, (long long)1024 * 2048, (long long)CAP * 1024);
    }

    combine_kernel<<<T_TOK, 256, 0, stream>>>(hb, oute, slot, wfull, gsum, out);
}

// Round 6
// 492.380 us; speedup vs baseline: 4.5804x; 1.0955x over previous
//
#include <hip/hip_runtime.h>
#include <hip/hip_bf16.h>
#include <math.h>

#define T_TOK 2048
#define DMODEL 1024
#define NH 16
#define HD 64
#define S_LEN 1024
#define NE 8
#define CAP 256
#define DFF 4096

typedef __attribute__((ext_vector_type(8))) short bf16x8;
typedef __attribute__((ext_vector_type(4))) float f32x4;

__device__ inline unsigned short f2bf(float f) {
    union { float f; unsigned int u; } x; x.f = f;
    unsigned int u = x.u;
    unsigned int r = (u + 0x7FFFu + ((u >> 16) & 1u)) >> 16;
    return (unsigned short)r;
}

__device__ inline float bf2f(unsigned short h) {
    union { unsigned int u; float f; } x; x.u = (unsigned int)h << 16; return x.f;
}

__device__ inline void gload16(const void* g, void* l) {
    __builtin_amdgcn_global_load_lds(
        (const __attribute__((address_space(1))) unsigned int*)g,
        (__attribute__((address_space(3))) unsigned int*)l, 16, 0, 0);
}

// ---------------- RoPE table ----------------
__global__ void rope_table_kernel(float* __restrict__ rc, float* __restrict__ rs) {
    int s = blockIdx.x;
    int i = threadIdx.x;
    float invf = powf(10000.0f, -(float)(2 * i) / 64.0f);
    float ang = (float)s * invf;
    rc[s * 32 + i] = cosf(ang);
    rs[s * 32 + i] = sinf(ang);
}

// ---------------- RMSNorm (OUTBF: 1 -> bf16 out, 0 -> f32 out) ----------------
template <int OUTBF>
__global__ __launch_bounds__(256) void rmsnorm_kernel(const float* __restrict__ x,
                                                      const float* __restrict__ g,
                                                      void* __restrict__ yv) {
    __shared__ float red[256];
    int t = blockIdx.x;
    int tid = threadIdx.x;
    const float* xr = x + (size_t)t * DMODEL;
    float ss = 0.f;
    for (int d = tid; d < DMODEL; d += 256) { float v = xr[d]; ss += v * v; }
    red[tid] = ss; __syncthreads();
    for (int o = 128; o > 0; o >>= 1) { if (tid < o) red[tid] += red[tid + o]; __syncthreads(); }
    float scale = 1.0f / sqrtf(red[0] / (float)DMODEL + 1e-6f);
    if (OUTBF) {
        unsigned short* yr = (unsigned short*)yv + (size_t)t * DMODEL;
        for (int d = tid; d < DMODEL; d += 256) yr[d] = f2bf(g[d] * xr[d] * scale);
    } else {
        float* yr = (float*)yv + (size_t)t * DMODEL;
        for (int d = tid; d < DMODEL; d += 256) yr[d] = g[d] * xr[d] * scale;
    }
}

// ---------------- transpose+convert: dst_bf16(C,R) = src_f32(R,C)^T (QKV/Wo only) ----------------
__global__ __launch_bounds__(256) void transpose_bf16(const float* __restrict__ src,
                                                      unsigned short* __restrict__ dst,
                                                      int ldS, int ldD,
                                                      long long sS, long long sD) {
    __shared__ float tile[64][65];
    src += (long long)blockIdx.z * sS;
    dst += (long long)blockIdx.z * sD;
    int c0 = blockIdx.x * 64, r0 = blockIdx.y * 64;
    int tr = threadIdx.x >> 4;
    int tc4 = (threadIdx.x & 15) * 4;
    #pragma unroll
    for (int j = 0; j < 4; j++) {
        float4 v = *(const float4*)&src[(size_t)(r0 + tr + j * 16) * ldS + c0 + tc4];
        tile[tr + j * 16][tc4 + 0] = v.x;
        tile[tr + j * 16][tc4 + 1] = v.y;
        tile[tr + j * 16][tc4 + 2] = v.z;
        tile[tr + j * 16][tc4 + 3] = v.w;
    }
    __syncthreads();
    int oc = threadIdx.x >> 3;
    int or8 = (threadIdx.x & 7) * 8;
    #pragma unroll
    for (int j = 0; j < 2; j++) {
        int c = oc + j * 32;
        unsigned short tmp[8];
        #pragma unroll
        for (int u = 0; u < 8; u++) tmp[u] = f2bf(tile[or8 + u][c]);
        *(uint4*)&dst[(size_t)(c0 + c) * ldD + r0 + or8] = *(uint4*)tmp;
    }
}

// ---------------- bf16 MFMA GEMM: C(f32) = A(M,K)bf16 @ BT(N,K)bf16^T ----------------
template <int BN, int RES>
__global__ __launch_bounds__(256) void gemm_mfma(const unsigned short* __restrict__ A,
                                                 const unsigned short* __restrict__ BT,
                                                 const float* __restrict__ Rr,
                                                 float* __restrict__ C,
                                                 int K, int lda, int ldc,
                                                 long long sA, long long sB, long long sC) {
    constexpr int BM = 128, BK = 64;
    constexpr int NF = BN / 32;
    __shared__ unsigned short As[BM * BK];
    __shared__ unsigned short Bs[BN * BK];
    A += (long long)blockIdx.z * sA;
    BT += (long long)blockIdx.z * sB;
    C += (long long)blockIdx.z * sC;
    const int tid = threadIdx.x;
    const int lane = tid & 63;
    const int wid = tid >> 6;
    const int wr = wid >> 1, wc = wid & 1;
    const int bx = blockIdx.x * BN, by = blockIdx.y * BM;

    f32x4 acc[4][NF] = {};

    for (int k0 = 0; k0 < K; k0 += BK) {
        #pragma unroll
        for (int i = 0; i < (BM * 8) / 256; i++) {
            int c = i * 256 + tid;
            int row = c >> 3, slot = c & 7;
            int gs = slot ^ (row & 7);
            gload16(A + (size_t)(by + row) * lda + k0 + gs * 8, &As[c * 8]);
        }
        #pragma unroll
        for (int i = 0; i < (BN * 8) / 256; i++) {
            int c = i * 256 + tid;
            int row = c >> 3, slot = c & 7;
            int gs = slot ^ (row & 7);
            gload16(BT + (size_t)(bx + row) * K + k0 + gs * 8, &Bs[c * 8]);
        }
        __syncthreads();
        #pragma unroll
        for (int ks = 0; ks < 2; ks++) {
            bf16x8 af[4], bfr[NF];
            #pragma unroll
            for (int m = 0; m < 4; m++) {
                int row = wr * 64 + m * 16 + (lane & 15);
                int slot = (ks * 4 + (lane >> 4)) ^ (row & 7);
                af[m] = *(const bf16x8*)&As[row * 64 + slot * 8];
            }
            #pragma unroll
            for (int n = 0; n < NF; n++) {
                int row = wc * (BN / 2) + n * 16 + (lane & 15);
                int slot = (ks * 4 + (lane >> 4)) ^ (row & 7);
                bfr[n] = *(const bf16x8*)&Bs[row * 64 + slot * 8];
            }
            #pragma unroll
            for (int m = 0; m < 4; m++)
                #pragma unroll
                for (int n = 0; n < NF; n++)
                    acc[m][n] = __builtin_amdgcn_mfma_f32_16x16x32_bf16(af[m], bfr[n], acc[m][n], 0, 0, 0);
        }
        __syncthreads();
    }
    #pragma unroll
    for (int m = 0; m < 4; m++) {
        int row0 = by + wr * 64 + m * 16 + (lane >> 4) * 4;
        #pragma unroll
        for (int n = 0; n < NF; n++) {
            int col = bx + wc * (BN / 2) + n * 16 + (lane & 15);
            #pragma unroll
            for (int r = 0; r < 4; r++) {
                size_t idx = (size_t)(row0 + r) * ldc + col;
                float v = acc[m][n][r];
                if (RES == 1) v += Rr[idx];
                if (RES == 2) v += C[idx];
                C[idx] = v;
            }
        }
    }
}

// ---------------- fused MoE W1 GEMM + SwiGLU: reads f32 W1 (K,N) directly ----------------
// BM=256 (all CAP rows), BN=32 per half, BK=64. B staged f32 with bit4(n)^((k>>3)&1) swizzle.
__global__ __launch_bounds__(256) void gemm_w1_fused(const unsigned short* __restrict__ tok,
                                                     const float* __restrict__ W1,
                                                     unsigned short* __restrict__ act) {
    __shared__ unsigned short As[256 * 64];
    __shared__ float B1s[64 * 32];
    __shared__ float B2s[64 * 32];
    const int e = blockIdx.y;
    const int bx = blockIdx.x * 32;
    const unsigned short* A = tok + (size_t)e * CAP * DMODEL;
    const float* B = W1 + (size_t)e * DMODEL * (2 * DFF);
    unsigned short* C = act + (size_t)e * CAP * DFF;
    const int tid = threadIdx.x, l = tid & 63, wid = tid >> 6;
    const int g = l >> 4;

    f32x4 acc1[4][2] = {};
    f32x4 acc2[4][2] = {};

    for (int k0 = 0; k0 < DMODEL; k0 += 64) {
        #pragma unroll
        for (int i = 0; i < 8; i++) {
            int c = i * 256 + tid;
            int row = c >> 3, sl = c & 7, gs = sl ^ (row & 7);
            gload16(A + (size_t)row * DMODEL + k0 + gs * 8, &As[c * 8]);
        }
        #pragma unroll
        for (int i = 0; i < 2; i++) {
            int c = i * 256 + tid;
            int kb = c >> 3, sl = c & 7;
            int ssl = sl ^ (((kb >> 3) & 1) << 2);
            gload16(B + (size_t)(k0 + kb) * (2 * DFF) + bx + ssl * 4, &B1s[c * 4]);
            gload16(B + (size_t)(k0 + kb) * (2 * DFF) + DFF + bx + ssl * 4, &B2s[c * 4]);
        }
        __syncthreads();
        #pragma unroll
        for (int ks = 0; ks < 2; ks++) {
            bf16x8 af[4];
            #pragma unroll
            for (int m = 0; m < 4; m++) {
                int row = wid * 64 + m * 16 + (l & 15);
                int sl = (ks * 4 + g) ^ (row & 7);
                af[m] = *(const bf16x8*)&As[row * 64 + sl * 8];
            }
            #pragma unroll
            for (int nf = 0; nf < 2; nf++) {
                int nsw = (nf * 16 + (l & 15)) ^ ((g & 1) << 4);
                bf16x8 b1, b2;
                unsigned int* p1 = (unsigned int*)&b1;
                unsigned int* p2 = (unsigned int*)&b2;
                #pragma unroll
                for (int u = 0; u < 4; u++) {
                    int k_ = ks * 32 + g * 8 + u * 2;
                    float a0 = B1s[k_ * 32 + nsw], a1 = B1s[(k_ + 1) * 32 + nsw];
                    p1[u] = ((unsigned)f2bf(a1) << 16) | f2bf(a0);
                    float c0 = B2s[k_ * 32 + nsw], c1 = B2s[(k_ + 1) * 32 + nsw];
                    p2[u] = ((unsigned)f2bf(c1) << 16) | f2bf(c0);
                }
                #pragma unroll
                for (int m = 0; m < 4; m++) {
                    acc1[m][nf] = __builtin_amdgcn_mfma_f32_16x16x32_bf16(af[m], b1, acc1[m][nf], 0, 0, 0);
                    acc2[m][nf] = __builtin_amdgcn_mfma_f32_16x16x32_bf16(af[m], b2, acc2[m][nf], 0, 0, 0);
                }
            }
        }
        __syncthreads();
    }
    #pragma unroll
    for (int m = 0; m < 4; m++) {
        int row0 = wid * 64 + m * 16 + (l >> 4) * 4;
        #pragma unroll
        for (int nf = 0; nf < 2; nf++) {
            int col = bx + nf * 16 + (l & 15);
            #pragma unroll
            for (int r = 0; r < 4; r++) {
                float h1 = acc1[m][nf][r], h2 = acc2[m][nf][r];
                float sil = h2 / (1.0f + __expf(-h2));
                C[(size_t)(row0 + r) * DFF + col] = f2bf(h1 * sil);
            }
        }
    }
}

// ---------------- fused MoE W2 GEMM: reads f32 W2 (K,N) directly, single pass K=4096 ----------------
__global__ __launch_bounds__(256) void gemm_w2_fused(const unsigned short* __restrict__ act,
                                                     const float* __restrict__ W2,
                                                     float* __restrict__ oute) {
    __shared__ unsigned short As[256 * 64];
    __shared__ float Bs[64 * 32];
    const int e = blockIdx.y;
    const int bx = blockIdx.x * 32;
    const unsigned short* A = act + (size_t)e * CAP * DFF;
    const float* B = W2 + (size_t)e * DFF * DMODEL;
    float* C = oute + (size_t)e * CAP * DMODEL;
    const int tid = threadIdx.x, l = tid & 63, wid = tid >> 6;
    const int g = l >> 4;

    f32x4 acc[4][2] = {};

    for (int k0 = 0; k0 < DFF; k0 += 64) {
        #pragma unroll
        for (int i = 0; i < 8; i++) {
            int c = i * 256 + tid;
            int row = c >> 3, sl = c & 7, gs = sl ^ (row & 7);
            gload16(A + (size_t)row * DFF + k0 + gs * 8, &As[c * 8]);
        }
        #pragma unroll
        for (int i = 0; i < 2; i++) {
            int c = i * 256 + tid;
            int kb = c >> 3, sl = c & 7;
            int ssl = sl ^ (((kb >> 3) & 1) << 2);
            gload16(B + (size_t)(k0 + kb) * DMODEL + bx + ssl * 4, &Bs[c * 4]);
        }
        __syncthreads();
        #pragma unroll
        for (int ks = 0; ks < 2; ks++) {
            bf16x8 af[4];
            #pragma unroll
            for (int m = 0; m < 4; m++) {
                int row = wid * 64 + m * 16 + (l & 15);
                int sl = (ks * 4 + g) ^ (row & 7);
                af[m] = *(const bf16x8*)&As[row * 64 + sl * 8];
            }
            #pragma unroll
            for (int nf = 0; nf < 2; nf++) {
                int nsw = (nf * 16 + (l & 15)) ^ ((g & 1) << 4);
                bf16x8 bfr;
                unsigned int* p1 = (unsigned int*)&bfr;
                #pragma unroll
                for (int u = 0; u < 4; u++) {
                    int k_ = ks * 32 + g * 8 + u * 2;
                    float a0 = Bs[k_ * 32 + nsw], a1 = Bs[(k_ + 1) * 32 + nsw];
                    p1[u] = ((unsigned)f2bf(a1) << 16) | f2bf(a0);
                }
                #pragma unroll
                for (int m = 0; m < 4; m++)
                    acc[m][nf] = __builtin_amdgcn_mfma_f32_16x16x32_bf16(af[m], bfr, acc[m][nf], 0, 0, 0);
            }
        }
        __syncthreads();
    }
    #pragma unroll
    for (int m = 0; m < 4; m++) {
        int row0 = wid * 64 + m * 16 + (l >> 4) * 4;
        #pragma unroll
        for (int nf = 0; nf < 2; nf++) {
            int col = bx + nf * 16 + (l & 15);
            #pragma unroll
            for (int r = 0; r < 4; r++)
                C[(size_t)(row0 + r) * DMODEL + col] = acc[m][nf][r];
        }
    }
}

// ---------------- RoPE + convert to hi/lo bf16 pairs, head-major ----------------
__global__ __launch_bounds__(512) void rope_cvt_kernel(const float* __restrict__ qkv,
                                                       const float* __restrict__ rc,
                                                       const float* __restrict__ rs,
                                                       unsigned short* __restrict__ Qh,
                                                       unsigned short* __restrict__ Ql,
                                                       unsigned short* __restrict__ Kh,
                                                       unsigned short* __restrict__ Kl) {
    int t = blockIdx.x;
    int b = t >> 10, s = t & 1023;
    int hh = threadIdx.x >> 5, i = threadIdx.x & 31;
    float c = rc[s * 32 + i], sn = rs[s * 32 + i];
    size_t base = (size_t)t * 3072 + hh * 64;
    float qa = qkv[base + i], qb_ = qkv[base + i + 32];
    float ka = qkv[base + 1024 + i], kb_ = qkv[base + 1024 + i + 32];
    size_t ob = ((size_t)(b * 16 + hh) * 1024 + s) * 64;
    float q0 = (qa * c - qb_ * sn) * 0.125f;
    float q1 = (qb_ * c + qa * sn) * 0.125f;
    float k0 = ka * c - kb_ * sn;
    float k1 = kb_ * c + ka * sn;
    unsigned short h0, h1;
    h0 = f2bf(q0); Qh[ob + i] = h0;      Ql[ob + i] = f2bf(q0 - bf2f(h0));
    h1 = f2bf(q1); Qh[ob + i + 32] = h1; Ql[ob + i + 32] = f2bf(q1 - bf2f(h1));
    h0 = f2bf(k0); Kh[ob + i] = h0;      Kl[ob + i] = f2bf(k0 - bf2f(h0));
    h1 = f2bf(k1); Kh[ob + i + 32] = h1; Kl[ob + i + 32] = f2bf(k1 - bf2f(h1));
}

// ---------------- V transpose+convert: qkv f32 -> Vtb bf16 [bh][d][s] ----------------
__global__ __launch_bounds__(256) void vt_cvt_kernel(const float* __restrict__ qkv,
                                                     unsigned short* __restrict__ Vtb) {
    __shared__ float tile[32][65];
    int st = blockIdx.x;
    int bh = blockIdx.y;
    int b = bh >> 4, h = bh & 15;
    int tid = threadIdx.x;
    int s0 = st * 32;
    int sr = tid >> 3, c8 = (tid & 7) * 8;
    const float* src = qkv + (size_t)(b * 1024 + s0 + sr) * 3072 + 2048 + h * 64 + c8;
    #pragma unroll
    for (int u = 0; u < 8; u++) tile[sr][c8 + u] = src[u];
    __syncthreads();
    int d = tid & 63, sj = (tid >> 6) * 8;
    unsigned short tmp[8];
    #pragma unroll
    for (int u = 0; u < 8; u++) tmp[u] = f2bf(tile[sj + u][d]);
    *(uint4*)(Vtb + ((size_t)bh * 64 + d) * 1024 + s0 + sj) = *(uint4*)tmp;
}

// ---------------- flash-style MFMA attention with hi/lo QK^T ----------------
__global__ __launch_bounds__(256) void attn_mfma_kernel(const unsigned short* __restrict__ Qh,
                                                        const unsigned short* __restrict__ Ql,
                                                        const unsigned short* __restrict__ Kh,
                                                        const unsigned short* __restrict__ Kl,
                                                        const unsigned short* __restrict__ Vtb,
                                                        const int* __restrict__ gtm,
                                                        unsigned short* __restrict__ o) {
    __shared__ unsigned short Ksh[64 * 64];
    __shared__ unsigned short Ksl[64 * 64];
    __shared__ unsigned short Vs[64 * 64];
    __shared__ unsigned short Pl[4][32 * 64];
    const int qt = blockIdx.x, h = blockIdx.y, b = blockIdx.z;
    const int bh = b * 16 + h;
    const int tid = threadIdx.x, l = tid & 63, w = tid >> 6;
    const int q0 = qt * 128 + w * 32;
    const unsigned short* Qhb = Qh + (size_t)bh * 1024 * 64;
    const unsigned short* Qlb = Ql + (size_t)bh * 1024 * 64;
    const unsigned short* Khb = Kh + (size_t)bh * 1024 * 64;
    const unsigned short* Klb = Kl + (size_t)bh * 1024 * 64;
    const unsigned short* Vbh = Vtb + (size_t)bh * 64 * 1024;
    const int* gb = gtm + b * 1024;

    bf16x8 afh[2][2], afl[2][2];
    #pragma unroll
    for (int m = 0; m < 2; m++)
        #pragma unroll
        for (int ks = 0; ks < 2; ks++) {
            size_t off = (size_t)(q0 + m * 16 + (l & 15)) * 64 + ks * 32 + (l >> 4) * 8;
            afh[m][ks] = *(const bf16x8*)(Qhb + off);
            afl[m][ks] = *(const bf16x8*)(Qlb + off);
        }

    int gqm[2];
    #pragma unroll
    for (int m = 0; m < 2; m++) {
        int bits = 0;
        #pragma unroll
        for (int r = 0; r < 4; r++)
            bits |= (gb[q0 + m * 16 + (l >> 4) * 4 + r] ? 1 : 0) << r;
        gqm[m] = bits;
    }

    f32x4 acc_o[2][4] = {};
    float m_run[2][4], l_run[2][4];
    #pragma unroll
    for (int m = 0; m < 2; m++)
        #pragma unroll
        for (int r = 0; r < 4; r++) { m_run[m][r] = -1e30f; l_run[m][r] = 0.f; }

    for (int jt = 0; jt < 16; jt++) {
        const int j0 = jt * 64;
        #pragma unroll
        for (int i = 0; i < 2; i++) {
            int c = i * 256 + tid, row = c >> 3, sl = c & 7, gs = sl ^ (row & 7);
            gload16(Khb + (size_t)(j0 + row) * 64 + gs * 8, &Ksh[c * 8]);
            gload16(Klb + (size_t)(j0 + row) * 64 + gs * 8, &Ksl[c * 8]);
            gload16(Vbh + (size_t)row * 1024 + j0 + gs * 8, &Vs[c * 8]);
        }
        __syncthreads();

        f32x4 sv[2][4] = {};
        #pragma unroll
        for (int n = 0; n < 4; n++) {
            #pragma unroll
            for (int ks = 0; ks < 2; ks++) {
                int row = n * 16 + (l & 15);
                int sl = (ks * 4 + (l >> 4)) ^ (row & 7);
                bf16x8 khf = *(const bf16x8*)&Ksh[row * 64 + sl * 8];
                bf16x8 klf = *(const bf16x8*)&Ksl[row * 64 + sl * 8];
                #pragma unroll
                for (int m = 0; m < 2; m++) {
                    sv[m][n] = __builtin_amdgcn_mfma_f32_16x16x32_bf16(afl[m][ks], khf, sv[m][n], 0, 0, 0);
                    sv[m][n] = __builtin_amdgcn_mfma_f32_16x16x32_bf16(afh[m][ks], klf, sv[m][n], 0, 0, 0);
                    sv[m][n] = __builtin_amdgcn_mfma_f32_16x16x32_bf16(afh[m][ks], khf, sv[m][n], 0, 0, 0);
                }
            }
        }

        int gk[4];
        #pragma unroll
        for (int n = 0; n < 4; n++) gk[n] = gb[j0 + n * 16 + (l & 15)];

        #pragma unroll
        for (int m = 0; m < 2; m++)
            #pragma unroll
            for (int n = 0; n < 4; n++)
                #pragma unroll
                for (int r = 0; r < 4; r++) {
                    int q = q0 + m * 16 + (l >> 4) * 4 + r;
                    int k = j0 + n * 16 + (l & 15);
                    bool allowed = ((gqm[m] >> r) & 1) || gk[n] || ((k <= q) && (q - k < 256));
                    if (!allowed) sv[m][n][r] = -1e30f;
                }

        #pragma unroll
        for (int m = 0; m < 2; m++) {
            float tm[4], corr[4], rsum[4];
            #pragma unroll
            for (int r = 0; r < 4; r++)
                tm[r] = fmaxf(fmaxf(sv[m][0][r], sv[m][1][r]), fmaxf(sv[m][2][r], sv[m][3][r]));
            #pragma unroll
            for (int wd = 1; wd <= 8; wd <<= 1)
                #pragma unroll
                for (int r = 0; r < 4; r++) tm[r] = fmaxf(tm[r], __shfl_xor(tm[r], wd, 64));
            #pragma unroll
            for (int r = 0; r < 4; r++) {
                float mn = fmaxf(m_run[m][r], tm[r]);
                corr[r] = __expf(m_run[m][r] - mn);
                m_run[m][r] = mn;
                rsum[r] = 0.f;
            }
            #pragma unroll
            for (int n = 0; n < 4; n++)
                #pragma unroll
                for (int r = 0; r < 4; r++) {
                    float p = __expf(sv[m][n][r] - m_run[m][r]);
                    sv[m][n][r] = p;
                    rsum[r] += p;
                }
            #pragma unroll
            for (int wd = 1; wd <= 8; wd <<= 1)
                #pragma unroll
                for (int r = 0; r < 4; r++) rsum[r] += __shfl_xor(rsum[r], wd, 64);
            #pragma unroll
            for (int r = 0; r < 4; r++) l_run[m][r] = l_run[m][r] * corr[r] + rsum[r];
            #pragma unroll
            for (int nd = 0; nd < 4; nd++)
                #pragma unroll
                for (int r = 0; r < 4; r++) acc_o[m][nd][r] *= corr[r];
            #pragma unroll
            for (int n = 0; n < 4; n++)
                #pragma unroll
                for (int r = 0; r < 4; r++) {
                    int qr = m * 16 + (l >> 4) * 4 + r;
                    int kc = n * 16 + (l & 15);
                    int byte = (qr * 128 + kc * 2) ^ ((qr & 7) << 4);
                    Pl[w][byte >> 1] = f2bf(sv[m][n][r]);
                }
        }

        asm volatile("s_waitcnt lgkmcnt(0)" ::: "memory");
        __builtin_amdgcn_sched_barrier(0);

        #pragma unroll
        for (int ks = 0; ks < 2; ks++) {
            bf16x8 pa[2];
            #pragma unroll
            for (int m = 0; m < 2; m++) {
                int row = m * 16 + (l & 15);
                int sl = (ks * 4 + (l >> 4)) ^ (row & 7);
                pa[m] = *(const bf16x8*)&Pl[w][row * 64 + sl * 8];
            }
            #pragma unroll
            for (int nd = 0; nd < 4; nd++) {
                int row = nd * 16 + (l & 15);
                int sl = (ks * 4 + (l >> 4)) ^ (row & 7);
                bf16x8 vf = *(const bf16x8*)&Vs[row * 64 + sl * 8];
                #pragma unroll
                for (int m = 0; m < 2; m++)
                    acc_o[m][nd] = __builtin_amdgcn_mfma_f32_16x16x32_bf16(pa[m], vf, acc_o[m][nd], 0, 0, 0);
            }
        }
        __syncthreads();
    }

    #pragma unroll
    for (int m = 0; m < 2; m++)
        #pragma unroll
        for (int r = 0; r < 4; r++) {
            float inv = 1.0f / l_run[m][r];
            int t_ = b * 1024 + q0 + m * 16 + (l >> 4) * 4 + r;
            #pragma unroll
            for (int nd = 0; nd < 4; nd++) {
                int col = h * 64 + nd * 16 + (l & 15);
                o[(size_t)t_ * 1024 + col] = f2bf(acc_o[m][nd][r] * inv);
            }
        }
}

// ---------------- gate v2: one wave per token, register-only ----------------
__global__ __launch_bounds__(256) void gate_kernel(const float* __restrict__ hn,
                                                   const float* __restrict__ Wgate,
                                                   float* __restrict__ wfull,
                                                   float* __restrict__ gate_sum) {
    int tid = threadIdx.x;
    int w = tid >> 6, l = tid & 63;
    int t = blockIdx.x * 4 + w;
    int e = l & 7, g = l >> 3;
    const float* xr = hn + (size_t)t * DMODEL;
    const float* wp = Wgate + l;
    float acc = 0.f;
    #pragma unroll 8
    for (int kk = 0; kk < 128; kk++)
        acc += xr[g + 8 * kk] * wp[64 * kk];
    #pragma unroll
    for (int o = 8; o < 64; o <<= 1) acc += __shfl_xor(acc, o, 64);
    float m = acc;
    #pragma unroll
    for (int o = 1; o < 8; o <<= 1) m = fmaxf(m, __shfl_xor(m, o, 64));
    float p = __expf(acc - m);
    float s = p;
    #pragma unroll
    for (int o = 1; o < 8; o <<= 1) s += __shfl_xor(s, o, 64);
    float pr = p / s;
    if (l < 8) atomicAdd(&gate_sum[e], pr);
    unsigned long long key = ((unsigned long long)__float_as_uint(pr) << 32) | (unsigned)(7 - e);
    unsigned long long k1 = key;
    #pragma unroll
    for (int o = 1; o < 8; o <<= 1) { unsigned long long t2 = __shfl_xor(k1, o, 64); if (t2 > k1) k1 = t2; }
    int e1 = 7 - (int)(k1 & 7);
    float v1 = __uint_as_float((unsigned)(k1 >> 32));
    unsigned long long key2 = (e == e1) ? 0ull : key;
    unsigned long long k2 = key2;
    #pragma unroll
    for (int o = 1; o < 8; o <<= 1) { unsigned long long t2 = __shfl_xor(k2, o, 64); if (t2 > k2) k2 = t2; }
    int e2 = 7 - (int)(k2 & 7);
    float v2 = __uint_as_float((unsigned)(k2 >> 32));
    if (l == 0) {
        wfull[t * 8 + e1] = v1;
        wfull[t * 8 + e2] = v2;
    }
}

// ---------------- per-expert top-CAP via bitonic sort ----------------
__global__ __launch_bounds__(1024) void expert_select_kernel(const float* __restrict__ wfull,
                                                             float* __restrict__ sw,
                                                             int* __restrict__ sidx,
                                                             int* __restrict__ slot) {
    __shared__ unsigned long long keys[2048];
    int e = blockIdx.x;
    int t = threadIdx.x;
    for (int i = t; i < 2048; i += 1024) {
        float w = wfull[i * 8 + e];
        unsigned int wb = __float_as_uint(w);
        keys[i] = ((unsigned long long)wb << 32) | (unsigned long long)(0xFFFFFFFFu - (unsigned int)i);
    }
    __syncthreads();
    for (int k = 2; k <= 2048; k <<= 1) {
        for (int j = k >> 1; j > 0; j >>= 1) {
            for (int i = t; i < 2048; i += 1024) {
                int ixj = i ^ j;
                if (ixj > i) {
                    bool desc = ((i & k) == 0);
                    unsigned long long a = keys[i], b = keys[ixj];
                    if ((a < b) == desc) { keys[i] = b; keys[ixj] = a; }
                }
            }
            __syncthreads();
        }
    }
    if (t < CAP) {
        unsigned long long kk = keys[t];
        float w = __uint_as_float((unsigned int)(kk >> 32));
        int idx = (int)(0xFFFFFFFFu - (unsigned int)(kk & 0xFFFFFFFFu));
        sw[e * CAP + t] = w;
        sidx[e * CAP + t] = idx;
        if (w > 0.f) slot[idx * 8 + e] = t;
    }
}

// ---------------- gather tokens -> bf16 ----------------
__global__ __launch_bounds__(256) void gather_tok_kernel(const float* __restrict__ hn,
                                                         const int* __restrict__ sidx,
                                                         const float* __restrict__ sw,
                                                         unsigned short* __restrict__ tok) {
    int ec = blockIdx.x;
    int tid = threadIdx.x;
    float w = sw[ec];
    int src = sidx[ec];
    const float* s = hn + (size_t)src * DMODEL;
    unsigned short* d = tok + (size_t)ec * DMODEL;
    for (int i = tid; i < DMODEL; i += 256) d[i] = (w > 0.f) ? f2bf(s[i]) : 0;
}

// ---------------- final combine ----------------
__global__ __launch_bounds__(256) void combine_kernel(const float* __restrict__ h,
                                                      const float* __restrict__ out_e,
                                                      const int* __restrict__ slot,
                                                      const float* __restrict__ wfull,
                                                      const float* __restrict__ gate_sum,
                                                      float* __restrict__ out) {
    int t = blockIdx.x;
    int tid = threadIdx.x;
    for (int d = tid; d < DMODEL; d += 256) {
        float acc = h[(size_t)t * DMODEL + d];
        #pragma unroll
        for (int e = 0; e < 8; e++) {
            int c = slot[t * 8 + e];
            if (c >= 0) acc += wfull[t * 8 + e] * out_e[((size_t)(e * CAP + c)) * DMODEL + d];
        }
        out[(size_t)t * DMODEL + d] = acc;
    }
    if (t == 0 && tid == 0) {
        float a = 0.f;
        #pragma unroll
        for (int e = 0; e < 8; e++) { float m = gate_sum[e] / (float)T_TOK; a += m * m; }
        out[(size_t)T_TOK * DMODEL] = 8.0f * a;
    }
}

extern "C" void kernel_launch(void* const* d_in, const int* in_sizes, int n_in,
                              void* d_out, int out_size, void* d_ws, size_t ws_size,
                              hipStream_t stream) {
    const float* x     = (const float*)d_in[0];
    const int*   gtm   = (const int*)d_in[2];
    const float* Wq    = (const float*)d_in[3];
    const float* Wk    = (const float*)d_in[4];
    const float* Wv    = (const float*)d_in[5];
    const float* Wo    = (const float*)d_in[6];
    const float* g1    = (const float*)d_in[7];
    const float* g2    = (const float*)d_in[8];
    const float* Wgate = (const float*)d_in[9];
    const float* W1    = (const float*)d_in[10];
    const float* W2    = (const float*)d_in[11];
    float* out = (float*)d_out;

    char* ws = (char*)d_ws;
    unsigned short* Qh   = (unsigned short*)(ws + 0);           // 4.2 MB
    unsigned short* Ql   = (unsigned short*)(ws + 4194304);     // 4.2 MB
    unsigned short* Kh   = (unsigned short*)(ws + 8388608);     // 4.2 MB
    unsigned short* Kl   = (unsigned short*)(ws + 12582912);    // 4.2 MB
    unsigned short* Vtb  = (unsigned short*)(ws + 16777216);    // 4.2 MB
    unsigned short* WqkvT = (unsigned short*)(ws + 33554432);   // 6.3 MB
    unsigned short* WoT   = (unsigned short*)(ws + 39845888);   // 2.1 MB
    unsigned short* xn    = (unsigned short*)(ws + 41943040);   // 4.2 MB
    unsigned short* attno = (unsigned short*)(ws + 46137344);   // 4.2 MB
    float* qkvb  = (float*)(ws + 50331648);                     // 25.2 MB
    float* oute  = (float*)(ws + 50331648);                     // 8.4 MB (MoE phase, qkvb dead)
    unsigned short* act = (unsigned short*)(ws + 33554432);     // 16.8 MB (MoE phase)
    float* hb    = (float*)(ws + 75497472);                     // 8.4 MB
    float* hnb   = (float*)(ws + 83886080);                     // 8.4 MB
    unsigned short* tok = (unsigned short*)(ws + 92274688);     // 4.2 MB
    float* ropec = (float*)(ws + 96468992);
    float* ropes = (float*)(ws + 96600064);
    float* wfull = (float*)(ws + 96731136);
    int*   slot  = (int*)(ws + 96796672);
    float* sw    = (float*)(ws + 96862208);
    int*   sidx  = (int*)(ws + 96870400);
    float* gsum  = (float*)(ws + 96878592);

    rope_table_kernel<<<S_LEN, 32, 0, stream>>>(ropec, ropes);
    rmsnorm_kernel<1><<<T_TOK, 256, 0, stream>>>(x, g1, xn);

    transpose_bf16<<<dim3(16, 16, 1), 256, 0, stream>>>(Wq, WqkvT, 1024, 1024, 0, 0);
    transpose_bf16<<<dim3(16, 16, 1), 256, 0, stream>>>(Wk, WqkvT + 1024 * 1024, 1024, 1024, 0, 0);
    transpose_bf16<<<dim3(16, 16, 1), 256, 0, stream>>>(Wv, WqkvT + 2048 * 1024, 1024, 1024, 0, 0);
    transpose_bf16<<<dim3(16, 16, 1), 256, 0, stream>>>(Wo, WoT, 1024, 1024, 0, 0);

    // QKV: qkvb(2048,3072) = xn @ [Wq|Wk|Wv]
    gemm_mfma<128, 0><<<dim3(24, 16, 1), 256, 0, stream>>>(
        xn, WqkvT, nullptr, qkvb, 1024, 1024, 3072, 0, 0, 0);

    rope_cvt_kernel<<<T_TOK, 512, 0, stream>>>(qkvb, ropec, ropes, Qh, Ql, Kh, Kl);
    vt_cvt_kernel<<<dim3(32, 32, 1), 256, 0, stream>>>(qkvb, Vtb);

    attn_mfma_kernel<<<dim3(8, 16, 2), 256, 0, stream>>>(Qh, Ql, Kh, Kl, Vtb, gtm, attno);

    // h = x + attno @ Wo
    gemm_mfma<128, 1><<<dim3(8, 16, 1), 256, 0, stream>>>(
        attno, WoT, x, hb, 1024, 1024, 1024, 0, 0, 0);
    rmsnorm_kernel<0><<<T_TOK, 256, 0, stream>>>(hb, g2, hnb);

    hipMemsetAsync(wfull, 0, (size_t)T_TOK * NE * 4, stream);
    hipMemsetAsync(slot, 0xFF, (size_t)T_TOK * NE * 4, stream);
    hipMemsetAsync(gsum, 0, 8 * 4, stream);

    gate_kernel<<<T_TOK / 4, 256, 0, stream>>>(hnb, Wgate, wfull, gsum);
    expert_select_kernel<<<NE, 1024, 0, stream>>>(wfull, sw, sidx, slot);
    gather_tok_kernel<<<NE * CAP, 256, 0, stream>>>(hnb, sidx, sw, tok);

    // fused MoE GEMMs reading f32 weights directly (no transpose pass)
    gemm_w1_fused<<<dim3(128, 8, 1), 256, 0, stream>>>(tok, W1, act);
    gemm_w2_fused<<<dim3(32, 8, 1), 256, 0, stream>>>(act, W2, oute);

    combine_kernel<<<T_TOK, 256, 0, stream>>>(hb, oute, slot, wfull, gsum, out);
}

// Round 7
// 403.955 us; speedup vs baseline: 5.5831x; 1.2189x over previous
//
#include <hip/hip_runtime.h>
#include <hip/hip_bf16.h>
#include <math.h>

#define T_TOK 2048
#define DMODEL 1024
#define NH 16
#define HD 64
#define S_LEN 1024
#define NE 8
#define CAP 256
#define DFF 4096

typedef __attribute__((ext_vector_type(8))) short bf16x8;
typedef __attribute__((ext_vector_type(4))) float f32x4;

__device__ inline unsigned short f2bf(float f) {
    union { float f; unsigned int u; } x; x.f = f;
    unsigned int u = x.u;
    unsigned int r = (u + 0x7FFFu + ((u >> 16) & 1u)) >> 16;
    return (unsigned short)r;
}

__device__ inline float bf2f(unsigned short h) {
    union { unsigned int u; float f; } x; x.u = (unsigned int)h << 16; return x.f;
}

// packed f32x2 -> bf16x2 (RTNE, single v_cvt_pk_bf16_f32); lo in low 16 bits
__device__ inline unsigned int pkbf(float lo, float hi) {
    __hip_bfloat162 h2 = __float22bfloat162_rn(make_float2(lo, hi));
    unsigned int r;
    __builtin_memcpy(&r, &h2, 4);
    return r;
}

__device__ inline void gload16(const void* g, void* l) {
    __builtin_amdgcn_global_load_lds(
        (const __attribute__((address_space(1))) unsigned int*)g,
        (__attribute__((address_space(3))) unsigned int*)l, 16, 0, 0);
}

// ---------------- RoPE table ----------------
__global__ void rope_table_kernel(float* __restrict__ rc, float* __restrict__ rs) {
    int s = blockIdx.x;
    int i = threadIdx.x;
    float invf = powf(10000.0f, -(float)(2 * i) / 64.0f);
    float ang = (float)s * invf;
    rc[s * 32 + i] = cosf(ang);
    rs[s * 32 + i] = sinf(ang);
}

// ---------------- RMSNorm (OUTBF: 1 -> bf16 out, 0 -> f32 out) ----------------
template <int OUTBF>
__global__ __launch_bounds__(256) void rmsnorm_kernel(const float* __restrict__ x,
                                                      const float* __restrict__ g,
                                                      void* __restrict__ yv) {
    __shared__ float red[256];
    int t = blockIdx.x;
    int tid = threadIdx.x;
    const float* xr = x + (size_t)t * DMODEL;
    float ss = 0.f;
    for (int d = tid; d < DMODEL; d += 256) { float v = xr[d]; ss += v * v; }
    red[tid] = ss; __syncthreads();
    for (int o = 128; o > 0; o >>= 1) { if (tid < o) red[tid] += red[tid + o]; __syncthreads(); }
    float scale = 1.0f / sqrtf(red[0] / (float)DMODEL + 1e-6f);
    if (OUTBF) {
        unsigned short* yr = (unsigned short*)yv + (size_t)t * DMODEL;
        for (int d = tid; d < DMODEL; d += 256) yr[d] = f2bf(g[d] * xr[d] * scale);
    } else {
        float* yr = (float*)yv + (size_t)t * DMODEL;
        for (int d = tid; d < DMODEL; d += 256) yr[d] = g[d] * xr[d] * scale;
    }
}

// ---------------- transpose+convert: dst_bf16(C,R) = src_f32(R,C)^T (QKV/Wo only) ----------------
__global__ __launch_bounds__(256) void transpose_bf16(const float* __restrict__ src,
                                                      unsigned short* __restrict__ dst,
                                                      int ldS, int ldD,
                                                      long long sS, long long sD) {
    __shared__ float tile[64][65];
    src += (long long)blockIdx.z * sS;
    dst += (long long)blockIdx.z * sD;
    int c0 = blockIdx.x * 64, r0 = blockIdx.y * 64;
    int tr = threadIdx.x >> 4;
    int tc4 = (threadIdx.x & 15) * 4;
    #pragma unroll
    for (int j = 0; j < 4; j++) {
        float4 v = *(const float4*)&src[(size_t)(r0 + tr + j * 16) * ldS + c0 + tc4];
        tile[tr + j * 16][tc4 + 0] = v.x;
        tile[tr + j * 16][tc4 + 1] = v.y;
        tile[tr + j * 16][tc4 + 2] = v.z;
        tile[tr + j * 16][tc4 + 3] = v.w;
    }
    __syncthreads();
    int oc = threadIdx.x >> 3;
    int or8 = (threadIdx.x & 7) * 8;
    #pragma unroll
    for (int j = 0; j < 2; j++) {
        int c = oc + j * 32;
        unsigned short tmp[8];
        #pragma unroll
        for (int u = 0; u < 8; u++) tmp[u] = f2bf(tile[or8 + u][c]);
        *(uint4*)&dst[(size_t)(c0 + c) * ldD + r0 + or8] = *(uint4*)tmp;
    }
}

// ---------------- bf16 MFMA GEMM: C(f32) = A(M,K)bf16 @ BT(N,K)bf16^T ----------------
template <int BN, int RES>
__global__ __launch_bounds__(256) void gemm_mfma(const unsigned short* __restrict__ A,
                                                 const unsigned short* __restrict__ BT,
                                                 const float* __restrict__ Rr,
                                                 float* __restrict__ C,
                                                 int K, int lda, int ldc,
                                                 long long sA, long long sB, long long sC) {
    constexpr int BM = 128, BK = 64;
    constexpr int NF = BN / 32;
    __shared__ unsigned short As[BM * BK];
    __shared__ unsigned short Bs[BN * BK];
    A += (long long)blockIdx.z * sA;
    BT += (long long)blockIdx.z * sB;
    C += (long long)blockIdx.z * sC;
    const int tid = threadIdx.x;
    const int lane = tid & 63;
    const int wid = tid >> 6;
    const int wr = wid >> 1, wc = wid & 1;
    const int bx = blockIdx.x * BN, by = blockIdx.y * BM;

    f32x4 acc[4][NF] = {};

    for (int k0 = 0; k0 < K; k0 += BK) {
        #pragma unroll
        for (int i = 0; i < (BM * 8) / 256; i++) {
            int c = i * 256 + tid;
            int row = c >> 3, slot = c & 7;
            int gs = slot ^ (row & 7);
            gload16(A + (size_t)(by + row) * lda + k0 + gs * 8, &As[c * 8]);
        }
        #pragma unroll
        for (int i = 0; i < (BN * 8) / 256; i++) {
            int c = i * 256 + tid;
            int row = c >> 3, slot = c & 7;
            int gs = slot ^ (row & 7);
            gload16(BT + (size_t)(bx + row) * K + k0 + gs * 8, &Bs[c * 8]);
        }
        __syncthreads();
        #pragma unroll
        for (int ks = 0; ks < 2; ks++) {
            bf16x8 af[4], bfr[NF];
            #pragma unroll
            for (int m = 0; m < 4; m++) {
                int row = wr * 64 + m * 16 + (lane & 15);
                int slot = (ks * 4 + (lane >> 4)) ^ (row & 7);
                af[m] = *(const bf16x8*)&As[row * 64 + slot * 8];
            }
            #pragma unroll
            for (int n = 0; n < NF; n++) {
                int row = wc * (BN / 2) + n * 16 + (lane & 15);
                int slot = (ks * 4 + (lane >> 4)) ^ (row & 7);
                bfr[n] = *(const bf16x8*)&Bs[row * 64 + slot * 8];
            }
            #pragma unroll
            for (int m = 0; m < 4; m++)
                #pragma unroll
                for (int n = 0; n < NF; n++)
                    acc[m][n] = __builtin_amdgcn_mfma_f32_16x16x32_bf16(af[m], bfr[n], acc[m][n], 0, 0, 0);
        }
        __syncthreads();
    }
    #pragma unroll
    for (int m = 0; m < 4; m++) {
        int row0 = by + wr * 64 + m * 16 + (lane >> 4) * 4;
        #pragma unroll
        for (int n = 0; n < NF; n++) {
            int col = bx + wc * (BN / 2) + n * 16 + (lane & 15);
            #pragma unroll
            for (int r = 0; r < 4; r++) {
                size_t idx = (size_t)(row0 + r) * ldc + col;
                float v = acc[m][n][r];
                if (RES == 1) v += Rr[idx];
                if (RES == 2) v += C[idx];
                C[idx] = v;
            }
        }
    }
}

// ---------------- fused MoE W1 GEMM + SwiGLU: reads f32 W1 (K,N) directly ----------------
// B reg-staged: float4 f32 loads -> cvt_pk bf16 k-pairs -> swizzled (n,kp) u32 LDS tile
// write idx = n*32 + ((kp>>2)^(n&7))*4 + (kp&3); read b128 at n*32 + ((ks*4+g)^(n&7))*4
__global__ __launch_bounds__(256) void gemm_w1_fused(const unsigned short* __restrict__ tok,
                                                     const float* __restrict__ W1,
                                                     unsigned short* __restrict__ act) {
    __shared__ unsigned short As[256 * 64];   // 32 KB
    __shared__ unsigned int B1p[32 * 32];     // 4 KB
    __shared__ unsigned int B2p[32 * 32];     // 4 KB
    const int e = blockIdx.y;
    const int bx = blockIdx.x * 32;
    const unsigned short* A = tok + (size_t)e * CAP * DMODEL;
    const float* B = W1 + (size_t)e * DMODEL * (2 * DFF);
    unsigned short* C = act + (size_t)e * CAP * DFF;
    const int tid = threadIdx.x, l = tid & 63, wid = tid >> 6;
    const int g = l >> 4;
    const int kp = tid >> 3;     // 0..31 k-pair index
    const int nc = tid & 7;      // float4 chunk over 32 n
    const int chunk = kp >> 2, within = kp & 3;

    f32x4 acc1[4][2] = {};
    f32x4 acc2[4][2] = {};

    for (int k0 = 0; k0 < DMODEL; k0 += 64) {
        // A staging (async direct-to-LDS)
        #pragma unroll
        for (int i = 0; i < 8; i++) {
            int c = i * 256 + tid;
            int row = c >> 3, sl = c & 7, gs = sl ^ (row & 7);
            gload16(A + (size_t)row * DMODEL + k0 + gs * 8, &As[c * 8]);
        }
        // B reg-stage: rows k0+2kp, k0+2kp+1; cols bx+nc*4..+3 for h1 and h2
        const float* Brow = B + (size_t)(k0 + 2 * kp) * 8192 + bx + nc * 4;
        float4 a0 = *(const float4*)(Brow);
        float4 a1 = *(const float4*)(Brow + 8192);
        float4 c0 = *(const float4*)(Brow + 4096);
        float4 c1 = *(const float4*)(Brow + 4096 + 8192);
        unsigned int p1[4], p2[4];
        p1[0] = pkbf(a0.x, a1.x); p1[1] = pkbf(a0.y, a1.y);
        p1[2] = pkbf(a0.z, a1.z); p1[3] = pkbf(a0.w, a1.w);
        p2[0] = pkbf(c0.x, c1.x); p2[1] = pkbf(c0.y, c1.y);
        p2[2] = pkbf(c0.z, c1.z); p2[3] = pkbf(c0.w, c1.w);
        #pragma unroll
        for (int i = 0; i < 4; i++) {
            int n_loc = nc * 4 + i;
            int idx = n_loc * 32 + ((chunk ^ (n_loc & 7)) << 2) + within;
            B1p[idx] = p1[i];
            B2p[idx] = p2[i];
        }
        __syncthreads();
        #pragma unroll
        for (int ks = 0; ks < 2; ks++) {
            bf16x8 af[4];
            #pragma unroll
            for (int m = 0; m < 4; m++) {
                int row = wid * 64 + m * 16 + (l & 15);
                int sl = (ks * 4 + g) ^ (row & 7);
                af[m] = *(const bf16x8*)&As[row * 64 + sl * 8];
            }
            #pragma unroll
            for (int nf = 0; nf < 2; nf++) {
                int n_loc = nf * 16 + (l & 15);
                int base = n_loc * 32 + (((ks * 4 + g) ^ (n_loc & 7)) << 2);
                bf16x8 b1 = *(const bf16x8*)&B1p[base];
                bf16x8 b2 = *(const bf16x8*)&B2p[base];
                #pragma unroll
                for (int m = 0; m < 4; m++) {
                    acc1[m][nf] = __builtin_amdgcn_mfma_f32_16x16x32_bf16(af[m], b1, acc1[m][nf], 0, 0, 0);
                    acc2[m][nf] = __builtin_amdgcn_mfma_f32_16x16x32_bf16(af[m], b2, acc2[m][nf], 0, 0, 0);
                }
            }
        }
        __syncthreads();
    }
    #pragma unroll
    for (int m = 0; m < 4; m++) {
        int row0 = wid * 64 + m * 16 + (l >> 4) * 4;
        #pragma unroll
        for (int nf = 0; nf < 2; nf++) {
            int col = bx + nf * 16 + (l & 15);
            #pragma unroll
            for (int r = 0; r < 4; r++) {
                float h1 = acc1[m][nf][r], h2 = acc2[m][nf][r];
                float sil = h2 / (1.0f + __expf(-h2));
                C[(size_t)(row0 + r) * DFF + col] = f2bf(h1 * sil);
            }
        }
    }
}

// ---------------- fused MoE W2 GEMM: reads f32 W2 (K,N) directly, K=4096 ----------------
__global__ __launch_bounds__(256) void gemm_w2_fused(const unsigned short* __restrict__ act,
                                                     const float* __restrict__ W2,
                                                     float* __restrict__ oute) {
    __shared__ unsigned short As[256 * 64];   // 32 KB
    __shared__ unsigned int Bp[32 * 32];      // 4 KB
    const int e = blockIdx.y;
    const int bx = blockIdx.x * 32;
    const unsigned short* A = act + (size_t)e * CAP * DFF;
    const float* B = W2 + (size_t)e * DFF * DMODEL;
    float* C = oute + (size_t)e * CAP * DMODEL;
    const int tid = threadIdx.x, l = tid & 63, wid = tid >> 6;
    const int g = l >> 4;
    const int kp = tid >> 3;
    const int nc = tid & 7;
    const int chunk = kp >> 2, within = kp & 3;

    f32x4 acc[4][2] = {};

    for (int k0 = 0; k0 < DFF; k0 += 64) {
        #pragma unroll
        for (int i = 0; i < 8; i++) {
            int c = i * 256 + tid;
            int row = c >> 3, sl = c & 7, gs = sl ^ (row & 7);
            gload16(A + (size_t)row * DFF + k0 + gs * 8, &As[c * 8]);
        }
        const float* Brow = B + (size_t)(k0 + 2 * kp) * DMODEL + bx + nc * 4;
        float4 a0 = *(const float4*)(Brow);
        float4 a1 = *(const float4*)(Brow + DMODEL);
        unsigned int p1[4];
        p1[0] = pkbf(a0.x, a1.x); p1[1] = pkbf(a0.y, a1.y);
        p1[2] = pkbf(a0.z, a1.z); p1[3] = pkbf(a0.w, a1.w);
        #pragma unroll
        for (int i = 0; i < 4; i++) {
            int n_loc = nc * 4 + i;
            int idx = n_loc * 32 + ((chunk ^ (n_loc & 7)) << 2) + within;
            Bp[idx] = p1[i];
        }
        __syncthreads();
        #pragma unroll
        for (int ks = 0; ks < 2; ks++) {
            bf16x8 af[4];
            #pragma unroll
            for (int m = 0; m < 4; m++) {
                int row = wid * 64 + m * 16 + (l & 15);
                int sl = (ks * 4 + g) ^ (row & 7);
                af[m] = *(const bf16x8*)&As[row * 64 + sl * 8];
            }
            #pragma unroll
            for (int nf = 0; nf < 2; nf++) {
                int n_loc = nf * 16 + (l & 15);
                int base = n_loc * 32 + (((ks * 4 + g) ^ (n_loc & 7)) << 2);
                bf16x8 bfr = *(const bf16x8*)&Bp[base];
                #pragma unroll
                for (int m = 0; m < 4; m++)
                    acc[m][nf] = __builtin_amdgcn_mfma_f32_16x16x32_bf16(af[m], bfr, acc[m][nf], 0, 0, 0);
            }
        }
        __syncthreads();
    }
    #pragma unroll
    for (int m = 0; m < 4; m++) {
        int row0 = wid * 64 + m * 16 + (l >> 4) * 4;
        #pragma unroll
        for (int nf = 0; nf < 2; nf++) {
            int col = bx + nf * 16 + (l & 15);
            #pragma unroll
            for (int r = 0; r < 4; r++)
                C[(size_t)(row0 + r) * DMODEL + col] = acc[m][nf][r];
        }
    }
}

// ---------------- RoPE + convert to hi/lo bf16 pairs, head-major ----------------
__global__ __launch_bounds__(512) void rope_cvt_kernel(const float* __restrict__ qkv,
                                                       const float* __restrict__ rc,
                                                       const float* __restrict__ rs,
                                                       unsigned short* __restrict__ Qh,
                                                       unsigned short* __restrict__ Ql,
                                                       unsigned short* __restrict__ Kh,
                                                       unsigned short* __restrict__ Kl) {
    int t = blockIdx.x;
    int b = t >> 10, s = t & 1023;
    int hh = threadIdx.x >> 5, i = threadIdx.x & 31;
    float c = rc[s * 32 + i], sn = rs[s * 32 + i];
    size_t base = (size_t)t * 3072 + hh * 64;
    float qa = qkv[base + i], qb_ = qkv[base + i + 32];
    float ka = qkv[base + 1024 + i], kb_ = qkv[base + 1024 + i + 32];
    size_t ob = ((size_t)(b * 16 + hh) * 1024 + s) * 64;
    float q0 = (qa * c - qb_ * sn) * 0.125f;
    float q1 = (qb_ * c + qa * sn) * 0.125f;
    float k0 = ka * c - kb_ * sn;
    float k1 = kb_ * c + ka * sn;
    unsigned short h0, h1;
    h0 = f2bf(q0); Qh[ob + i] = h0;      Ql[ob + i] = f2bf(q0 - bf2f(h0));
    h1 = f2bf(q1); Qh[ob + i + 32] = h1; Ql[ob + i + 32] = f2bf(q1 - bf2f(h1));
    h0 = f2bf(k0); Kh[ob + i] = h0;      Kl[ob + i] = f2bf(k0 - bf2f(h0));
    h1 = f2bf(k1); Kh[ob + i + 32] = h1; Kl[ob + i + 32] = f2bf(k1 - bf2f(h1));
}

// ---------------- V transpose+convert: qkv f32 -> Vtb bf16 [bh][d][s] ----------------
__global__ __launch_bounds__(256) void vt_cvt_kernel(const float* __restrict__ qkv,
                                                     unsigned short* __restrict__ Vtb) {
    __shared__ float tile[32][65];
    int st = blockIdx.x;
    int bh = blockIdx.y;
    int b = bh >> 4, h = bh & 15;
    int tid = threadIdx.x;
    int s0 = st * 32;
    int sr = tid >> 3, c8 = (tid & 7) * 8;
    const float* src = qkv + (size_t)(b * 1024 + s0 + sr) * 3072 + 2048 + h * 64 + c8;
    #pragma unroll
    for (int u = 0; u < 8; u++) tile[sr][c8 + u] = src[u];
    __syncthreads();
    int d = tid & 63, sj = (tid >> 6) * 8;
    unsigned short tmp[8];
    #pragma unroll
    for (int u = 0; u < 8; u++) tmp[u] = f2bf(tile[sj + u][d]);
    *(uint4*)(Vtb + ((size_t)bh * 64 + d) * 1024 + s0 + sj) = *(uint4*)tmp;
}

// ---------------- flash-style MFMA attention with hi/lo QK^T ----------------
__global__ __launch_bounds__(256) void attn_mfma_kernel(const unsigned short* __restrict__ Qh,
                                                        const unsigned short* __restrict__ Ql,
                                                        const unsigned short* __restrict__ Kh,
                                                        const unsigned short* __restrict__ Kl,
                                                        const unsigned short* __restrict__ Vtb,
                                                        const int* __restrict__ gtm,
                                                        unsigned short* __restrict__ o) {
    __shared__ unsigned short Ksh[64 * 64];
    __shared__ unsigned short Ksl[64 * 64];
    __shared__ unsigned short Vs[64 * 64];
    __shared__ unsigned short Pl[4][32 * 64];
    const int qt = blockIdx.x, h = blockIdx.y, b = blockIdx.z;
    const int bh = b * 16 + h;
    const int tid = threadIdx.x, l = tid & 63, w = tid >> 6;
    const int q0 = qt * 128 + w * 32;
    const unsigned short* Qhb = Qh + (size_t)bh * 1024 * 64;
    const unsigned short* Qlb = Ql + (size_t)bh * 1024 * 64;
    const unsigned short* Khb = Kh + (size_t)bh * 1024 * 64;
    const unsigned short* Klb = Kl + (size_t)bh * 1024 * 64;
    const unsigned short* Vbh = Vtb + (size_t)bh * 64 * 1024;
    const int* gb = gtm + b * 1024;

    bf16x8 afh[2][2], afl[2][2];
    #pragma unroll
    for (int m = 0; m < 2; m++)
        #pragma unroll
        for (int ks = 0; ks < 2; ks++) {
            size_t off = (size_t)(q0 + m * 16 + (l & 15)) * 64 + ks * 32 + (l >> 4) * 8;
            afh[m][ks] = *(const bf16x8*)(Qhb + off);
            afl[m][ks] = *(const bf16x8*)(Qlb + off);
        }

    int gqm[2];
    #pragma unroll
    for (int m = 0; m < 2; m++) {
        int bits = 0;
        #pragma unroll
        for (int r = 0; r < 4; r++)
            bits |= (gb[q0 + m * 16 + (l >> 4) * 4 + r] ? 1 : 0) << r;
        gqm[m] = bits;
    }

    f32x4 acc_o[2][4] = {};
    float m_run[2][4], l_run[2][4];
    #pragma unroll
    for (int m = 0; m < 2; m++)
        #pragma unroll
        for (int r = 0; r < 4; r++) { m_run[m][r] = -1e30f; l_run[m][r] = 0.f; }

    for (int jt = 0; jt < 16; jt++) {
        const int j0 = jt * 64;
        #pragma unroll
        for (int i = 0; i < 2; i++) {
            int c = i * 256 + tid, row = c >> 3, sl = c & 7, gs = sl ^ (row & 7);
            gload16(Khb + (size_t)(j0 + row) * 64 + gs * 8, &Ksh[c * 8]);
            gload16(Klb + (size_t)(j0 + row) * 64 + gs * 8, &Ksl[c * 8]);
            gload16(Vbh + (size_t)row * 1024 + j0 + gs * 8, &Vs[c * 8]);
        }
        __syncthreads();

        f32x4 sv[2][4] = {};
        #pragma unroll
        for (int n = 0; n < 4; n++) {
            #pragma unroll
            for (int ks = 0; ks < 2; ks++) {
                int row = n * 16 + (l & 15);
                int sl = (ks * 4 + (l >> 4)) ^ (row & 7);
                bf16x8 khf = *(const bf16x8*)&Ksh[row * 64 + sl * 8];
                bf16x8 klf = *(const bf16x8*)&Ksl[row * 64 + sl * 8];
                #pragma unroll
                for (int m = 0; m < 2; m++) {
                    sv[m][n] = __builtin_amdgcn_mfma_f32_16x16x32_bf16(afl[m][ks], khf, sv[m][n], 0, 0, 0);
                    sv[m][n] = __builtin_amdgcn_mfma_f32_16x16x32_bf16(afh[m][ks], klf, sv[m][n], 0, 0, 0);
                    sv[m][n] = __builtin_amdgcn_mfma_f32_16x16x32_bf16(afh[m][ks], khf, sv[m][n], 0, 0, 0);
                }
            }
        }

        int gk[4];
        #pragma unroll
        for (int n = 0; n < 4; n++) gk[n] = gb[j0 + n * 16 + (l & 15)];

        #pragma unroll
        for (int m = 0; m < 2; m++)
            #pragma unroll
            for (int n = 0; n < 4; n++)
                #pragma unroll
                for (int r = 0; r < 4; r++) {
                    int q = q0 + m * 16 + (l >> 4) * 4 + r;
                    int k = j0 + n * 16 + (l & 15);
                    bool allowed = ((gqm[m] >> r) & 1) || gk[n] || ((k <= q) && (q - k < 256));
                    if (!allowed) sv[m][n][r] = -1e30f;
                }

        #pragma unroll
        for (int m = 0; m < 2; m++) {
            float tm[4], corr[4], rsum[4];
            #pragma unroll
            for (int r = 0; r < 4; r++)
                tm[r] = fmaxf(fmaxf(sv[m][0][r], sv[m][1][r]), fmaxf(sv[m][2][r], sv[m][3][r]));
            #pragma unroll
            for (int wd = 1; wd <= 8; wd <<= 1)
                #pragma unroll
                for (int r = 0; r < 4; r++) tm[r] = fmaxf(tm[r], __shfl_xor(tm[r], wd, 64));
            #pragma unroll
            for (int r = 0; r < 4; r++) {
                float mn = fmaxf(m_run[m][r], tm[r]);
                corr[r] = __expf(m_run[m][r] - mn);
                m_run[m][r] = mn;
                rsum[r] = 0.f;
            }
            #pragma unroll
            for (int n = 0; n < 4; n++)
                #pragma unroll
                for (int r = 0; r < 4; r++) {
                    float p = __expf(sv[m][n][r] - m_run[m][r]);
                    sv[m][n][r] = p;
                    rsum[r] += p;
                }
            #pragma unroll
            for (int wd = 1; wd <= 8; wd <<= 1)
                #pragma unroll
                for (int r = 0; r < 4; r++) rsum[r] += __shfl_xor(rsum[r], wd, 64);
            #pragma unroll
            for (int r = 0; r < 4; r++) l_run[m][r] = l_run[m][r] * corr[r] + rsum[r];
            #pragma unroll
            for (int nd = 0; nd < 4; nd++)
                #pragma unroll
                for (int r = 0; r < 4; r++) acc_o[m][nd][r] *= corr[r];
            #pragma unroll
            for (int n = 0; n < 4; n++)
                #pragma unroll
                for (int r = 0; r < 4; r++) {
                    int qr = m * 16 + (l >> 4) * 4 + r;
                    int kc = n * 16 + (l & 15);
                    int byte = (qr * 128 + kc * 2) ^ ((qr & 7) << 4);
                    Pl[w][byte >> 1] = f2bf(sv[m][n][r]);
                }
        }

        asm volatile("s_waitcnt lgkmcnt(0)" ::: "memory");
        __builtin_amdgcn_sched_barrier(0);

        #pragma unroll
        for (int ks = 0; ks < 2; ks++) {
            bf16x8 pa[2];
            #pragma unroll
            for (int m = 0; m < 2; m++) {
                int row = m * 16 + (l & 15);
                int sl = (ks * 4 + (l >> 4)) ^ (row & 7);
                pa[m] = *(const bf16x8*)&Pl[w][row * 64 + sl * 8];
            }
            #pragma unroll
            for (int nd = 0; nd < 4; nd++) {
                int row = nd * 16 + (l & 15);
                int sl = (ks * 4 + (l >> 4)) ^ (row & 7);
                bf16x8 vf = *(const bf16x8*)&Vs[row * 64 + sl * 8];
                #pragma unroll
                for (int m = 0; m < 2; m++)
                    acc_o[m][nd] = __builtin_amdgcn_mfma_f32_16x16x32_bf16(pa[m], vf, acc_o[m][nd], 0, 0, 0);
            }
        }
        __syncthreads();
    }

    #pragma unroll
    for (int m = 0; m < 2; m++)
        #pragma unroll
        for (int r = 0; r < 4; r++) {
            float inv = 1.0f / l_run[m][r];
            int t_ = b * 1024 + q0 + m * 16 + (l >> 4) * 4 + r;
            #pragma unroll
            for (int nd = 0; nd < 4; nd++) {
                int col = h * 64 + nd * 16 + (l & 15);
                o[(size_t)t_ * 1024 + col] = f2bf(acc_o[m][nd][r] * inv);
            }
        }
}

// ---------------- gate v2: one wave per token, register-only ----------------
__global__ __launch_bounds__(256) void gate_kernel(const float* __restrict__ hn,
                                                   const float* __restrict__ Wgate,
                                                   float* __restrict__ wfull,
                                                   float* __restrict__ gate_sum) {
    int tid = threadIdx.x;
    int w = tid >> 6, l = tid & 63;
    int t = blockIdx.x * 4 + w;
    int e = l & 7, g = l >> 3;
    const float* xr = hn + (size_t)t * DMODEL;
    const float* wp = Wgate + l;
    float acc = 0.f;
    #pragma unroll 8
    for (int kk = 0; kk < 128; kk++)
        acc += xr[g + 8 * kk] * wp[64 * kk];
    #pragma unroll
    for (int o = 8; o < 64; o <<= 1) acc += __shfl_xor(acc, o, 64);
    float m = acc;
    #pragma unroll
    for (int o = 1; o < 8; o <<= 1) m = fmaxf(m, __shfl_xor(m, o, 64));
    float p = __expf(acc - m);
    float s = p;
    #pragma unroll
    for (int o = 1; o < 8; o <<= 1) s += __shfl_xor(s, o, 64);
    float pr = p / s;
    if (l < 8) atomicAdd(&gate_sum[e], pr);
    unsigned long long key = ((unsigned long long)__float_as_uint(pr) << 32) | (unsigned)(7 - e);
    unsigned long long k1 = key;
    #pragma unroll
    for (int o = 1; o < 8; o <<= 1) { unsigned long long t2 = __shfl_xor(k1, o, 64); if (t2 > k1) k1 = t2; }
    int e1 = 7 - (int)(k1 & 7);
    float v1 = __uint_as_float((unsigned)(k1 >> 32));
    unsigned long long key2 = (e == e1) ? 0ull : key;
    unsigned long long k2 = key2;
    #pragma unroll
    for (int o = 1; o < 8; o <<= 1) { unsigned long long t2 = __shfl_xor(k2, o, 64); if (t2 > k2) k2 = t2; }
    int e2 = 7 - (int)(k2 & 7);
    float v2 = __uint_as_float((unsigned)(k2 >> 32));
    if (l == 0) {
        wfull[t * 8 + e1] = v1;
        wfull[t * 8 + e2] = v2;
    }
}

// ---------------- per-expert top-CAP via bitonic sort ----------------
__global__ __launch_bounds__(1024) void expert_select_kernel(const float* __restrict__ wfull,
                                                             float* __restrict__ sw,
                                                             int* __restrict__ sidx,
                                                             int* __restrict__ slot) {
    __shared__ unsigned long long keys[2048];
    int e = blockIdx.x;
    int t = threadIdx.x;
    for (int i = t; i < 2048; i += 1024) {
        float w = wfull[i * 8 + e];
        unsigned int wb = __float_as_uint(w);
        keys[i] = ((unsigned long long)wb << 32) | (unsigned long long)(0xFFFFFFFFu - (unsigned int)i);
    }
    __syncthreads();
    for (int k = 2; k <= 2048; k <<= 1) {
        for (int j = k >> 1; j > 0; j >>= 1) {
            for (int i = t; i < 2048; i += 1024) {
                int ixj = i ^ j;
                if (ixj > i) {
                    bool desc = ((i & k) == 0);
                    unsigned long long a = keys[i], b = keys[ixj];
                    if ((a < b) == desc) { keys[i] = b; keys[ixj] = a; }
                }
            }
            __syncthreads();
        }
    }
    if (t < CAP) {
        unsigned long long kk = keys[t];
        float w = __uint_as_float((unsigned int)(kk >> 32));
        int idx = (int)(0xFFFFFFFFu - (unsigned int)(kk & 0xFFFFFFFFu));
        sw[e * CAP + t] = w;
        sidx[e * CAP + t] = idx;
        if (w > 0.f) slot[idx * 8 + e] = t;
    }
}

// ---------------- gather tokens -> bf16 ----------------
__global__ __launch_bounds__(256) void gather_tok_kernel(const float* __restrict__ hn,
                                                         const int* __restrict__ sidx,
                                                         const float* __restrict__ sw,
                                                         unsigned short* __restrict__ tok) {
    int ec = blockIdx.x;
    int tid = threadIdx.x;
    float w = sw[ec];
    int src = sidx[ec];
    const float* s = hn + (size_t)src * DMODEL;
    unsigned short* d = tok + (size_t)ec * DMODEL;
    for (int i = tid; i < DMODEL; i += 256) d[i] = (w > 0.f) ? f2bf(s[i]) : 0;
}

// ---------------- final combine ----------------
__global__ __launch_bounds__(256) void combine_kernel(const float* __restrict__ h,
                                                      const float* __restrict__ out_e,
                                                      const int* __restrict__ slot,
                                                      const float* __restrict__ wfull,
                                                      const float* __restrict__ gate_sum,
                                                      float* __restrict__ out) {
    int t = blockIdx.x;
    int tid = threadIdx.x;
    for (int d = tid; d < DMODEL; d += 256) {
        float acc = h[(size_t)t * DMODEL + d];
        #pragma unroll
        for (int e = 0; e < 8; e++) {
            int c = slot[t * 8 + e];
            if (c >= 0) acc += wfull[t * 8 + e] * out_e[((size_t)(e * CAP + c)) * DMODEL + d];
        }
        out[(size_t)t * DMODEL + d] = acc;
    }
    if (t == 0 && tid == 0) {
        float a = 0.f;
        #pragma unroll
        for (int e = 0; e < 8; e++) { float m = gate_sum[e] / (float)T_TOK; a += m * m; }
        out[(size_t)T_TOK * DMODEL] = 8.0f * a;
    }
}

extern "C" void kernel_launch(void* const* d_in, const int* in_sizes, int n_in,
                              void* d_out, int out_size, void* d_ws, size_t ws_size,
                              hipStream_t stream) {
    const float* x     = (const float*)d_in[0];
    const int*   gtm   = (const int*)d_in[2];
    const float* Wq    = (const float*)d_in[3];
    const float* Wk    = (const float*)d_in[4];
    const float* Wv    = (const float*)d_in[5];
    const float* Wo    = (const float*)d_in[6];
    const float* g1    = (const float*)d_in[7];
    const float* g2    = (const float*)d_in[8];
    const float* Wgate = (const float*)d_in[9];
    const float* W1    = (const float*)d_in[10];
    const float* W2    = (const float*)d_in[11];
    float* out = (float*)d_out;

    char* ws = (char*)d_ws;
    unsigned short* Qh   = (unsigned short*)(ws + 0);           // 4.2 MB
    unsigned short* Ql   = (unsigned short*)(ws + 4194304);     // 4.2 MB
    unsigned short* Kh   = (unsigned short*)(ws + 8388608);     // 4.2 MB
    unsigned short* Kl   = (unsigned short*)(ws + 12582912);    // 4.2 MB
    unsigned short* Vtb  = (unsigned short*)(ws + 16777216);    // 4.2 MB
    unsigned short* WqkvT = (unsigned short*)(ws + 33554432);   // 6.3 MB
    unsigned short* WoT   = (unsigned short*)(ws + 39845888);   // 2.1 MB
    unsigned short* xn    = (unsigned short*)(ws + 41943040);   // 4.2 MB
    unsigned short* attno = (unsigned short*)(ws + 46137344);   // 4.2 MB
    float* qkvb  = (float*)(ws + 50331648);                     // 25.2 MB
    float* oute  = (float*)(ws + 50331648);                     // 8.4 MB (MoE phase, qkvb dead)
    unsigned short* act = (unsigned short*)(ws + 33554432);     // 16.8 MB (MoE phase)
    float* hb    = (float*)(ws + 75497472);                     // 8.4 MB
    float* hnb   = (float*)(ws + 83886080);                     // 8.4 MB
    unsigned short* tok = (unsigned short*)(ws + 92274688);     // 4.2 MB
    float* ropec = (float*)(ws + 96468992);
    float* ropes = (float*)(ws + 96600064);
    float* wfull = (float*)(ws + 96731136);
    int*   slot  = (int*)(ws + 96796672);
    float* sw    = (float*)(ws + 96862208);
    int*   sidx  = (int*)(ws + 96870400);
    float* gsum  = (float*)(ws + 96878592);

    rope_table_kernel<<<S_LEN, 32, 0, stream>>>(ropec, ropes);
    rmsnorm_kernel<1><<<T_TOK, 256, 0, stream>>>(x, g1, xn);

    transpose_bf16<<<dim3(16, 16, 1), 256, 0, stream>>>(Wq, WqkvT, 1024, 1024, 0, 0);
    transpose_bf16<<<dim3(16, 16, 1), 256, 0, stream>>>(Wk, WqkvT + 1024 * 1024, 1024, 1024, 0, 0);
    transpose_bf16<<<dim3(16, 16, 1), 256, 0, stream>>>(Wv, WqkvT + 2048 * 1024, 1024, 1024, 0, 0);
    transpose_bf16<<<dim3(16, 16, 1), 256, 0, stream>>>(Wo, WoT, 1024, 1024, 0, 0);

    // QKV: qkvb(2048,3072) = xn @ [Wq|Wk|Wv]
    gemm_mfma<128, 0><<<dim3(24, 16, 1), 256, 0, stream>>>(
        xn, WqkvT, nullptr, qkvb, 1024, 1024, 3072, 0, 0, 0);

    rope_cvt_kernel<<<T_TOK, 512, 0, stream>>>(qkvb, ropec, ropes, Qh, Ql, Kh, Kl);
    vt_cvt_kernel<<<dim3(32, 32, 1), 256, 0, stream>>>(qkvb, Vtb);

    attn_mfma_kernel<<<dim3(8, 16, 2), 256, 0, stream>>>(Qh, Ql, Kh, Kl, Vtb, gtm, attno);

    // h = x + attno @ Wo  (BN=64 -> 256 blocks)
    gemm_mfma<64, 1><<<dim3(16, 16, 1), 256, 0, stream>>>(
        attno, WoT, x, hb, 1024, 1024, 1024, 0, 0, 0);
    rmsnorm_kernel<0><<<T_TOK, 256, 0, stream>>>(hb, g2, hnb);

    hipMemsetAsync(wfull, 0, (size_t)T_TOK * NE * 4, stream);
    hipMemsetAsync(slot, 0xFF, (size_t)T_TOK * NE * 4, stream);
    hipMemsetAsync(gsum, 0, 8 * 4, stream);

    gate_kernel<<<T_TOK / 4, 256, 0, stream>>>(hnb, Wgate, wfull, gsum);
    expert_select_kernel<<<NE, 1024, 0, stream>>>(wfull, sw, sidx, slot);
    gather_tok_kernel<<<NE * CAP, 256, 0, stream>>>(hnb, sidx, sw, tok);

    // fused MoE GEMMs reading f32 weights directly (no transpose pass)
    gemm_w1_fused<<<dim3(128, 8, 1), 256, 0, stream>>>(tok, W1, act);
    gemm_w2_fused<<<dim3(32, 8, 1), 256, 0, stream>>>(act, W2, oute);

    combine_kernel<<<T_TOK, 256, 0, stream>>>(hb, oute, slot, wfull, gsum, out);
}

// Round 8
// 372.274 us; speedup vs baseline: 6.0582x; 1.0851x over previous
//
#include <hip/hip_runtime.h>
#include <hip/hip_bf16.h>
#include <math.h>

#define T_TOK 2048
#define DMODEL 1024
#define NH 16
#define HD 64
#define S_LEN 1024
#define NE 8
#define CAP 256
#define DFF 4096

typedef __attribute__((ext_vector_type(8))) short bf16x8;
typedef __attribute__((ext_vector_type(4))) float f32x4;

__device__ inline unsigned short f2bf(float f) {
    union { float f; unsigned int u; } x; x.f = f;
    unsigned int u = x.u;
    unsigned int r = (u + 0x7FFFu + ((u >> 16) & 1u)) >> 16;
    return (unsigned short)r;
}

__device__ inline float bf2f(unsigned short h) {
    union { unsigned int u; float f; } x; x.u = (unsigned int)h << 16; return x.f;
}

// packed f32x2 -> bf16x2 (RTNE, single v_cvt_pk_bf16_f32); lo in low 16 bits
__device__ inline unsigned int pkbf(float lo, float hi) {
    __hip_bfloat162 h2 = __float22bfloat162_rn(make_float2(lo, hi));
    unsigned int r;
    __builtin_memcpy(&r, &h2, 4);
    return r;
}

__device__ inline void gload16(const void* g, void* l) {
    __builtin_amdgcn_global_load_lds(
        (const __attribute__((address_space(1))) unsigned int*)g,
        (__attribute__((address_space(3))) unsigned int*)l, 16, 0, 0);
}

// ---------------- RoPE table ----------------
__global__ void rope_table_kernel(float* __restrict__ rc, float* __restrict__ rs) {
    int s = blockIdx.x;
    int i = threadIdx.x;
    float invf = powf(10000.0f, -(float)(2 * i) / 64.0f);
    float ang = (float)s * invf;
    rc[s * 32 + i] = cosf(ang);
    rs[s * 32 + i] = sinf(ang);
}

// ---------------- RMSNorm (OUTBF: 1 -> bf16 out, 0 -> f32 out) ----------------
template <int OUTBF>
__global__ __launch_bounds__(256) void rmsnorm_kernel(const float* __restrict__ x,
                                                      const float* __restrict__ g,
                                                      void* __restrict__ yv) {
    __shared__ float red[256];
    int t = blockIdx.x;
    int tid = threadIdx.x;
    const float* xr = x + (size_t)t * DMODEL;
    float ss = 0.f;
    for (int d = tid; d < DMODEL; d += 256) { float v = xr[d]; ss += v * v; }
    red[tid] = ss; __syncthreads();
    for (int o = 128; o > 0; o >>= 1) { if (tid < o) red[tid] += red[tid + o]; __syncthreads(); }
    float scale = 1.0f / sqrtf(red[0] / (float)DMODEL + 1e-6f);
    if (OUTBF) {
        unsigned short* yr = (unsigned short*)yv + (size_t)t * DMODEL;
        for (int d = tid; d < DMODEL; d += 256) yr[d] = f2bf(g[d] * xr[d] * scale);
    } else {
        float* yr = (float*)yv + (size_t)t * DMODEL;
        for (int d = tid; d < DMODEL; d += 256) yr[d] = g[d] * xr[d] * scale;
    }
}

// ---------------- transpose+convert: dst_bf16(C,R) = src_f32(R,C)^T (QKV/Wo only) ----------------
__global__ __launch_bounds__(256) void transpose_bf16(const float* __restrict__ src,
                                                      unsigned short* __restrict__ dst,
                                                      int ldS, int ldD,
                                                      long long sS, long long sD) {
    __shared__ float tile[64][65];
    src += (long long)blockIdx.z * sS;
    dst += (long long)blockIdx.z * sD;
    int c0 = blockIdx.x * 64, r0 = blockIdx.y * 64;
    int tr = threadIdx.x >> 4;
    int tc4 = (threadIdx.x & 15) * 4;
    #pragma unroll
    for (int j = 0; j < 4; j++) {
        float4 v = *(const float4*)&src[(size_t)(r0 + tr + j * 16) * ldS + c0 + tc4];
        tile[tr + j * 16][tc4 + 0] = v.x;
        tile[tr + j * 16][tc4 + 1] = v.y;
        tile[tr + j * 16][tc4 + 2] = v.z;
        tile[tr + j * 16][tc4 + 3] = v.w;
    }
    __syncthreads();
    int oc = threadIdx.x >> 3;
    int or8 = (threadIdx.x & 7) * 8;
    #pragma unroll
    for (int j = 0; j < 2; j++) {
        int c = oc + j * 32;
        unsigned short tmp[8];
        #pragma unroll
        for (int u = 0; u < 8; u++) tmp[u] = f2bf(tile[or8 + u][c]);
        *(uint4*)&dst[(size_t)(c0 + c) * ldD + r0 + or8] = *(uint4*)tmp;
    }
}

// ---------------- bf16 MFMA GEMM: C(f32) = A(M,K)bf16 @ BT(N,K)bf16^T ----------------
template <int BN, int RES>
__global__ __launch_bounds__(256) void gemm_mfma(const unsigned short* __restrict__ A,
                                                 const unsigned short* __restrict__ BT,
                                                 const float* __restrict__ Rr,
                                                 float* __restrict__ C,
                                                 int K, int lda, int ldc,
                                                 long long sA, long long sB, long long sC) {
    constexpr int BM = 128, BK = 64;
    constexpr int NF = BN / 32;
    __shared__ unsigned short As[BM * BK];
    __shared__ unsigned short Bs[BN * BK];
    A += (long long)blockIdx.z * sA;
    BT += (long long)blockIdx.z * sB;
    C += (long long)blockIdx.z * sC;
    const int tid = threadIdx.x;
    const int lane = tid & 63;
    const int wid = tid >> 6;
    const int wr = wid >> 1, wc = wid & 1;
    const int bx = blockIdx.x * BN, by = blockIdx.y * BM;

    f32x4 acc[4][NF] = {};

    for (int k0 = 0; k0 < K; k0 += BK) {
        #pragma unroll
        for (int i = 0; i < (BM * 8) / 256; i++) {
            int c = i * 256 + tid;
            int row = c >> 3, slot = c & 7;
            int gs = slot ^ (row & 7);
            gload16(A + (size_t)(by + row) * lda + k0 + gs * 8, &As[c * 8]);
        }
        #pragma unroll
        for (int i = 0; i < (BN * 8) / 256; i++) {
            int c = i * 256 + tid;
            int row = c >> 3, slot = c & 7;
            int gs = slot ^ (row & 7);
            gload16(BT + (size_t)(bx + row) * K + k0 + gs * 8, &Bs[c * 8]);
        }
        __syncthreads();
        #pragma unroll
        for (int ks = 0; ks < 2; ks++) {
            bf16x8 af[4], bfr[NF];
            #pragma unroll
            for (int m = 0; m < 4; m++) {
                int row = wr * 64 + m * 16 + (lane & 15);
                int slot = (ks * 4 + (lane >> 4)) ^ (row & 7);
                af[m] = *(const bf16x8*)&As[row * 64 + slot * 8];
            }
            #pragma unroll
            for (int n = 0; n < NF; n++) {
                int row = wc * (BN / 2) + n * 16 + (lane & 15);
                int slot = (ks * 4 + (lane >> 4)) ^ (row & 7);
                bfr[n] = *(const bf16x8*)&Bs[row * 64 + slot * 8];
            }
            #pragma unroll
            for (int m = 0; m < 4; m++)
                #pragma unroll
                for (int n = 0; n < NF; n++)
                    acc[m][n] = __builtin_amdgcn_mfma_f32_16x16x32_bf16(af[m], bfr[n], acc[m][n], 0, 0, 0);
        }
        __syncthreads();
    }
    #pragma unroll
    for (int m = 0; m < 4; m++) {
        int row0 = by + wr * 64 + m * 16 + (lane >> 4) * 4;
        #pragma unroll
        for (int n = 0; n < NF; n++) {
            int col = bx + wc * (BN / 2) + n * 16 + (lane & 15);
            #pragma unroll
            for (int r = 0; r < 4; r++) {
                size_t idx = (size_t)(row0 + r) * ldc + col;
                float v = acc[m][n][r];
                if (RES == 1) v += Rr[idx];
                if (RES == 2) v += C[idx];
                C[idx] = v;
            }
        }
    }
}

// ---------------- fused MoE W1 GEMM + SwiGLU: reads f32 W1 (K,N) directly ----------------
__global__ __launch_bounds__(256) void gemm_w1_fused(const unsigned short* __restrict__ tok,
                                                     const float* __restrict__ W1,
                                                     unsigned short* __restrict__ act) {
    __shared__ unsigned short As[256 * 64];   // 32 KB
    __shared__ unsigned int B1p[32 * 32];     // 4 KB
    __shared__ unsigned int B2p[32 * 32];     // 4 KB
    const int e = blockIdx.y;
    const int bx = blockIdx.x * 32;
    const unsigned short* A = tok + (size_t)e * CAP * DMODEL;
    const float* B = W1 + (size_t)e * DMODEL * (2 * DFF);
    unsigned short* C = act + (size_t)e * CAP * DFF;
    const int tid = threadIdx.x, l = tid & 63, wid = tid >> 6;
    const int g = l >> 4;
    const int kp = tid >> 3;
    const int nc = tid & 7;
    const int chunk = kp >> 2, within = kp & 3;

    f32x4 acc1[4][2] = {};
    f32x4 acc2[4][2] = {};

    for (int k0 = 0; k0 < DMODEL; k0 += 64) {
        #pragma unroll
        for (int i = 0; i < 8; i++) {
            int c = i * 256 + tid;
            int row = c >> 3, sl = c & 7, gs = sl ^ (row & 7);
            gload16(A + (size_t)row * DMODEL + k0 + gs * 8, &As[c * 8]);
        }
        const float* Brow = B + (size_t)(k0 + 2 * kp) * 8192 + bx + nc * 4;
        float4 a0 = *(const float4*)(Brow);
        float4 a1 = *(const float4*)(Brow + 8192);
        float4 c0 = *(const float4*)(Brow + 4096);
        float4 c1 = *(const float4*)(Brow + 4096 + 8192);
        unsigned int p1[4], p2[4];
        p1[0] = pkbf(a0.x, a1.x); p1[1] = pkbf(a0.y, a1.y);
        p1[2] = pkbf(a0.z, a1.z); p1[3] = pkbf(a0.w, a1.w);
        p2[0] = pkbf(c0.x, c1.x); p2[1] = pkbf(c0.y, c1.y);
        p2[2] = pkbf(c0.z, c1.z); p2[3] = pkbf(c0.w, c1.w);
        #pragma unroll
        for (int i = 0; i < 4; i++) {
            int n_loc = nc * 4 + i;
            int idx = n_loc * 32 + ((chunk ^ (n_loc & 7)) << 2) + within;
            B1p[idx] = p1[i];
            B2p[idx] = p2[i];
        }
        __syncthreads();
        #pragma unroll
        for (int ks = 0; ks < 2; ks++) {
            bf16x8 af[4];
            #pragma unroll
            for (int m = 0; m < 4; m++) {
                int row = wid * 64 + m * 16 + (l & 15);
                int sl = (ks * 4 + g) ^ (row & 7);
                af[m] = *(const bf16x8*)&As[row * 64 + sl * 8];
            }
            #pragma unroll
            for (int nf = 0; nf < 2; nf++) {
                int n_loc = nf * 16 + (l & 15);
                int base = n_loc * 32 + (((ks * 4 + g) ^ (n_loc & 7)) << 2);
                bf16x8 b1 = *(const bf16x8*)&B1p[base];
                bf16x8 b2 = *(const bf16x8*)&B2p[base];
                #pragma unroll
                for (int m = 0; m < 4; m++) {
                    acc1[m][nf] = __builtin_amdgcn_mfma_f32_16x16x32_bf16(af[m], b1, acc1[m][nf], 0, 0, 0);
                    acc2[m][nf] = __builtin_amdgcn_mfma_f32_16x16x32_bf16(af[m], b2, acc2[m][nf], 0, 0, 0);
                }
            }
        }
        __syncthreads();
    }
    #pragma unroll
    for (int m = 0; m < 4; m++) {
        int row0 = wid * 64 + m * 16 + (l >> 4) * 4;
        #pragma unroll
        for (int nf = 0; nf < 2; nf++) {
            int col = bx + nf * 16 + (l & 15);
            #pragma unroll
            for (int r = 0; r < 4; r++) {
                float h1 = acc1[m][nf][r], h2 = acc2[m][nf][r];
                float sil = h2 / (1.0f + __expf(-h2));
                C[(size_t)(row0 + r) * DFF + col] = f2bf(h1 * sil);
            }
        }
    }
}

// ---------------- fused MoE W2 GEMM: BM=128 (2 blocks/expert-row), K=4096 ----------------
__global__ __launch_bounds__(256) void gemm_w2_fused(const unsigned short* __restrict__ act,
                                                     const float* __restrict__ W2,
                                                     float* __restrict__ oute) {
    __shared__ unsigned short As[128 * 64];   // 16 KB
    __shared__ unsigned int Bp[32 * 32];      // 4 KB
    const int e = blockIdx.y >> 1, mb = blockIdx.y & 1;
    const int bx = blockIdx.x * 32;
    const unsigned short* A = act + (size_t)e * CAP * DFF + (size_t)mb * 128 * DFF;
    const float* B = W2 + (size_t)e * DFF * DMODEL;
    float* C = oute + (size_t)e * CAP * DMODEL + (size_t)mb * 128 * DMODEL;
    const int tid = threadIdx.x, l = tid & 63, wid = tid >> 6;
    const int g = l >> 4;
    const int kp = tid >> 3;
    const int nc = tid & 7;
    const int chunk = kp >> 2, within = kp & 3;

    f32x4 acc[2][2] = {};

    for (int k0 = 0; k0 < DFF; k0 += 64) {
        #pragma unroll
        for (int i = 0; i < 4; i++) {
            int c = i * 256 + tid;
            int row = c >> 3, sl = c & 7, gs = sl ^ (row & 7);
            gload16(A + (size_t)row * DFF + k0 + gs * 8, &As[c * 8]);
        }
        const float* Brow = B + (size_t)(k0 + 2 * kp) * DMODEL + bx + nc * 4;
        float4 a0 = *(const float4*)(Brow);
        float4 a1 = *(const float4*)(Brow + DMODEL);
        unsigned int p1[4];
        p1[0] = pkbf(a0.x, a1.x); p1[1] = pkbf(a0.y, a1.y);
        p1[2] = pkbf(a0.z, a1.z); p1[3] = pkbf(a0.w, a1.w);
        #pragma unroll
        for (int i = 0; i < 4; i++) {
            int n_loc = nc * 4 + i;
            int idx = n_loc * 32 + ((chunk ^ (n_loc & 7)) << 2) + within;
            Bp[idx] = p1[i];
        }
        __syncthreads();
        #pragma unroll
        for (int ks = 0; ks < 2; ks++) {
            bf16x8 af[2];
            #pragma unroll
            for (int m = 0; m < 2; m++) {
                int row = wid * 32 + m * 16 + (l & 15);
                int sl = (ks * 4 + g) ^ (row & 7);
                af[m] = *(const bf16x8*)&As[row * 64 + sl * 8];
            }
            #pragma unroll
            for (int nf = 0; nf < 2; nf++) {
                int n_loc = nf * 16 + (l & 15);
                int base = n_loc * 32 + (((ks * 4 + g) ^ (n_loc & 7)) << 2);
                bf16x8 bfr = *(const bf16x8*)&Bp[base];
                #pragma unroll
                for (int m = 0; m < 2; m++)
                    acc[m][nf] = __builtin_amdgcn_mfma_f32_16x16x32_bf16(af[m], bfr, acc[m][nf], 0, 0, 0);
            }
        }
        __syncthreads();
    }
    #pragma unroll
    for (int m = 0; m < 2; m++) {
        int row0 = wid * 32 + m * 16 + (l >> 4) * 4;
        #pragma unroll
        for (int nf = 0; nf < 2; nf++) {
            int col = bx + nf * 16 + (l & 15);
            #pragma unroll
            for (int r = 0; r < 4; r++)
                C[(size_t)(row0 + r) * DMODEL + col] = acc[m][nf][r];
        }
    }
}

// ---------------- RoPE + convert to hi/lo bf16 pairs, head-major ----------------
__global__ __launch_bounds__(512) void rope_cvt_kernel(const float* __restrict__ qkv,
                                                       const float* __restrict__ rc,
                                                       const float* __restrict__ rs,
                                                       unsigned short* __restrict__ Qh,
                                                       unsigned short* __restrict__ Ql,
                                                       unsigned short* __restrict__ Kh,
                                                       unsigned short* __restrict__ Kl) {
    int t = blockIdx.x;
    int b = t >> 10, s = t & 1023;
    int hh = threadIdx.x >> 5, i = threadIdx.x & 31;
    float c = rc[s * 32 + i], sn = rs[s * 32 + i];
    size_t base = (size_t)t * 3072 + hh * 64;
    float qa = qkv[base + i], qb_ = qkv[base + i + 32];
    float ka = qkv[base + 1024 + i], kb_ = qkv[base + 1024 + i + 32];
    size_t ob = ((size_t)(b * 16 + hh) * 1024 + s) * 64;
    float q0 = (qa * c - qb_ * sn) * 0.125f;
    float q1 = (qb_ * c + qa * sn) * 0.125f;
    float k0 = ka * c - kb_ * sn;
    float k1 = kb_ * c + ka * sn;
    unsigned short h0, h1;
    h0 = f2bf(q0); Qh[ob + i] = h0;      Ql[ob + i] = f2bf(q0 - bf2f(h0));
    h1 = f2bf(q1); Qh[ob + i + 32] = h1; Ql[ob + i + 32] = f2bf(q1 - bf2f(h1));
    h0 = f2bf(k0); Kh[ob + i] = h0;      Kl[ob + i] = f2bf(k0 - bf2f(h0));
    h1 = f2bf(k1); Kh[ob + i + 32] = h1; Kl[ob + i + 32] = f2bf(k1 - bf2f(h1));
}

// ---------------- V transpose+convert: qkv f32 -> Vtb bf16 [bh][d][s] ----------------
__global__ __launch_bounds__(256) void vt_cvt_kernel(const float* __restrict__ qkv,
                                                     unsigned short* __restrict__ Vtb) {
    __shared__ float tile[32][65];
    int st = blockIdx.x;
    int bh = blockIdx.y;
    int b = bh >> 4, h = bh & 15;
    int tid = threadIdx.x;
    int s0 = st * 32;
    int sr = tid >> 3, c8 = (tid & 7) * 8;
    const float* src = qkv + (size_t)(b * 1024 + s0 + sr) * 3072 + 2048 + h * 64 + c8;
    #pragma unroll
    for (int u = 0; u < 8; u++) tile[sr][c8 + u] = src[u];
    __syncthreads();
    int d = tid & 63, sj = (tid >> 6) * 8;
    unsigned short tmp[8];
    #pragma unroll
    for (int u = 0; u < 8; u++) tmp[u] = f2bf(tile[sj + u][d]);
    *(uint4*)(Vtb + ((size_t)bh * 64 + d) * 1024 + s0 + sj) = *(uint4*)tmp;
}

// ---------------- flash-style MFMA attention, 16 q-rows per wave, 2 blocks/CU ----------------
__global__ __launch_bounds__(256) void attn_mfma_kernel(const unsigned short* __restrict__ Qh,
                                                        const unsigned short* __restrict__ Ql,
                                                        const unsigned short* __restrict__ Kh,
                                                        const unsigned short* __restrict__ Kl,
                                                        const unsigned short* __restrict__ Vtb,
                                                        const int* __restrict__ gtm,
                                                        unsigned short* __restrict__ o) {
    __shared__ unsigned short Ksh[64 * 64];
    __shared__ unsigned short Ksl[64 * 64];
    __shared__ unsigned short Vs[64 * 64];
    __shared__ unsigned short Pl[4][16 * 64];
    const int qt = blockIdx.x, h = blockIdx.y, b = blockIdx.z;
    const int bh = b * 16 + h;
    const int tid = threadIdx.x, l = tid & 63, w = tid >> 6;
    const int q0 = qt * 64 + w * 16;
    const unsigned short* Qhb = Qh + (size_t)bh * 1024 * 64;
    const unsigned short* Qlb = Ql + (size_t)bh * 1024 * 64;
    const unsigned short* Khb = Kh + (size_t)bh * 1024 * 64;
    const unsigned short* Klb = Kl + (size_t)bh * 1024 * 64;
    const unsigned short* Vbh = Vtb + (size_t)bh * 64 * 1024;
    const int* gb = gtm + b * 1024;

    bf16x8 afh[2], afl[2];
    #pragma unroll
    for (int ks = 0; ks < 2; ks++) {
        size_t off = (size_t)(q0 + (l & 15)) * 64 + ks * 32 + (l >> 4) * 8;
        afh[ks] = *(const bf16x8*)(Qhb + off);
        afl[ks] = *(const bf16x8*)(Qlb + off);
    }

    int gqm = 0;
    #pragma unroll
    for (int r = 0; r < 4; r++)
        gqm |= (gb[q0 + (l >> 4) * 4 + r] ? 1 : 0) << r;

    f32x4 acc_o[4] = {};
    float m_run[4], l_run[4];
    #pragma unroll
    for (int r = 0; r < 4; r++) { m_run[r] = -1e30f; l_run[r] = 0.f; }

    for (int jt = 0; jt < 16; jt++) {
        const int j0 = jt * 64;
        #pragma unroll
        for (int i = 0; i < 2; i++) {
            int c = i * 256 + tid, row = c >> 3, sl = c & 7, gs = sl ^ (row & 7);
            gload16(Khb + (size_t)(j0 + row) * 64 + gs * 8, &Ksh[c * 8]);
            gload16(Klb + (size_t)(j0 + row) * 64 + gs * 8, &Ksl[c * 8]);
            gload16(Vbh + (size_t)row * 1024 + j0 + gs * 8, &Vs[c * 8]);
        }
        __syncthreads();

        // S = Qh·Kh + Ql·Kh + Qh·Kl: 24 mfma
        f32x4 sv[4] = {};
        #pragma unroll
        for (int n = 0; n < 4; n++) {
            #pragma unroll
            for (int ks = 0; ks < 2; ks++) {
                int row = n * 16 + (l & 15);
                int sl = (ks * 4 + (l >> 4)) ^ (row & 7);
                bf16x8 khf = *(const bf16x8*)&Ksh[row * 64 + sl * 8];
                bf16x8 klf = *(const bf16x8*)&Ksl[row * 64 + sl * 8];
                sv[n] = __builtin_amdgcn_mfma_f32_16x16x32_bf16(afl[ks], khf, sv[n], 0, 0, 0);
                sv[n] = __builtin_amdgcn_mfma_f32_16x16x32_bf16(afh[ks], klf, sv[n], 0, 0, 0);
                sv[n] = __builtin_amdgcn_mfma_f32_16x16x32_bf16(afh[ks], khf, sv[n], 0, 0, 0);
            }
        }

        int gk[4];
        #pragma unroll
        for (int n = 0; n < 4; n++) gk[n] = gb[j0 + n * 16 + (l & 15)];

        #pragma unroll
        for (int n = 0; n < 4; n++)
            #pragma unroll
            for (int r = 0; r < 4; r++) {
                int q = q0 + (l >> 4) * 4 + r;
                int k = j0 + n * 16 + (l & 15);
                bool allowed = ((gqm >> r) & 1) || gk[n] || ((k <= q) && (q - k < 256));
                if (!allowed) sv[n][r] = -1e30f;
            }

        // online softmax (rows owned per (l>>4, r))
        {
            float tm[4], corr[4], rsum[4];
            #pragma unroll
            for (int r = 0; r < 4; r++)
                tm[r] = fmaxf(fmaxf(sv[0][r], sv[1][r]), fmaxf(sv[2][r], sv[3][r]));
            #pragma unroll
            for (int wd = 1; wd <= 8; wd <<= 1)
                #pragma unroll
                for (int r = 0; r < 4; r++) tm[r] = fmaxf(tm[r], __shfl_xor(tm[r], wd, 64));
            #pragma unroll
            for (int r = 0; r < 4; r++) {
                float mn = fmaxf(m_run[r], tm[r]);
                corr[r] = __expf(m_run[r] - mn);
                m_run[r] = mn;
                rsum[r] = 0.f;
            }
            #pragma unroll
            for (int n = 0; n < 4; n++)
                #pragma unroll
                for (int r = 0; r < 4; r++) {
                    float p = __expf(sv[n][r] - m_run[r]);
                    sv[n][r] = p;
                    rsum[r] += p;
                }
            #pragma unroll
            for (int wd = 1; wd <= 8; wd <<= 1)
                #pragma unroll
                for (int r = 0; r < 4; r++) rsum[r] += __shfl_xor(rsum[r], wd, 64);
            #pragma unroll
            for (int r = 0; r < 4; r++) l_run[r] = l_run[r] * corr[r] + rsum[r];
            #pragma unroll
            for (int nd = 0; nd < 4; nd++)
                #pragma unroll
                for (int r = 0; r < 4; r++) acc_o[nd][r] *= corr[r];
            #pragma unroll
            for (int n = 0; n < 4; n++)
                #pragma unroll
                for (int r = 0; r < 4; r++) {
                    int qr = (l >> 4) * 4 + r;
                    int kc = n * 16 + (l & 15);
                    int byte = (qr * 128 + kc * 2) ^ ((qr & 7) << 4);
                    Pl[w][byte >> 1] = f2bf(sv[n][r]);
                }
        }

        asm volatile("s_waitcnt lgkmcnt(0)" ::: "memory");
        __builtin_amdgcn_sched_barrier(0);

        // O += P V : 8 mfma
        #pragma unroll
        for (int ks = 0; ks < 2; ks++) {
            int prow = l & 15;
            int psl = (ks * 4 + (l >> 4)) ^ (prow & 7);
            bf16x8 pa = *(const bf16x8*)&Pl[w][prow * 64 + psl * 8];
            #pragma unroll
            for (int nd = 0; nd < 4; nd++) {
                int row = nd * 16 + (l & 15);
                int sl = (ks * 4 + (l >> 4)) ^ (row & 7);
                bf16x8 vf = *(const bf16x8*)&Vs[row * 64 + sl * 8];
                acc_o[nd] = __builtin_amdgcn_mfma_f32_16x16x32_bf16(pa, vf, acc_o[nd], 0, 0, 0);
            }
        }
        __syncthreads();
    }

    #pragma unroll
    for (int r = 0; r < 4; r++) {
        float inv = 1.0f / l_run[r];
        int t_ = b * 1024 + q0 + (l >> 4) * 4 + r;
        #pragma unroll
        for (int nd = 0; nd < 4; nd++) {
            int col = h * 64 + nd * 16 + (l & 15);
            o[(size_t)t_ * 1024 + col] = f2bf(acc_o[nd][r] * inv);
        }
    }
}

// ---------------- gate v2: one wave per token, register-only ----------------
__global__ __launch_bounds__(256) void gate_kernel(const float* __restrict__ hn,
                                                   const float* __restrict__ Wgate,
                                                   float* __restrict__ wfull,
                                                   float* __restrict__ gate_sum) {
    int tid = threadIdx.x;
    int w = tid >> 6, l = tid & 63;
    int t = blockIdx.x * 4 + w;
    int e = l & 7, g = l >> 3;
    const float* xr = hn + (size_t)t * DMODEL;
    const float* wp = Wgate + l;
    float acc = 0.f;
    #pragma unroll 8
    for (int kk = 0; kk < 128; kk++)
        acc += xr[g + 8 * kk] * wp[64 * kk];
    #pragma unroll
    for (int o = 8; o < 64; o <<= 1) acc += __shfl_xor(acc, o, 64);
    float m = acc;
    #pragma unroll
    for (int o = 1; o < 8; o <<= 1) m = fmaxf(m, __shfl_xor(m, o, 64));
    float p = __expf(acc - m);
    float s = p;
    #pragma unroll
    for (int o = 1; o < 8; o <<= 1) s += __shfl_xor(s, o, 64);
    float pr = p / s;
    if (l < 8) atomicAdd(&gate_sum[e], pr);
    unsigned long long key = ((unsigned long long)__float_as_uint(pr) << 32) | (unsigned)(7 - e);
    unsigned long long k1 = key;
    #pragma unroll
    for (int o = 1; o < 8; o <<= 1) { unsigned long long t2 = __shfl_xor(k1, o, 64); if (t2 > k1) k1 = t2; }
    int e1 = 7 - (int)(k1 & 7);
    float v1 = __uint_as_float((unsigned)(k1 >> 32));
    unsigned long long key2 = (e == e1) ? 0ull : key;
    unsigned long long k2 = key2;
    #pragma unroll
    for (int o = 1; o < 8; o <<= 1) { unsigned long long t2 = __shfl_xor(k2, o, 64); if (t2 > k2) k2 = t2; }
    int e2 = 7 - (int)(k2 & 7);
    float v2 = __uint_as_float((unsigned)(k2 >> 32));
    if (l == 0) {
        wfull[t * 8 + e1] = v1;
        wfull[t * 8 + e2] = v2;
    }
}

// ---------------- per-expert top-CAP via bitonic sort ----------------
__global__ __launch_bounds__(1024) void expert_select_kernel(const float* __restrict__ wfull,
                                                             float* __restrict__ sw,
                                                             int* __restrict__ sidx,
                                                             int* __restrict__ slot) {
    __shared__ unsigned long long keys[2048];
    int e = blockIdx.x;
    int t = threadIdx.x;
    for (int i = t; i < 2048; i += 1024) {
        float w = wfull[i * 8 + e];
        unsigned int wb = __float_as_uint(w);
        keys[i] = ((unsigned long long)wb << 32) | (unsigned long long)(0xFFFFFFFFu - (unsigned int)i);
    }
    __syncthreads();
    for (int k = 2; k <= 2048; k <<= 1) {
        for (int j = k >> 1; j > 0; j >>= 1) {
            for (int i = t; i < 2048; i += 1024) {
                int ixj = i ^ j;
                if (ixj > i) {
                    bool desc = ((i & k) == 0);
                    unsigned long long a = keys[i], b = keys[ixj];
                    if ((a < b) == desc) { keys[i] = b; keys[ixj] = a; }
                }
            }
            __syncthreads();
        }
    }
    if (t < CAP) {
        unsigned long long kk = keys[t];
        float w = __uint_as_float((unsigned int)(kk >> 32));
        int idx = (int)(0xFFFFFFFFu - (unsigned int)(kk & 0xFFFFFFFFu));
        sw[e * CAP + t] = w;
        sidx[e * CAP + t] = idx;
        if (w > 0.f) slot[idx * 8 + e] = t;
    }
}

// ---------------- gather tokens -> bf16 ----------------
__global__ __launch_bounds__(256) void gather_tok_kernel(const float* __restrict__ hn,
                                                         const int* __restrict__ sidx,
                                                         const float* __restrict__ sw,
                                                         unsigned short* __restrict__ tok) {
    int ec = blockIdx.x;
    int tid = threadIdx.x;
    float w = sw[ec];
    int src = sidx[ec];
    const float* s = hn + (size_t)src * DMODEL;
    unsigned short* d = tok + (size_t)ec * DMODEL;
    for (int i = tid; i < DMODEL; i += 256) d[i] = (w > 0.f) ? f2bf(s[i]) : 0;
}

// ---------------- final combine ----------------
__global__ __launch_bounds__(256) void combine_kernel(const float* __restrict__ h,
                                                      const float* __restrict__ out_e,
                                                      const int* __restrict__ slot,
                                                      const float* __restrict__ wfull,
                                                      const float* __restrict__ gate_sum,
                                                      float* __restrict__ out) {
    int t = blockIdx.x;
    int tid = threadIdx.x;
    for (int d = tid; d < DMODEL; d += 256) {
        float acc = h[(size_t)t * DMODEL + d];
        #pragma unroll
        for (int e = 0; e < 8; e++) {
            int c = slot[t * 8 + e];
            if (c >= 0) acc += wfull[t * 8 + e] * out_e[((size_t)(e * CAP + c)) * DMODEL + d];
        }
        out[(size_t)t * DMODEL + d] = acc;
    }
    if (t == 0 && tid == 0) {
        float a = 0.f;
        #pragma unroll
        for (int e = 0; e < 8; e++) { float m = gate_sum[e] / (float)T_TOK; a += m * m; }
        out[(size_t)T_TOK * DMODEL] = 8.0f * a;
    }
}

extern "C" void kernel_launch(void* const* d_in, const int* in_sizes, int n_in,
                              void* d_out, int out_size, void* d_ws, size_t ws_size,
                              hipStream_t stream) {
    const float* x     = (const float*)d_in[0];
    const int*   gtm   = (const int*)d_in[2];
    const float* Wq    = (const float*)d_in[3];
    const float* Wk    = (const float*)d_in[4];
    const float* Wv    = (const float*)d_in[5];
    const float* Wo    = (const float*)d_in[6];
    const float* g1    = (const float*)d_in[7];
    const float* g2    = (const float*)d_in[8];
    const float* Wgate = (const float*)d_in[9];
    const float* W1    = (const float*)d_in[10];
    const float* W2    = (const float*)d_in[11];
    float* out = (float*)d_out;

    char* ws = (char*)d_ws;
    unsigned short* Qh   = (unsigned short*)(ws + 0);           // 4.2 MB
    unsigned short* Ql   = (unsigned short*)(ws + 4194304);     // 4.2 MB
    unsigned short* Kh   = (unsigned short*)(ws + 8388608);     // 4.2 MB
    unsigned short* Kl   = (unsigned short*)(ws + 12582912);    // 4.2 MB
    unsigned short* Vtb  = (unsigned short*)(ws + 16777216);    // 4.2 MB
    unsigned short* WqkvT = (unsigned short*)(ws + 33554432);   // 6.3 MB
    unsigned short* WoT   = (unsigned short*)(ws + 39845888);   // 2.1 MB
    unsigned short* xn    = (unsigned short*)(ws + 41943040);   // 4.2 MB
    unsigned short* attno = (unsigned short*)(ws + 46137344);   // 4.2 MB
    float* qkvb  = (float*)(ws + 50331648);                     // 25.2 MB
    float* oute  = (float*)(ws + 50331648);                     // 8.4 MB (MoE phase, qkvb dead)
    unsigned short* act = (unsigned short*)(ws + 33554432);     // 16.8 MB (MoE phase)
    float* hb    = (float*)(ws + 75497472);                     // 8.4 MB
    float* hnb   = (float*)(ws + 83886080);                     // 8.4 MB
    unsigned short* tok = (unsigned short*)(ws + 92274688);     // 4.2 MB
    float* ropec = (float*)(ws + 96468992);
    float* ropes = (float*)(ws + 96600064);
    float* wfull = (float*)(ws + 96731136);
    int*   slot  = (int*)(ws + 96796672);
    float* sw    = (float*)(ws + 96862208);
    int*   sidx  = (int*)(ws + 96870400);
    float* gsum  = (float*)(ws + 96878592);

    rope_table_kernel<<<S_LEN, 32, 0, stream>>>(ropec, ropes);
    rmsnorm_kernel<1><<<T_TOK, 256, 0, stream>>>(x, g1, xn);

    transpose_bf16<<<dim3(16, 16, 1), 256, 0, stream>>>(Wq, WqkvT, 1024, 1024, 0, 0);
    transpose_bf16<<<dim3(16, 16, 1), 256, 0, stream>>>(Wk, WqkvT + 1024 * 1024, 1024, 1024, 0, 0);
    transpose_bf16<<<dim3(16, 16, 1), 256, 0, stream>>>(Wv, WqkvT + 2048 * 1024, 1024, 1024, 0, 0);
    transpose_bf16<<<dim3(16, 16, 1), 256, 0, stream>>>(Wo, WoT, 1024, 1024, 0, 0);

    // QKV: qkvb(2048,3072) = xn @ [Wq|Wk|Wv]
    gemm_mfma<128, 0><<<dim3(24, 16, 1), 256, 0, stream>>>(
        xn, WqkvT, nullptr, qkvb, 1024, 1024, 3072, 0, 0, 0);

    rope_cvt_kernel<<<T_TOK, 512, 0, stream>>>(qkvb, ropec, ropes, Qh, Ql, Kh, Kl);
    vt_cvt_kernel<<<dim3(32, 32, 1), 256, 0, stream>>>(qkvb, Vtb);

    attn_mfma_kernel<<<dim3(16, 16, 2), 256, 0, stream>>>(Qh, Ql, Kh, Kl, Vtb, gtm, attno);

    // h = x + attno @ Wo  (BN=64 -> 256 blocks)
    gemm_mfma<64, 1><<<dim3(16, 16, 1), 256, 0, stream>>>(
        attno, WoT, x, hb, 1024, 1024, 1024, 0, 0, 0);
    rmsnorm_kernel<0><<<T_TOK, 256, 0, stream>>>(hb, g2, hnb);

    hipMemsetAsync(wfull, 0, (size_t)T_TOK * NE * 4, stream);
    hipMemsetAsync(slot, 0xFF, (size_t)T_TOK * NE * 4, stream);
    hipMemsetAsync(gsum, 0, 8 * 4, stream);

    gate_kernel<<<T_TOK / 4, 256, 0, stream>>>(hnb, Wgate, wfull, gsum);
    expert_select_kernel<<<NE, 1024, 0, stream>>>(wfull, sw, sidx, slot);
    gather_tok_kernel<<<NE * CAP, 256, 0, stream>>>(hnb, sidx, sw, tok);

    // fused MoE GEMMs reading f32 weights directly
    gemm_w1_fused<<<dim3(128, 8, 1), 256, 0, stream>>>(tok, W1, act);
    gemm_w2_fused<<<dim3(32, 16, 1), 256, 0, stream>>>(act, W2, oute);

    combine_kernel<<<T_TOK, 256, 0, stream>>>(hb, oute, slot, wfull, gsum, out);
}

// Round 9
// 356.577 us; speedup vs baseline: 6.3249x; 1.0440x over previous
//
#include <hip/hip_runtime.h>
#include <hip/hip_bf16.h>
#include <math.h>

#define T_TOK 2048
#define DMODEL 1024
#define NH 16
#define HD 64
#define S_LEN 1024
#define NE 8
#define CAP 256
#define DFF 4096

typedef __attribute__((ext_vector_type(8))) short bf16x8;
typedef __attribute__((ext_vector_type(4))) float f32x4;

__device__ inline unsigned short f2bf(float f) {
    union { float f; unsigned int u; } x; x.f = f;
    unsigned int u = x.u;
    unsigned int r = (u + 0x7FFFu + ((u >> 16) & 1u)) >> 16;
    return (unsigned short)r;
}

__device__ inline float bf2f(unsigned short h) {
    union { unsigned int u; float f; } x; x.u = (unsigned int)h << 16; return x.f;
}

// packed f32x2 -> bf16x2 (RTNE); lo in low 16 bits
__device__ inline unsigned int pkbf(float lo, float hi) {
    __hip_bfloat162 h2 = __float22bfloat162_rn(make_float2(lo, hi));
    unsigned int r;
    __builtin_memcpy(&r, &h2, 4);
    return r;
}

__device__ inline void gload16(const void* g, void* l) {
    __builtin_amdgcn_global_load_lds(
        (const __attribute__((address_space(1))) unsigned int*)g,
        (__attribute__((address_space(3))) unsigned int*)l, 16, 0, 0);
}

// ---------------- RoPE table (+ gsum zero) ----------------
__global__ void rope_table_kernel(float* __restrict__ rc, float* __restrict__ rs,
                                  float* __restrict__ gsum) {
    int s = blockIdx.x;
    int i = threadIdx.x;
    float invf = powf(10000.0f, -(float)(2 * i) / 64.0f);
    float ang = (float)s * invf;
    rc[s * 32 + i] = cosf(ang);
    rs[s * 32 + i] = sinf(ang);
    if (blockIdx.x == 0 && threadIdx.x < 8) gsum[threadIdx.x] = 0.f;
}

// ---------------- RMSNorm (OUTBF: 1 -> bf16 out, 0 -> f32 out) ----------------
template <int OUTBF>
__global__ __launch_bounds__(256) void rmsnorm_kernel(const float* __restrict__ x,
                                                      const float* __restrict__ g,
                                                      void* __restrict__ yv) {
    __shared__ float red[256];
    int t = blockIdx.x;
    int tid = threadIdx.x;
    const float* xr = x + (size_t)t * DMODEL;
    float ss = 0.f;
    for (int d = tid; d < DMODEL; d += 256) { float v = xr[d]; ss += v * v; }
    red[tid] = ss; __syncthreads();
    for (int o = 128; o > 0; o >>= 1) { if (tid < o) red[tid] += red[tid + o]; __syncthreads(); }
    float scale = 1.0f / sqrtf(red[0] / (float)DMODEL + 1e-6f);
    if (OUTBF) {
        unsigned short* yr = (unsigned short*)yv + (size_t)t * DMODEL;
        for (int d = tid; d < DMODEL; d += 256) yr[d] = f2bf(g[d] * xr[d] * scale);
    } else {
        float* yr = (float*)yv + (size_t)t * DMODEL;
        for (int d = tid; d < DMODEL; d += 256) yr[d] = g[d] * xr[d] * scale;
    }
}

// ---------------- fused QKV GEMM + RoPE + hi/lo + V-transpose ----------------
// grid (48,16): mat = bx>>4 (0=Q,1=K,2=V), head = bx&15 (BN=64 = one head), 128 rows/block
__global__ __launch_bounds__(256) void gemm_qkv_rope(const unsigned short* __restrict__ xn,
                                                     const float* __restrict__ Wq,
                                                     const float* __restrict__ Wk,
                                                     const float* __restrict__ Wv,
                                                     const float* __restrict__ rc,
                                                     const float* __restrict__ rs,
                                                     unsigned short* __restrict__ Qh,
                                                     unsigned short* __restrict__ Ql,
                                                     unsigned short* __restrict__ Kh,
                                                     unsigned short* __restrict__ Kl,
                                                     unsigned short* __restrict__ Vtb) {
    __shared__ unsigned short As[128 * 64];   // 16 KB
    __shared__ unsigned int Bp[64 * 32];      // 8 KB
    const int mat = blockIdx.x >> 4;
    const int h = blockIdx.x & 15;
    const float* B = ((mat == 0) ? Wq : (mat == 1) ? Wk : Wv) + h * 64;
    const int by = blockIdx.y * 128;
    const int tid = threadIdx.x, l = tid & 63, wid = tid >> 6;
    const int g = l >> 4;
    const int kp = tid >> 3;     // 0..31
    const int nc = tid & 7;      // 8-col chunk
    const int chunk = kp >> 2, within = kp & 3;

    f32x4 acc[2][4] = {};

    for (int k0 = 0; k0 < 1024; k0 += 64) {
        #pragma unroll
        for (int i = 0; i < 4; i++) {
            int c = i * 256 + tid;
            int row = c >> 3, sl = c & 7, gs = sl ^ (row & 7);
            gload16(xn + (size_t)(by + row) * 1024 + k0 + gs * 8, &As[c * 8]);
        }
        const float* Brow = B + (size_t)(k0 + 2 * kp) * 1024 + nc * 8;
        float4 a0 = *(const float4*)(Brow);
        float4 a1 = *(const float4*)(Brow + 4);
        float4 b0 = *(const float4*)(Brow + 1024);
        float4 b1 = *(const float4*)(Brow + 1028);
        unsigned int p[8];
        p[0] = pkbf(a0.x, b0.x); p[1] = pkbf(a0.y, b0.y);
        p[2] = pkbf(a0.z, b0.z); p[3] = pkbf(a0.w, b0.w);
        p[4] = pkbf(a1.x, b1.x); p[5] = pkbf(a1.y, b1.y);
        p[6] = pkbf(a1.z, b1.z); p[7] = pkbf(a1.w, b1.w);
        #pragma unroll
        for (int i = 0; i < 8; i++) {
            int n_loc = nc * 8 + i;
            int idx = n_loc * 32 + ((chunk ^ (n_loc & 7)) << 2) + within;
            Bp[idx] = p[i];
        }
        __syncthreads();
        #pragma unroll
        for (int ks = 0; ks < 2; ks++) {
            bf16x8 af[2];
            #pragma unroll
            for (int m = 0; m < 2; m++) {
                int row = wid * 32 + m * 16 + (l & 15);
                int sl = (ks * 4 + g) ^ (row & 7);
                af[m] = *(const bf16x8*)&As[row * 64 + sl * 8];
            }
            #pragma unroll
            for (int nf = 0; nf < 4; nf++) {
                int n_loc = nf * 16 + (l & 15);
                int base = n_loc * 32 + (((ks * 4 + g) ^ (n_loc & 7)) << 2);
                bf16x8 bfr = *(const bf16x8*)&Bp[base];
                #pragma unroll
                for (int m = 0; m < 2; m++)
                    acc[m][nf] = __builtin_amdgcn_mfma_f32_16x16x32_bf16(af[m], bfr, acc[m][nf], 0, 0, 0);
            }
        }
        __syncthreads();
    }

    if (mat < 2) {
        unsigned short* Dh = (mat == 0) ? Qh : Kh;
        unsigned short* Dl = (mat == 0) ? Ql : Kl;
        float scale = (mat == 0) ? 0.125f : 1.0f;
        #pragma unroll
        for (int m = 0; m < 2; m++)
            #pragma unroll
            for (int r = 0; r < 4; r++) {
                int t = by + wid * 32 + m * 16 + g * 4 + r;
                int b = t >> 10, s = t & 1023;
                size_t ob = ((size_t)(b * 16 + h) * 1024 + s) * 64;
                #pragma unroll
                for (int pr = 0; pr < 2; pr++) {
                    int i = pr * 16 + (l & 15);
                    float c = rc[s * 32 + i], sn = rs[s * 32 + i];
                    float a = acc[m][pr][r], bb = acc[m][pr + 2][r];
                    float v0 = (a * c - bb * sn) * scale;
                    float v1 = (bb * c + a * sn) * scale;
                    unsigned short h0 = f2bf(v0), h1 = f2bf(v1);
                    Dh[ob + i] = h0;      Dl[ob + i] = f2bf(v0 - bf2f(h0));
                    Dh[ob + i + 32] = h1; Dl[ob + i + 32] = f2bf(v1 - bf2f(h1));
                }
            }
    } else {
        #pragma unroll
        for (int m = 0; m < 2; m++) {
            int t0 = by + wid * 32 + m * 16 + g * 4;
            int b = t0 >> 10, s0 = t0 & 1023;
            #pragma unroll
            for (int nf = 0; nf < 4; nf++) {
                int d = nf * 16 + (l & 15);
                unsigned short tmp[4];
                #pragma unroll
                for (int r = 0; r < 4; r++) tmp[r] = f2bf(acc[m][nf][r]);
                *(uint2*)&Vtb[((size_t)(b * 16 + h) * 64 + d) * 1024 + s0] = *(uint2*)tmp;
            }
        }
    }
}

// ---------------- generic fused GEMM: C(f32) = A(bf16, M x K) @ B(f32, K x 1024) ----------------
// BM=128, BN=32; RES=1 adds Rr. Batched via blockIdx.z strides; m-blocks via blockIdx.y.
template <int RES>
__global__ __launch_bounds__(256) void gemm_bf32(const unsigned short* __restrict__ A,
                                                 const float* __restrict__ B,
                                                 const float* __restrict__ Rr,
                                                 float* __restrict__ C,
                                                 int K, int lda,
                                                 long long sA, long long sB, long long sC) {
    __shared__ unsigned short As[128 * 64];   // 16 KB
    __shared__ unsigned int Bp[32 * 32];      // 4 KB
    A += (long long)blockIdx.z * sA + (long long)blockIdx.y * 128 * lda;
    B += (long long)blockIdx.z * sB;
    C += (long long)blockIdx.z * sC + (long long)blockIdx.y * 128 * 1024;
    const float* Rp = RES ? (Rr + (long long)blockIdx.y * 128 * 1024) : nullptr;
    const int bx = blockIdx.x * 32;
    const int tid = threadIdx.x, l = tid & 63, wid = tid >> 6;
    const int g = l >> 4;
    const int kp = tid >> 3;
    const int nc = tid & 7;
    const int chunk = kp >> 2, within = kp & 3;

    f32x4 acc[2][2] = {};

    for (int k0 = 0; k0 < K; k0 += 64) {
        #pragma unroll
        for (int i = 0; i < 4; i++) {
            int c = i * 256 + tid;
            int row = c >> 3, sl = c & 7, gs = sl ^ (row & 7);
            gload16(A + (size_t)row * lda + k0 + gs * 8, &As[c * 8]);
        }
        const float* Brow = B + (size_t)(k0 + 2 * kp) * 1024 + bx + nc * 4;
        float4 a0 = *(const float4*)(Brow);
        float4 a1 = *(const float4*)(Brow + 1024);
        unsigned int p1[4];
        p1[0] = pkbf(a0.x, a1.x); p1[1] = pkbf(a0.y, a1.y);
        p1[2] = pkbf(a0.z, a1.z); p1[3] = pkbf(a0.w, a1.w);
        #pragma unroll
        for (int i = 0; i < 4; i++) {
            int n_loc = nc * 4 + i;
            int idx = n_loc * 32 + ((chunk ^ (n_loc & 7)) << 2) + within;
            Bp[idx] = p1[i];
        }
        __syncthreads();
        #pragma unroll
        for (int ks = 0; ks < 2; ks++) {
            bf16x8 af[2];
            #pragma unroll
            for (int m = 0; m < 2; m++) {
                int row = wid * 32 + m * 16 + (l & 15);
                int sl = (ks * 4 + g) ^ (row & 7);
                af[m] = *(const bf16x8*)&As[row * 64 + sl * 8];
            }
            #pragma unroll
            for (int nf = 0; nf < 2; nf++) {
                int n_loc = nf * 16 + (l & 15);
                int base = n_loc * 32 + (((ks * 4 + g) ^ (n_loc & 7)) << 2);
                bf16x8 bfr = *(const bf16x8*)&Bp[base];
                #pragma unroll
                for (int m = 0; m < 2; m++)
                    acc[m][nf] = __builtin_amdgcn_mfma_f32_16x16x32_bf16(af[m], bfr, acc[m][nf], 0, 0, 0);
            }
        }
        __syncthreads();
    }
    #pragma unroll
    for (int m = 0; m < 2; m++) {
        int row0 = wid * 32 + m * 16 + g * 4;
        #pragma unroll
        for (int nf = 0; nf < 2; nf++) {
            int col = bx + nf * 16 + (l & 15);
            #pragma unroll
            for (int r = 0; r < 4; r++) {
                size_t idx = (size_t)(row0 + r) * 1024 + col;
                float v = acc[m][nf][r];
                if (RES) v += Rp[idx];
                C[idx] = v;
            }
        }
    }
}

// ---------------- fused MoE W1 GEMM + SwiGLU ----------------
__global__ __launch_bounds__(256) void gemm_w1_fused(const unsigned short* __restrict__ tok,
                                                     const float* __restrict__ W1,
                                                     unsigned short* __restrict__ act) {
    __shared__ unsigned short As[256 * 64];   // 32 KB
    __shared__ unsigned int B1p[32 * 32];     // 4 KB
    __shared__ unsigned int B2p[32 * 32];     // 4 KB
    const int e = blockIdx.y;
    const int bx = blockIdx.x * 32;
    const unsigned short* A = tok + (size_t)e * CAP * DMODEL;
    const float* B = W1 + (size_t)e * DMODEL * (2 * DFF);
    unsigned short* C = act + (size_t)e * CAP * DFF;
    const int tid = threadIdx.x, l = tid & 63, wid = tid >> 6;
    const int g = l >> 4;
    const int kp = tid >> 3;
    const int nc = tid & 7;
    const int chunk = kp >> 2, within = kp & 3;

    f32x4 acc1[4][2] = {};
    f32x4 acc2[4][2] = {};

    for (int k0 = 0; k0 < DMODEL; k0 += 64) {
        #pragma unroll
        for (int i = 0; i < 8; i++) {
            int c = i * 256 + tid;
            int row = c >> 3, sl = c & 7, gs = sl ^ (row & 7);
            gload16(A + (size_t)row * DMODEL + k0 + gs * 8, &As[c * 8]);
        }
        const float* Brow = B + (size_t)(k0 + 2 * kp) * 8192 + bx + nc * 4;
        float4 a0 = *(const float4*)(Brow);
        float4 a1 = *(const float4*)(Brow + 8192);
        float4 c0 = *(const float4*)(Brow + 4096);
        float4 c1 = *(const float4*)(Brow + 4096 + 8192);
        unsigned int p1[4], p2[4];
        p1[0] = pkbf(a0.x, a1.x); p1[1] = pkbf(a0.y, a1.y);
        p1[2] = pkbf(a0.z, a1.z); p1[3] = pkbf(a0.w, a1.w);
        p2[0] = pkbf(c0.x, c1.x); p2[1] = pkbf(c0.y, c1.y);
        p2[2] = pkbf(c0.z, c1.z); p2[3] = pkbf(c0.w, c1.w);
        #pragma unroll
        for (int i = 0; i < 4; i++) {
            int n_loc = nc * 4 + i;
            int idx = n_loc * 32 + ((chunk ^ (n_loc & 7)) << 2) + within;
            B1p[idx] = p1[i];
            B2p[idx] = p2[i];
        }
        __syncthreads();
        #pragma unroll
        for (int ks = 0; ks < 2; ks++) {
            bf16x8 af[4];
            #pragma unroll
            for (int m = 0; m < 4; m++) {
                int row = wid * 64 + m * 16 + (l & 15);
                int sl = (ks * 4 + g) ^ (row & 7);
                af[m] = *(const bf16x8*)&As[row * 64 + sl * 8];
            }
            #pragma unroll
            for (int nf = 0; nf < 2; nf++) {
                int n_loc = nf * 16 + (l & 15);
                int base = n_loc * 32 + (((ks * 4 + g) ^ (n_loc & 7)) << 2);
                bf16x8 b1 = *(const bf16x8*)&B1p[base];
                bf16x8 b2 = *(const bf16x8*)&B2p[base];
                #pragma unroll
                for (int m = 0; m < 4; m++) {
                    acc1[m][nf] = __builtin_amdgcn_mfma_f32_16x16x32_bf16(af[m], b1, acc1[m][nf], 0, 0, 0);
                    acc2[m][nf] = __builtin_amdgcn_mfma_f32_16x16x32_bf16(af[m], b2, acc2[m][nf], 0, 0, 0);
                }
            }
        }
        __syncthreads();
    }
    #pragma unroll
    for (int m = 0; m < 4; m++) {
        int row0 = wid * 64 + m * 16 + g * 4;
        #pragma unroll
        for (int nf = 0; nf < 2; nf++) {
            int col = bx + nf * 16 + (l & 15);
            #pragma unroll
            for (int r = 0; r < 4; r++) {
                float h1 = acc1[m][nf][r], h2 = acc2[m][nf][r];
                float sil = h2 / (1.0f + __expf(-h2));
                C[(size_t)(row0 + r) * DFF + col] = f2bf(h1 * sil);
            }
        }
    }
}

// ---------------- flash-style MFMA attention, 16 q-rows per wave ----------------
__global__ __launch_bounds__(256) void attn_mfma_kernel(const unsigned short* __restrict__ Qh,
                                                        const unsigned short* __restrict__ Ql,
                                                        const unsigned short* __restrict__ Kh,
                                                        const unsigned short* __restrict__ Kl,
                                                        const unsigned short* __restrict__ Vtb,
                                                        const int* __restrict__ gtm,
                                                        unsigned short* __restrict__ o) {
    __shared__ unsigned short Ksh[64 * 64];
    __shared__ unsigned short Ksl[64 * 64];
    __shared__ unsigned short Vs[64 * 64];
    __shared__ unsigned short Pl[4][16 * 64];
    const int qt = blockIdx.x, h = blockIdx.y, b = blockIdx.z;
    const int bh = b * 16 + h;
    const int tid = threadIdx.x, l = tid & 63, w = tid >> 6;
    const int q0 = qt * 64 + w * 16;
    const unsigned short* Qhb = Qh + (size_t)bh * 1024 * 64;
    const unsigned short* Qlb = Ql + (size_t)bh * 1024 * 64;
    const unsigned short* Khb = Kh + (size_t)bh * 1024 * 64;
    const unsigned short* Klb = Kl + (size_t)bh * 1024 * 64;
    const unsigned short* Vbh = Vtb + (size_t)bh * 64 * 1024;
    const int* gb = gtm + b * 1024;

    bf16x8 afh[2], afl[2];
    #pragma unroll
    for (int ks = 0; ks < 2; ks++) {
        size_t off = (size_t)(q0 + (l & 15)) * 64 + ks * 32 + (l >> 4) * 8;
        afh[ks] = *(const bf16x8*)(Qhb + off);
        afl[ks] = *(const bf16x8*)(Qlb + off);
    }

    int gqm = 0;
    #pragma unroll
    for (int r = 0; r < 4; r++)
        gqm |= (gb[q0 + (l >> 4) * 4 + r] ? 1 : 0) << r;

    f32x4 acc_o[4] = {};
    float m_run[4], l_run[4];
    #pragma unroll
    for (int r = 0; r < 4; r++) { m_run[r] = -1e30f; l_run[r] = 0.f; }

    for (int jt = 0; jt < 16; jt++) {
        const int j0 = jt * 64;
        #pragma unroll
        for (int i = 0; i < 2; i++) {
            int c = i * 256 + tid, row = c >> 3, sl = c & 7, gs = sl ^ (row & 7);
            gload16(Khb + (size_t)(j0 + row) * 64 + gs * 8, &Ksh[c * 8]);
            gload16(Klb + (size_t)(j0 + row) * 64 + gs * 8, &Ksl[c * 8]);
            gload16(Vbh + (size_t)row * 1024 + j0 + gs * 8, &Vs[c * 8]);
        }
        __syncthreads();

        f32x4 sv[4] = {};
        #pragma unroll
        for (int n = 0; n < 4; n++) {
            #pragma unroll
            for (int ks = 0; ks < 2; ks++) {
                int row = n * 16 + (l & 15);
                int sl = (ks * 4 + (l >> 4)) ^ (row & 7);
                bf16x8 khf = *(const bf16x8*)&Ksh[row * 64 + sl * 8];
                bf16x8 klf = *(const bf16x8*)&Ksl[row * 64 + sl * 8];
                sv[n] = __builtin_amdgcn_mfma_f32_16x16x32_bf16(afl[ks], khf, sv[n], 0, 0, 0);
                sv[n] = __builtin_amdgcn_mfma_f32_16x16x32_bf16(afh[ks], klf, sv[n], 0, 0, 0);
                sv[n] = __builtin_amdgcn_mfma_f32_16x16x32_bf16(afh[ks], khf, sv[n], 0, 0, 0);
            }
        }

        int gk[4];
        #pragma unroll
        for (int n = 0; n < 4; n++) gk[n] = gb[j0 + n * 16 + (l & 15)];

        #pragma unroll
        for (int n = 0; n < 4; n++)
            #pragma unroll
            for (int r = 0; r < 4; r++) {
                int q = q0 + (l >> 4) * 4 + r;
                int k = j0 + n * 16 + (l & 15);
                bool allowed = ((gqm >> r) & 1) || gk[n] || ((k <= q) && (q - k < 256));
                if (!allowed) sv[n][r] = -1e30f;
            }

        {
            float tm[4], corr[4], rsum[4];
            #pragma unroll
            for (int r = 0; r < 4; r++)
                tm[r] = fmaxf(fmaxf(sv[0][r], sv[1][r]), fmaxf(sv[2][r], sv[3][r]));
            #pragma unroll
            for (int wd = 1; wd <= 8; wd <<= 1)
                #pragma unroll
                for (int r = 0; r < 4; r++) tm[r] = fmaxf(tm[r], __shfl_xor(tm[r], wd, 64));
            #pragma unroll
            for (int r = 0; r < 4; r++) {
                float mn = fmaxf(m_run[r], tm[r]);
                corr[r] = __expf(m_run[r] - mn);
                m_run[r] = mn;
                rsum[r] = 0.f;
            }
            #pragma unroll
            for (int n = 0; n < 4; n++)
                #pragma unroll
                for (int r = 0; r < 4; r++) {
                    float p = __expf(sv[n][r] - m_run[r]);
                    sv[n][r] = p;
                    rsum[r] += p;
                }
            #pragma unroll
            for (int wd = 1; wd <= 8; wd <<= 1)
                #pragma unroll
                for (int r = 0; r < 4; r++) rsum[r] += __shfl_xor(rsum[r], wd, 64);
            #pragma unroll
            for (int r = 0; r < 4; r++) l_run[r] = l_run[r] * corr[r] + rsum[r];
            #pragma unroll
            for (int nd = 0; nd < 4; nd++)
                #pragma unroll
                for (int r = 0; r < 4; r++) acc_o[nd][r] *= corr[r];
            #pragma unroll
            for (int n = 0; n < 4; n++)
                #pragma unroll
                for (int r = 0; r < 4; r++) {
                    int qr = (l >> 4) * 4 + r;
                    int kc = n * 16 + (l & 15);
                    int byte = (qr * 128 + kc * 2) ^ ((qr & 7) << 4);
                    Pl[w][byte >> 1] = f2bf(sv[n][r]);
                }
        }

        asm volatile("s_waitcnt lgkmcnt(0)" ::: "memory");
        __builtin_amdgcn_sched_barrier(0);

        #pragma unroll
        for (int ks = 0; ks < 2; ks++) {
            int prow = l & 15;
            int psl = (ks * 4 + (l >> 4)) ^ (prow & 7);
            bf16x8 pa = *(const bf16x8*)&Pl[w][prow * 64 + psl * 8];
            #pragma unroll
            for (int nd = 0; nd < 4; nd++) {
                int row = nd * 16 + (l & 15);
                int sl = (ks * 4 + (l >> 4)) ^ (row & 7);
                bf16x8 vf = *(const bf16x8*)&Vs[row * 64 + sl * 8];
                acc_o[nd] = __builtin_amdgcn_mfma_f32_16x16x32_bf16(pa, vf, acc_o[nd], 0, 0, 0);
            }
        }
        __syncthreads();
    }

    #pragma unroll
    for (int r = 0; r < 4; r++) {
        float inv = 1.0f / l_run[r];
        int t_ = b * 1024 + q0 + (l >> 4) * 4 + r;
        #pragma unroll
        for (int nd = 0; nd < 4; nd++) {
            int col = h * 64 + nd * 16 + (l & 15);
            o[(size_t)t_ * 1024 + col] = f2bf(acc_o[nd][r] * inv);
        }
    }
}

// ---------------- gate: one wave per token; writes all 8 wfull + slot=-1 ----------------
__global__ __launch_bounds__(256) void gate_kernel(const float* __restrict__ hn,
                                                   const float* __restrict__ Wgate,
                                                   float* __restrict__ wfull,
                                                   int* __restrict__ slot,
                                                   float* __restrict__ gate_sum) {
    int tid = threadIdx.x;
    int w = tid >> 6, l = tid & 63;
    int t = blockIdx.x * 4 + w;
    int e = l & 7, g = l >> 3;
    const float* xr = hn + (size_t)t * DMODEL;
    const float* wp = Wgate + l;
    float acc = 0.f;
    #pragma unroll 8
    for (int kk = 0; kk < 128; kk++)
        acc += xr[g + 8 * kk] * wp[64 * kk];
    #pragma unroll
    for (int o = 8; o < 64; o <<= 1) acc += __shfl_xor(acc, o, 64);
    float m = acc;
    #pragma unroll
    for (int o = 1; o < 8; o <<= 1) m = fmaxf(m, __shfl_xor(m, o, 64));
    float p = __expf(acc - m);
    float s = p;
    #pragma unroll
    for (int o = 1; o < 8; o <<= 1) s += __shfl_xor(s, o, 64);
    float pr = p / s;
    unsigned long long key = ((unsigned long long)__float_as_uint(pr) << 32) | (unsigned)(7 - e);
    unsigned long long k1 = key;
    #pragma unroll
    for (int o = 1; o < 8; o <<= 1) { unsigned long long t2 = __shfl_xor(k1, o, 64); if (t2 > k1) k1 = t2; }
    int e1 = 7 - (int)(k1 & 7);
    unsigned long long key2 = (e == e1) ? 0ull : key;
    unsigned long long k2 = key2;
    #pragma unroll
    for (int o = 1; o < 8; o <<= 1) { unsigned long long t2 = __shfl_xor(k2, o, 64); if (t2 > k2) k2 = t2; }
    int e2 = 7 - (int)(k2 & 7);
    if (l < 8) {
        wfull[t * 8 + e] = (e == e1 || e == e2) ? pr : 0.f;
        slot[t * 8 + e] = -1;
        atomicAdd(&gate_sum[e], pr);
    }
}

// ---------------- per-expert top-CAP via bitonic sort ----------------
__global__ __launch_bounds__(1024) void expert_select_kernel(const float* __restrict__ wfull,
                                                             float* __restrict__ sw,
                                                             int* __restrict__ sidx,
                                                             int* __restrict__ slot) {
    __shared__ unsigned long long keys[2048];
    int e = blockIdx.x;
    int t = threadIdx.x;
    for (int i = t; i < 2048; i += 1024) {
        float w = wfull[i * 8 + e];
        unsigned int wb = __float_as_uint(w);
        keys[i] = ((unsigned long long)wb << 32) | (unsigned long long)(0xFFFFFFFFu - (unsigned int)i);
    }
    __syncthreads();
    for (int k = 2; k <= 2048; k <<= 1) {
        for (int j = k >> 1; j > 0; j >>= 1) {
            for (int i = t; i < 2048; i += 1024) {
                int ixj = i ^ j;
                if (ixj > i) {
                    bool desc = ((i & k) == 0);
                    unsigned long long a = keys[i], b = keys[ixj];
                    if ((a < b) == desc) { keys[i] = b; keys[ixj] = a; }
                }
            }
            __syncthreads();
        }
    }
    if (t < CAP) {
        unsigned long long kk = keys[t];
        float w = __uint_as_float((unsigned int)(kk >> 32));
        int idx = (int)(0xFFFFFFFFu - (unsigned int)(kk & 0xFFFFFFFFu));
        sw[e * CAP + t] = w;
        sidx[e * CAP + t] = idx;
        if (w > 0.f) slot[idx * 8 + e] = t;
    }
}

// ---------------- gather tokens -> bf16 ----------------
__global__ __launch_bounds__(256) void gather_tok_kernel(const float* __restrict__ hn,
                                                         const int* __restrict__ sidx,
                                                         const float* __restrict__ sw,
                                                         unsigned short* __restrict__ tok) {
    int ec = blockIdx.x;
    int tid = threadIdx.x;
    float w = sw[ec];
    int src = sidx[ec];
    const float* s = hn + (size_t)src * DMODEL;
    unsigned short* d = tok + (size_t)ec * DMODEL;
    for (int i = tid; i < DMODEL; i += 256) d[i] = (w > 0.f) ? f2bf(s[i]) : 0;
}

// ---------------- final combine ----------------
__global__ __launch_bounds__(256) void combine_kernel(const float* __restrict__ h,
                                                      const float* __restrict__ out_e,
                                                      const int* __restrict__ slot,
                                                      const float* __restrict__ wfull,
                                                      const float* __restrict__ gate_sum,
                                                      float* __restrict__ out) {
    int t = blockIdx.x;
    int tid = threadIdx.x;
    for (int d = tid; d < DMODEL; d += 256) {
        float acc = h[(size_t)t * DMODEL + d];
        #pragma unroll
        for (int e = 0; e < 8; e++) {
            int c = slot[t * 8 + e];
            if (c >= 0) acc += wfull[t * 8 + e] * out_e[((size_t)(e * CAP + c)) * DMODEL + d];
        }
        out[(size_t)t * DMODEL + d] = acc;
    }
    if (t == 0 && tid == 0) {
        float a = 0.f;
        #pragma unroll
        for (int e = 0; e < 8; e++) { float m = gate_sum[e] / (float)T_TOK; a += m * m; }
        out[(size_t)T_TOK * DMODEL] = 8.0f * a;
    }
}

extern "C" void kernel_launch(void* const* d_in, const int* in_sizes, int n_in,
                              void* d_out, int out_size, void* d_ws, size_t ws_size,
                              hipStream_t stream) {
    const float* x     = (const float*)d_in[0];
    const int*   gtm   = (const int*)d_in[2];
    const float* Wq    = (const float*)d_in[3];
    const float* Wk    = (const float*)d_in[4];
    const float* Wv    = (const float*)d_in[5];
    const float* Wo    = (const float*)d_in[6];
    const float* g1    = (const float*)d_in[7];
    const float* g2    = (const float*)d_in[8];
    const float* Wgate = (const float*)d_in[9];
    const float* W1    = (const float*)d_in[10];
    const float* W2    = (const float*)d_in[11];
    float* out = (float*)d_out;

    char* ws = (char*)d_ws;
    unsigned short* Qh   = (unsigned short*)(ws + 0);           // 4 MB
    unsigned short* Ql   = (unsigned short*)(ws + 4194304);
    unsigned short* Kh   = (unsigned short*)(ws + 8388608);
    unsigned short* Kl   = (unsigned short*)(ws + 12582912);
    unsigned short* Vtb  = (unsigned short*)(ws + 16777216);    // ends 20971520
    unsigned short* act  = (unsigned short*)(ws + 0);           // 16.8 MB (MoE phase; Q/K dead)
    unsigned short* xn   = (unsigned short*)(ws + 20971520);    // 4.2 MB
    unsigned short* attno= (unsigned short*)(ws + 25165824);    // 4.2 MB
    float* hb    = (float*)(ws + 29360128);                     // 8.4 MB
    float* hnb   = (float*)(ws + 37748736);                     // 8.4 MB
    float* oute  = (float*)(ws + 46137344);                     // 8.4 MB
    unsigned short* tok = (unsigned short*)(ws + 54525952);     // 4.2 MB
    float* ropec = (float*)(ws + 58720256);
    float* ropes = (float*)(ws + 58851328);
    float* wfull = (float*)(ws + 58982400);
    int*   slot  = (int*)(ws + 59047936);
    float* sw    = (float*)(ws + 59113472);
    int*   sidx  = (int*)(ws + 59121664);
    float* gsum  = (float*)(ws + 59129856);

    rope_table_kernel<<<S_LEN, 32, 0, stream>>>(ropec, ropes, gsum);
    rmsnorm_kernel<1><<<T_TOK, 256, 0, stream>>>(x, g1, xn);

    // fused QKV GEMM + RoPE + hi/lo split + V transpose
    gemm_qkv_rope<<<dim3(48, 16, 1), 256, 0, stream>>>(
        xn, Wq, Wk, Wv, ropec, ropes, Qh, Ql, Kh, Kl, Vtb);

    attn_mfma_kernel<<<dim3(16, 16, 2), 256, 0, stream>>>(Qh, Ql, Kh, Kl, Vtb, gtm, attno);

    // h = x + attno @ Wo  (f32 Wo read directly)
    gemm_bf32<1><<<dim3(32, 16, 1), 256, 0, stream>>>(
        attno, Wo, x, hb, 1024, 1024, 0, 0, 0);
    rmsnorm_kernel<0><<<T_TOK, 256, 0, stream>>>(hb, g2, hnb);

    gate_kernel<<<T_TOK / 4, 256, 0, stream>>>(hnb, Wgate, wfull, slot, gsum);
    expert_select_kernel<<<NE, 1024, 0, stream>>>(wfull, sw, sidx, slot);
    gather_tok_kernel<<<NE * CAP, 256, 0, stream>>>(hnb, sidx, sw, tok);

    gemm_w1_fused<<<dim3(128, 8, 1), 256, 0, stream>>>(tok, W1, act);
    gemm_bf32<0><<<dim3(32, 2, 8), 256, 0, stream>>>(
        act, W2, nullptr, oute, 4096, 4096,
        (long long)CAP * DFF, (long long)DFF * 1024, (long long)CAP * 1024);

    combine_kernel<<<T_TOK, 256, 0, stream>>>(hb, oute, slot, wfull, gsum, out);
}

// Round 10
// 356.192 us; speedup vs baseline: 6.3317x; 1.0011x over previous
//
#include <hip/hip_runtime.h>
#include <hip/hip_bf16.h>
#include <math.h>

#define T_TOK 2048
#define DMODEL 1024
#define NH 16
#define HD 64
#define S_LEN 1024
#define NE 8
#define CAP 256
#define DFF 4096

typedef __attribute__((ext_vector_type(8))) short bf16x8;
typedef __attribute__((ext_vector_type(4))) float f32x4;

__device__ inline unsigned short f2bf(float f) {
    union { float f; unsigned int u; } x; x.f = f;
    unsigned int u = x.u;
    unsigned int r = (u + 0x7FFFu + ((u >> 16) & 1u)) >> 16;
    return (unsigned short)r;
}

__device__ inline float bf2f(unsigned short h) {
    union { unsigned int u; float f; } x; x.u = (unsigned int)h << 16; return x.f;
}

// packed f32x2 -> bf16x2 (RTNE); lo in low 16 bits
__device__ inline unsigned int pkbf(float lo, float hi) {
    __hip_bfloat162 h2 = __float22bfloat162_rn(make_float2(lo, hi));
    unsigned int r;
    __builtin_memcpy(&r, &h2, 4);
    return r;
}

__device__ inline void gload16(const void* g, void* l) {
    __builtin_amdgcn_global_load_lds(
        (const __attribute__((address_space(1))) unsigned int*)g,
        (__attribute__((address_space(3))) unsigned int*)l, 16, 0, 0);
}

// ---------------- RoPE table (+ gsum zero) ----------------
__global__ void rope_table_kernel(float* __restrict__ rc, float* __restrict__ rs,
                                  float* __restrict__ gsum) {
    int s = blockIdx.x;
    int i = threadIdx.x;
    float invf = powf(10000.0f, -(float)(2 * i) / 64.0f);
    float ang = (float)s * invf;
    rc[s * 32 + i] = cosf(ang);
    rs[s * 32 + i] = sinf(ang);
    if (blockIdx.x == 0 && threadIdx.x < 8) gsum[threadIdx.x] = 0.f;
}

// ---------------- RMSNorm (OUTBF: 1 -> bf16 out, 0 -> f32 out) ----------------
template <int OUTBF>
__global__ __launch_bounds__(256) void rmsnorm_kernel(const float* __restrict__ x,
                                                      const float* __restrict__ g,
                                                      void* __restrict__ yv) {
    __shared__ float red[256];
    int t = blockIdx.x;
    int tid = threadIdx.x;
    const float* xr = x + (size_t)t * DMODEL;
    float ss = 0.f;
    for (int d = tid; d < DMODEL; d += 256) { float v = xr[d]; ss += v * v; }
    red[tid] = ss; __syncthreads();
    for (int o = 128; o > 0; o >>= 1) { if (tid < o) red[tid] += red[tid + o]; __syncthreads(); }
    float scale = 1.0f / sqrtf(red[0] / (float)DMODEL + 1e-6f);
    if (OUTBF) {
        unsigned short* yr = (unsigned short*)yv + (size_t)t * DMODEL;
        for (int d = tid; d < DMODEL; d += 256) yr[d] = f2bf(g[d] * xr[d] * scale);
    } else {
        float* yr = (float*)yv + (size_t)t * DMODEL;
        for (int d = tid; d < DMODEL; d += 256) yr[d] = g[d] * xr[d] * scale;
    }
}

// ---------------- fused QKV GEMM + RoPE + hi/lo + V-transpose ----------------
// grid (48,16): mat = bx>>4 (0=Q,1=K,2=V), head = bx&15 (BN=64 = one head), 128 rows/block
__global__ __launch_bounds__(256) void gemm_qkv_rope(const unsigned short* __restrict__ xn,
                                                     const float* __restrict__ Wq,
                                                     const float* __restrict__ Wk,
                                                     const float* __restrict__ Wv,
                                                     const float* __restrict__ rc,
                                                     const float* __restrict__ rs,
                                                     unsigned short* __restrict__ Qh,
                                                     unsigned short* __restrict__ Ql,
                                                     unsigned short* __restrict__ Kh,
                                                     unsigned short* __restrict__ Kl,
                                                     unsigned short* __restrict__ Vtb) {
    __shared__ unsigned short As[128 * 64];   // 16 KB
    __shared__ unsigned int Bp[64 * 32];      // 8 KB
    const int mat = blockIdx.x >> 4;
    const int h = blockIdx.x & 15;
    const float* B = ((mat == 0) ? Wq : (mat == 1) ? Wk : Wv) + h * 64;
    const int by = blockIdx.y * 128;
    const int tid = threadIdx.x, l = tid & 63, wid = tid >> 6;
    const int g = l >> 4;
    const int kp = tid >> 3;     // 0..31
    const int nc = tid & 7;      // 8-col chunk
    const int chunk = kp >> 2, within = kp & 3;

    f32x4 acc[2][4] = {};

    for (int k0 = 0; k0 < 1024; k0 += 64) {
        #pragma unroll
        for (int i = 0; i < 4; i++) {
            int c = i * 256 + tid;
            int row = c >> 3, sl = c & 7, gs = sl ^ (row & 7);
            gload16(xn + (size_t)(by + row) * 1024 + k0 + gs * 8, &As[c * 8]);
        }
        const float* Brow = B + (size_t)(k0 + 2 * kp) * 1024 + nc * 8;
        float4 a0 = *(const float4*)(Brow);
        float4 a1 = *(const float4*)(Brow + 4);
        float4 b0 = *(const float4*)(Brow + 1024);
        float4 b1 = *(const float4*)(Brow + 1028);
        unsigned int p[8];
        p[0] = pkbf(a0.x, b0.x); p[1] = pkbf(a0.y, b0.y);
        p[2] = pkbf(a0.z, b0.z); p[3] = pkbf(a0.w, b0.w);
        p[4] = pkbf(a1.x, b1.x); p[5] = pkbf(a1.y, b1.y);
        p[6] = pkbf(a1.z, b1.z); p[7] = pkbf(a1.w, b1.w);
        #pragma unroll
        for (int i = 0; i < 8; i++) {
            int n_loc = nc * 8 + i;
            int idx = n_loc * 32 + ((chunk ^ (n_loc & 7)) << 2) + within;
            Bp[idx] = p[i];
        }
        __syncthreads();
        #pragma unroll
        for (int ks = 0; ks < 2; ks++) {
            bf16x8 af[2];
            #pragma unroll
            for (int m = 0; m < 2; m++) {
                int row = wid * 32 + m * 16 + (l & 15);
                int sl = (ks * 4 + g) ^ (row & 7);
                af[m] = *(const bf16x8*)&As[row * 64 + sl * 8];
            }
            #pragma unroll
            for (int nf = 0; nf < 4; nf++) {
                int n_loc = nf * 16 + (l & 15);
                int base = n_loc * 32 + (((ks * 4 + g) ^ (n_loc & 7)) << 2);
                bf16x8 bfr = *(const bf16x8*)&Bp[base];
                #pragma unroll
                for (int m = 0; m < 2; m++)
                    acc[m][nf] = __builtin_amdgcn_mfma_f32_16x16x32_bf16(af[m], bfr, acc[m][nf], 0, 0, 0);
            }
        }
        __syncthreads();
    }

    if (mat < 2) {
        unsigned short* Dh = (mat == 0) ? Qh : Kh;
        unsigned short* Dl = (mat == 0) ? Ql : Kl;
        float scale = (mat == 0) ? 0.125f : 1.0f;
        #pragma unroll
        for (int m = 0; m < 2; m++)
            #pragma unroll
            for (int r = 0; r < 4; r++) {
                int t = by + wid * 32 + m * 16 + g * 4 + r;
                int b = t >> 10, s = t & 1023;
                size_t ob = ((size_t)(b * 16 + h) * 1024 + s) * 64;
                #pragma unroll
                for (int pr = 0; pr < 2; pr++) {
                    int i = pr * 16 + (l & 15);
                    float c = rc[s * 32 + i], sn = rs[s * 32 + i];
                    float a = acc[m][pr][r], bb = acc[m][pr + 2][r];
                    float v0 = (a * c - bb * sn) * scale;
                    float v1 = (bb * c + a * sn) * scale;
                    unsigned short h0 = f2bf(v0), h1 = f2bf(v1);
                    Dh[ob + i] = h0;      Dl[ob + i] = f2bf(v0 - bf2f(h0));
                    Dh[ob + i + 32] = h1; Dl[ob + i + 32] = f2bf(v1 - bf2f(h1));
                }
            }
    } else {
        #pragma unroll
        for (int m = 0; m < 2; m++) {
            int t0 = by + wid * 32 + m * 16 + g * 4;
            int b = t0 >> 10, s0 = t0 & 1023;
            #pragma unroll
            for (int nf = 0; nf < 4; nf++) {
                int d = nf * 16 + (l & 15);
                unsigned short tmp[4];
                #pragma unroll
                for (int r = 0; r < 4; r++) tmp[r] = f2bf(acc[m][nf][r]);
                *(uint2*)&Vtb[((size_t)(b * 16 + h) * 64 + d) * 1024 + s0] = *(uint2*)tmp;
            }
        }
    }
}

// ---------------- generic fused GEMM: C(f32) = A(bf16, M x K) @ B(f32, K x 1024) ----------------
// BM=128, BN=32; RES=1 adds Rr. Batched via blockIdx.z strides; m-blocks via blockIdx.y.
template <int RES>
__global__ __launch_bounds__(256) void gemm_bf32(const unsigned short* __restrict__ A,
                                                 const float* __restrict__ B,
                                                 const float* __restrict__ Rr,
                                                 float* __restrict__ C,
                                                 int K, int lda,
                                                 long long sA, long long sB, long long sC) {
    __shared__ unsigned short As[128 * 64];   // 16 KB
    __shared__ unsigned int Bp[32 * 32];      // 4 KB
    A += (long long)blockIdx.z * sA + (long long)blockIdx.y * 128 * lda;
    B += (long long)blockIdx.z * sB;
    C += (long long)blockIdx.z * sC + (long long)blockIdx.y * 128 * 1024;
    const float* Rp = RES ? (Rr + (long long)blockIdx.y * 128 * 1024) : nullptr;
    const int bx = blockIdx.x * 32;
    const int tid = threadIdx.x, l = tid & 63, wid = tid >> 6;
    const int g = l >> 4;
    const int kp = tid >> 3;
    const int nc = tid & 7;
    const int chunk = kp >> 2, within = kp & 3;

    f32x4 acc[2][2] = {};

    for (int k0 = 0; k0 < K; k0 += 64) {
        #pragma unroll
        for (int i = 0; i < 4; i++) {
            int c = i * 256 + tid;
            int row = c >> 3, sl = c & 7, gs = sl ^ (row & 7);
            gload16(A + (size_t)row * lda + k0 + gs * 8, &As[c * 8]);
        }
        const float* Brow = B + (size_t)(k0 + 2 * kp) * 1024 + bx + nc * 4;
        float4 a0 = *(const float4*)(Brow);
        float4 a1 = *(const float4*)(Brow + 1024);
        unsigned int p1[4];
        p1[0] = pkbf(a0.x, a1.x); p1[1] = pkbf(a0.y, a1.y);
        p1[2] = pkbf(a0.z, a1.z); p1[3] = pkbf(a0.w, a1.w);
        #pragma unroll
        for (int i = 0; i < 4; i++) {
            int n_loc = nc * 4 + i;
            int idx = n_loc * 32 + ((chunk ^ (n_loc & 7)) << 2) + within;
            Bp[idx] = p1[i];
        }
        __syncthreads();
        #pragma unroll
        for (int ks = 0; ks < 2; ks++) {
            bf16x8 af[2];
            #pragma unroll
            for (int m = 0; m < 2; m++) {
                int row = wid * 32 + m * 16 + (l & 15);
                int sl = (ks * 4 + g) ^ (row & 7);
                af[m] = *(const bf16x8*)&As[row * 64 + sl * 8];
            }
            #pragma unroll
            for (int nf = 0; nf < 2; nf++) {
                int n_loc = nf * 16 + (l & 15);
                int base = n_loc * 32 + (((ks * 4 + g) ^ (n_loc & 7)) << 2);
                bf16x8 bfr = *(const bf16x8*)&Bp[base];
                #pragma unroll
                for (int m = 0; m < 2; m++)
                    acc[m][nf] = __builtin_amdgcn_mfma_f32_16x16x32_bf16(af[m], bfr, acc[m][nf], 0, 0, 0);
            }
        }
        __syncthreads();
    }
    #pragma unroll
    for (int m = 0; m < 2; m++) {
        int row0 = wid * 32 + m * 16 + g * 4;
        #pragma unroll
        for (int nf = 0; nf < 2; nf++) {
            int col = bx + nf * 16 + (l & 15);
            #pragma unroll
            for (int r = 0; r < 4; r++) {
                size_t idx = (size_t)(row0 + r) * 1024 + col;
                float v = acc[m][nf][r];
                if (RES) v += Rp[idx];
                C[idx] = v;
            }
        }
    }
}

// ---------------- fused MoE W1 GEMM + SwiGLU ----------------
__global__ __launch_bounds__(256) void gemm_w1_fused(const unsigned short* __restrict__ tok,
                                                     const float* __restrict__ W1,
                                                     unsigned short* __restrict__ act) {
    __shared__ unsigned short As[256 * 64];   // 32 KB
    __shared__ unsigned int B1p[32 * 32];     // 4 KB
    __shared__ unsigned int B2p[32 * 32];     // 4 KB
    const int e = blockIdx.y;
    const int bx = blockIdx.x * 32;
    const unsigned short* A = tok + (size_t)e * CAP * DMODEL;
    const float* B = W1 + (size_t)e * DMODEL * (2 * DFF);
    unsigned short* C = act + (size_t)e * CAP * DFF;
    const int tid = threadIdx.x, l = tid & 63, wid = tid >> 6;
    const int g = l >> 4;
    const int kp = tid >> 3;
    const int nc = tid & 7;
    const int chunk = kp >> 2, within = kp & 3;

    f32x4 acc1[4][2] = {};
    f32x4 acc2[4][2] = {};

    for (int k0 = 0; k0 < DMODEL; k0 += 64) {
        #pragma unroll
        for (int i = 0; i < 8; i++) {
            int c = i * 256 + tid;
            int row = c >> 3, sl = c & 7, gs = sl ^ (row & 7);
            gload16(A + (size_t)row * DMODEL + k0 + gs * 8, &As[c * 8]);
        }
        const float* Brow = B + (size_t)(k0 + 2 * kp) * 8192 + bx + nc * 4;
        float4 a0 = *(const float4*)(Brow);
        float4 a1 = *(const float4*)(Brow + 8192);
        float4 c0 = *(const float4*)(Brow + 4096);
        float4 c1 = *(const float4*)(Brow + 4096 + 8192);
        unsigned int p1[4], p2[4];
        p1[0] = pkbf(a0.x, a1.x); p1[1] = pkbf(a0.y, a1.y);
        p1[2] = pkbf(a0.z, a1.z); p1[3] = pkbf(a0.w, a1.w);
        p2[0] = pkbf(c0.x, c1.x); p2[1] = pkbf(c0.y, c1.y);
        p2[2] = pkbf(c0.z, c1.z); p2[3] = pkbf(c0.w, c1.w);
        #pragma unroll
        for (int i = 0; i < 4; i++) {
            int n_loc = nc * 4 + i;
            int idx = n_loc * 32 + ((chunk ^ (n_loc & 7)) << 2) + within;
            B1p[idx] = p1[i];
            B2p[idx] = p2[i];
        }
        __syncthreads();
        #pragma unroll
        for (int ks = 0; ks < 2; ks++) {
            bf16x8 af[4];
            #pragma unroll
            for (int m = 0; m < 4; m++) {
                int row = wid * 64 + m * 16 + (l & 15);
                int sl = (ks * 4 + g) ^ (row & 7);
                af[m] = *(const bf16x8*)&As[row * 64 + sl * 8];
            }
            #pragma unroll
            for (int nf = 0; nf < 2; nf++) {
                int n_loc = nf * 16 + (l & 15);
                int base = n_loc * 32 + (((ks * 4 + g) ^ (n_loc & 7)) << 2);
                bf16x8 b1 = *(const bf16x8*)&B1p[base];
                bf16x8 b2 = *(const bf16x8*)&B2p[base];
                #pragma unroll
                for (int m = 0; m < 4; m++) {
                    acc1[m][nf] = __builtin_amdgcn_mfma_f32_16x16x32_bf16(af[m], b1, acc1[m][nf], 0, 0, 0);
                    acc2[m][nf] = __builtin_amdgcn_mfma_f32_16x16x32_bf16(af[m], b2, acc2[m][nf], 0, 0, 0);
                }
            }
        }
        __syncthreads();
    }
    #pragma unroll
    for (int m = 0; m < 4; m++) {
        int row0 = wid * 64 + m * 16 + g * 4;
        #pragma unroll
        for (int nf = 0; nf < 2; nf++) {
            int col = bx + nf * 16 + (l & 15);
            #pragma unroll
            for (int r = 0; r < 4; r++) {
                float h1 = acc1[m][nf][r], h2 = acc2[m][nf][r];
                float sil = h2 / (1.0f + __expf(-h2));
                C[(size_t)(row0 + r) * DFF + col] = f2bf(h1 * sil);
            }
        }
    }
}

// ---------------- flash-style MFMA attention, 16 q-rows per wave ----------------
__global__ __launch_bounds__(256) void attn_mfma_kernel(const unsigned short* __restrict__ Qh,
                                                        const unsigned short* __restrict__ Ql,
                                                        const unsigned short* __restrict__ Kh,
                                                        const unsigned short* __restrict__ Kl,
                                                        const unsigned short* __restrict__ Vtb,
                                                        const int* __restrict__ gtm,
                                                        unsigned short* __restrict__ o) {
    __shared__ unsigned short Ksh[64 * 64];
    __shared__ unsigned short Ksl[64 * 64];
    __shared__ unsigned short Vs[64 * 64];
    __shared__ unsigned short Pl[4][16 * 64];
    const int qt = blockIdx.x, h = blockIdx.y, b = blockIdx.z;
    const int bh = b * 16 + h;
    const int tid = threadIdx.x, l = tid & 63, w = tid >> 6;
    const int q0 = qt * 64 + w * 16;
    const unsigned short* Qhb = Qh + (size_t)bh * 1024 * 64;
    const unsigned short* Qlb = Ql + (size_t)bh * 1024 * 64;
    const unsigned short* Khb = Kh + (size_t)bh * 1024 * 64;
    const unsigned short* Klb = Kl + (size_t)bh * 1024 * 64;
    const unsigned short* Vbh = Vtb + (size_t)bh * 64 * 1024;
    const int* gb = gtm + b * 1024;

    bf16x8 afh[2], afl[2];
    #pragma unroll
    for (int ks = 0; ks < 2; ks++) {
        size_t off = (size_t)(q0 + (l & 15)) * 64 + ks * 32 + (l >> 4) * 8;
        afh[ks] = *(const bf16x8*)(Qhb + off);
        afl[ks] = *(const bf16x8*)(Qlb + off);
    }

    int gqm = 0;
    #pragma unroll
    for (int r = 0; r < 4; r++)
        gqm |= (gb[q0 + (l >> 4) * 4 + r] ? 1 : 0) << r;

    f32x4 acc_o[4] = {};
    float m_run[4], l_run[4];
    #pragma unroll
    for (int r = 0; r < 4; r++) { m_run[r] = -1e30f; l_run[r] = 0.f; }

    for (int jt = 0; jt < 16; jt++) {
        const int j0 = jt * 64;
        #pragma unroll
        for (int i = 0; i < 2; i++) {
            int c = i * 256 + tid, row = c >> 3, sl = c & 7, gs = sl ^ (row & 7);
            gload16(Khb + (size_t)(j0 + row) * 64 + gs * 8, &Ksh[c * 8]);
            gload16(Klb + (size_t)(j0 + row) * 64 + gs * 8, &Ksl[c * 8]);
            gload16(Vbh + (size_t)row * 1024 + j0 + gs * 8, &Vs[c * 8]);
        }
        __syncthreads();

        f32x4 sv[4] = {};
        #pragma unroll
        for (int n = 0; n < 4; n++) {
            #pragma unroll
            for (int ks = 0; ks < 2; ks++) {
                int row = n * 16 + (l & 15);
                int sl = (ks * 4 + (l >> 4)) ^ (row & 7);
                bf16x8 khf = *(const bf16x8*)&Ksh[row * 64 + sl * 8];
                bf16x8 klf = *(const bf16x8*)&Ksl[row * 64 + sl * 8];
                sv[n] = __builtin_amdgcn_mfma_f32_16x16x32_bf16(afl[ks], khf, sv[n], 0, 0, 0);
                sv[n] = __builtin_amdgcn_mfma_f32_16x16x32_bf16(afh[ks], klf, sv[n], 0, 0, 0);
                sv[n] = __builtin_amdgcn_mfma_f32_16x16x32_bf16(afh[ks], khf, sv[n], 0, 0, 0);
            }
        }

        int gk[4];
        #pragma unroll
        for (int n = 0; n < 4; n++) gk[n] = gb[j0 + n * 16 + (l & 15)];

        #pragma unroll
        for (int n = 0; n < 4; n++)
            #pragma unroll
            for (int r = 0; r < 4; r++) {
                int q = q0 + (l >> 4) * 4 + r;
                int k = j0 + n * 16 + (l & 15);
                bool allowed = ((gqm >> r) & 1) || gk[n] || ((k <= q) && (q - k < 256));
                if (!allowed) sv[n][r] = -1e30f;
            }

        {
            float tm[4], corr[4], rsum[4];
            #pragma unroll
            for (int r = 0; r < 4; r++)
                tm[r] = fmaxf(fmaxf(sv[0][r], sv[1][r]), fmaxf(sv[2][r], sv[3][r]));
            #pragma unroll
            for (int wd = 1; wd <= 8; wd <<= 1)
                #pragma unroll
                for (int r = 0; r < 4; r++) tm[r] = fmaxf(tm[r], __shfl_xor(tm[r], wd, 64));
            #pragma unroll
            for (int r = 0; r < 4; r++) {
                float mn = fmaxf(m_run[r], tm[r]);
                corr[r] = __expf(m_run[r] - mn);
                m_run[r] = mn;
                rsum[r] = 0.f;
            }
            #pragma unroll
            for (int n = 0; n < 4; n++)
                #pragma unroll
                for (int r = 0; r < 4; r++) {
                    float p = __expf(sv[n][r] - m_run[r]);
                    sv[n][r] = p;
                    rsum[r] += p;
                }
            #pragma unroll
            for (int wd = 1; wd <= 8; wd <<= 1)
                #pragma unroll
                for (int r = 0; r < 4; r++) rsum[r] += __shfl_xor(rsum[r], wd, 64);
            #pragma unroll
            for (int r = 0; r < 4; r++) l_run[r] = l_run[r] * corr[r] + rsum[r];
            #pragma unroll
            for (int nd = 0; nd < 4; nd++)
                #pragma unroll
                for (int r = 0; r < 4; r++) acc_o[nd][r] *= corr[r];
            #pragma unroll
            for (int n = 0; n < 4; n++)
                #pragma unroll
                for (int r = 0; r < 4; r++) {
                    int qr = (l >> 4) * 4 + r;
                    int kc = n * 16 + (l & 15);
                    int byte = (qr * 128 + kc * 2) ^ ((qr & 7) << 4);
                    Pl[w][byte >> 1] = f2bf(sv[n][r]);
                }
        }

        asm volatile("s_waitcnt lgkmcnt(0)" ::: "memory");
        __builtin_amdgcn_sched_barrier(0);

        #pragma unroll
        for (int ks = 0; ks < 2; ks++) {
            int prow = l & 15;
            int psl = (ks * 4 + (l >> 4)) ^ (prow & 7);
            bf16x8 pa = *(const bf16x8*)&Pl[w][prow * 64 + psl * 8];
            #pragma unroll
            for (int nd = 0; nd < 4; nd++) {
                int row = nd * 16 + (l & 15);
                int sl = (ks * 4 + (l >> 4)) ^ (row & 7);
                bf16x8 vf = *(const bf16x8*)&Vs[row * 64 + sl * 8];
                acc_o[nd] = __builtin_amdgcn_mfma_f32_16x16x32_bf16(pa, vf, acc_o[nd], 0, 0, 0);
            }
        }
        __syncthreads();
    }

    #pragma unroll
    for (int r = 0; r < 4; r++) {
        float inv = 1.0f / l_run[r];
        int t_ = b * 1024 + q0 + (l >> 4) * 4 + r;
        #pragma unroll
        for (int nd = 0; nd < 4; nd++) {
            int col = h * 64 + nd * 16 + (l & 15);
            o[(size_t)t_ * 1024 + col] = f2bf(acc_o[nd][r] * inv);
        }
    }
}

// ---------------- gate: one wave per token; writes all 8 wfull + slot=-1 ----------------
__global__ __launch_bounds__(256) void gate_kernel(const float* __restrict__ hn,
                                                   const float* __restrict__ Wgate,
                                                   float* __restrict__ wfull,
                                                   int* __restrict__ slot,
                                                   float* __restrict__ gate_sum) {
    int tid = threadIdx.x;
    int w = tid >> 6, l = tid & 63;
    int t = blockIdx.x * 4 + w;
    int e = l & 7, g = l >> 3;
    const float* xr = hn + (size_t)t * DMODEL;
    const float* wp = Wgate + l;
    float acc = 0.f;
    #pragma unroll 8
    for (int kk = 0; kk < 128; kk++)
        acc += xr[g + 8 * kk] * wp[64 * kk];
    #pragma unroll
    for (int o = 8; o < 64; o <<= 1) acc += __shfl_xor(acc, o, 64);
    float m = acc;
    #pragma unroll
    for (int o = 1; o < 8; o <<= 1) m = fmaxf(m, __shfl_xor(m, o, 64));
    float p = __expf(acc - m);
    float s = p;
    #pragma unroll
    for (int o = 1; o < 8; o <<= 1) s += __shfl_xor(s, o, 64);
    float pr = p / s;
    unsigned long long key = ((unsigned long long)__float_as_uint(pr) << 32) | (unsigned)(7 - e);
    unsigned long long k1 = key;
    #pragma unroll
    for (int o = 1; o < 8; o <<= 1) { unsigned long long t2 = __shfl_xor(k1, o, 64); if (t2 > k1) k1 = t2; }
    int e1 = 7 - (int)(k1 & 7);
    unsigned long long key2 = (e == e1) ? 0ull : key;
    unsigned long long k2 = key2;
    #pragma unroll
    for (int o = 1; o < 8; o <<= 1) { unsigned long long t2 = __shfl_xor(k2, o, 64); if (t2 > k2) k2 = t2; }
    int e2 = 7 - (int)(k2 & 7);
    if (l < 8) {
        wfull[t * 8 + e] = (e == e1 || e == e2) ? pr : 0.f;
        slot[t * 8 + e] = -1;
        atomicAdd(&gate_sum[e], pr);
    }
}

// ---------------- per-expert top-CAP via bitonic sort ----------------
__global__ __launch_bounds__(1024) void expert_select_kernel(const float* __restrict__ wfull,
                                                             float* __restrict__ sw,
                                                             int* __restrict__ sidx,
                                                             int* __restrict__ slot) {
    __shared__ unsigned long long keys[2048];
    int e = blockIdx.x;
    int t = threadIdx.x;
    for (int i = t; i < 2048; i += 1024) {
        float w = wfull[i * 8 + e];
        unsigned int wb = __float_as_uint(w);
        keys[i] = ((unsigned long long)wb << 32) | (unsigned long long)(0xFFFFFFFFu - (unsigned int)i);
    }
    __syncthreads();
    for (int k = 2; k <= 2048; k <<= 1) {
        for (int j = k >> 1; j > 0; j >>= 1) {
            for (int i = t; i < 2048; i += 1024) {
                int ixj = i ^ j;
                if (ixj > i) {
                    bool desc = ((i & k) == 0);
                    unsigned long long a = keys[i], b = keys[ixj];
                    if ((a < b) == desc) { keys[i] = b; keys[ixj] = a; }
                }
            }
            __syncthreads();
        }
    }
    if (t < CAP) {
        unsigned long long kk = keys[t];
        float w = __uint_as_float((unsigned int)(kk >> 32));
        int idx = (int)(0xFFFFFFFFu - (unsigned int)(kk & 0xFFFFFFFFu));
        sw[e * CAP + t] = w;
        sidx[e * CAP + t] = idx;
        if (w > 0.f) slot[idx * 8 + e] = t;
    }
}

// ---------------- gather tokens -> bf16 ----------------
__global__ __launch_bounds__(256) void gather_tok_kernel(const float* __restrict__ hn,
                                                         const int* __restrict__ sidx,
                                                         const float* __restrict__ sw,
                                                         unsigned short* __restrict__ tok) {
    int ec = blockIdx.x;
    int tid = threadIdx.x;
    float w = sw[ec];
    int src = sidx[ec];
    const float* s = hn + (size_t)src * DMODEL;
    unsigned short* d = tok + (size_t)ec * DMODEL;
    for (int i = tid; i < DMODEL; i += 256) d[i] = (w > 0.f) ? f2bf(s[i]) : 0;
}

// ---------------- final combine ----------------
__global__ __launch_bounds__(256) void combine_kernel(const float* __restrict__ h,
                                                      const float* __restrict__ out_e,
                                                      const int* __restrict__ slot,
                                                      const float* __restrict__ wfull,
                                                      const float* __restrict__ gate_sum,
                                                      float* __restrict__ out) {
    int t = blockIdx.x;
    int tid = threadIdx.x;
    for (int d = tid; d < DMODEL; d += 256) {
        float acc = h[(size_t)t * DMODEL + d];
        #pragma unroll
        for (int e = 0; e < 8; e++) {
            int c = slot[t * 8 + e];
            if (c >= 0) acc += wfull[t * 8 + e] * out_e[((size_t)(e * CAP + c)) * DMODEL + d];
        }
        out[(size_t)t * DMODEL + d] = acc;
    }
    if (t == 0 && tid == 0) {
        float a = 0.f;
        #pragma unroll
        for (int e = 0; e < 8; e++) { float m = gate_sum[e] / (float)T_TOK; a += m * m; }
        out[(size_t)T_TOK * DMODEL] = 8.0f * a;
    }
}

extern "C" void kernel_launch(void* const* d_in, const int* in_sizes, int n_in,
                              void* d_out, int out_size, void* d_ws, size_t ws_size,
                              hipStream_t stream) {
    const float* x     = (const float*)d_in[0];
    const int*   gtm   = (const int*)d_in[2];
    const float* Wq    = (const float*)d_in[3];
    const float* Wk    = (const float*)d_in[4];
    const float* Wv    = (const float*)d_in[5];
    const float* Wo    = (const float*)d_in[6];
    const float* g1    = (const float*)d_in[7];
    const float* g2    = (const float*)d_in[8];
    const float* Wgate = (const float*)d_in[9];
    const float* W1    = (const float*)d_in[10];
    const float* W2    = (const float*)d_in[11];
    float* out = (float*)d_out;

    char* ws = (char*)d_ws;
    unsigned short* Qh   = (unsigned short*)(ws + 0);           // 4 MB
    unsigned short* Ql   = (unsigned short*)(ws + 4194304);
    unsigned short* Kh   = (unsigned short*)(ws + 8388608);
    unsigned short* Kl   = (unsigned short*)(ws + 12582912);
    unsigned short* Vtb  = (unsigned short*)(ws + 16777216);    // ends 20971520
    unsigned short* act  = (unsigned short*)(ws + 0);           // 16.8 MB (MoE phase; Q/K dead)
    unsigned short* xn   = (unsigned short*)(ws + 20971520);    // 4.2 MB
    unsigned short* attno= (unsigned short*)(ws + 25165824);    // 4.2 MB
    float* hb    = (float*)(ws + 29360128);                     // 8.4 MB
    float* hnb   = (float*)(ws + 37748736);                     // 8.4 MB
    float* oute  = (float*)(ws + 46137344);                     // 8.4 MB
    unsigned short* tok = (unsigned short*)(ws + 54525952);     // 4.2 MB
    float* ropec = (float*)(ws + 58720256);
    float* ropes = (float*)(ws + 58851328);
    float* wfull = (float*)(ws + 58982400);
    int*   slot  = (int*)(ws + 59047936);
    float* sw    = (float*)(ws + 59113472);
    int*   sidx  = (int*)(ws + 59121664);
    float* gsum  = (float*)(ws + 59129856);

    rope_table_kernel<<<S_LEN, 32, 0, stream>>>(ropec, ropes, gsum);
    rmsnorm_kernel<1><<<T_TOK, 256, 0, stream>>>(x, g1, xn);

    // fused QKV GEMM + RoPE + hi/lo split + V transpose
    gemm_qkv_rope<<<dim3(48, 16, 1), 256, 0, stream>>>(
        xn, Wq, Wk, Wv, ropec, ropes, Qh, Ql, Kh, Kl, Vtb);

    attn_mfma_kernel<<<dim3(16, 16, 2), 256, 0, stream>>>(Qh, Ql, Kh, Kl, Vtb, gtm, attno);

    // h = x + attno @ Wo  (f32 Wo read directly)
    gemm_bf32<1><<<dim3(32, 16, 1), 256, 0, stream>>>(
        attno, Wo, x, hb, 1024, 1024, 0, 0, 0);
    rmsnorm_kernel<0><<<T_TOK, 256, 0, stream>>>(hb, g2, hnb);

    gate_kernel<<<T_TOK / 4, 256, 0, stream>>>(hnb, Wgate, wfull, slot, gsum);
    expert_select_kernel<<<NE, 1024, 0, stream>>>(wfull, sw, sidx, slot);
    gather_tok_kernel<<<NE * CAP, 256, 0, stream>>>(hnb, sidx, sw, tok);

    gemm_w1_fused<<<dim3(128, 8, 1), 256, 0, stream>>>(tok, W1, act);
    gemm_bf32<0><<<dim3(32, 2, 8), 256, 0, stream>>>(
        act, W2, nullptr, oute, 4096, 4096,
        (long long)CAP * DFF, (long long)DFF * 1024, (long long)CAP * 1024);

    combine_kernel<<<T_TOK, 256, 0, stream>>>(hb, oute, slot, wfull, gsum, out);
}

// Round 11
// 353.545 us; speedup vs baseline: 6.3791x; 1.0075x over previous
//
#include <hip/hip_runtime.h>
#include <hip/hip_bf16.h>
#include <math.h>

#define T_TOK 2048
#define DMODEL 1024
#define NH 16
#define HD 64
#define S_LEN 1024
#define NE 8
#define CAP 256
#define DFF 4096

typedef __attribute__((ext_vector_type(8))) short bf16x8;
typedef __attribute__((ext_vector_type(4))) float f32x4;

__device__ inline unsigned short f2bf(float f) {
    union { float f; unsigned int u; } x; x.f = f;
    unsigned int u = x.u;
    unsigned int r = (u + 0x7FFFu + ((u >> 16) & 1u)) >> 16;
    return (unsigned short)r;
}

__device__ inline float bf2f(unsigned short h) {
    union { unsigned int u; float f; } x; x.u = (unsigned int)h << 16; return x.f;
}

// packed f32x2 -> bf16x2 (RTNE); lo in low 16 bits
__device__ inline unsigned int pkbf(float lo, float hi) {
    __hip_bfloat162 h2 = __float22bfloat162_rn(make_float2(lo, hi));
    unsigned int r;
    __builtin_memcpy(&r, &h2, 4);
    return r;
}

__device__ inline void gload16(const void* g, void* l) {
    __builtin_amdgcn_global_load_lds(
        (const __attribute__((address_space(1))) unsigned int*)g,
        (__attribute__((address_space(3))) unsigned int*)l, 16, 0, 0);
}

// ---------------- RoPE table (+ gsum zero) ----------------
__global__ void rope_table_kernel(float* __restrict__ rc, float* __restrict__ rs,
                                  float* __restrict__ gsum) {
    int s = blockIdx.x;
    int i = threadIdx.x;
    float invf = powf(10000.0f, -(float)(2 * i) / 64.0f);
    float ang = (float)s * invf;
    rc[s * 32 + i] = cosf(ang);
    rs[s * 32 + i] = sinf(ang);
    if (blockIdx.x == 0 && threadIdx.x < 8) gsum[threadIdx.x] = 0.f;
}

// ---------------- RMSNorm (OUTBF: 1 -> bf16 out, 0 -> f32 out) ----------------
template <int OUTBF>
__global__ __launch_bounds__(256) void rmsnorm_kernel(const float* __restrict__ x,
                                                      const float* __restrict__ g,
                                                      void* __restrict__ yv) {
    __shared__ float red[256];
    int t = blockIdx.x;
    int tid = threadIdx.x;
    const float* xr = x + (size_t)t * DMODEL;
    float ss = 0.f;
    for (int d = tid; d < DMODEL; d += 256) { float v = xr[d]; ss += v * v; }
    red[tid] = ss; __syncthreads();
    for (int o = 128; o > 0; o >>= 1) { if (tid < o) red[tid] += red[tid + o]; __syncthreads(); }
    float scale = 1.0f / sqrtf(red[0] / (float)DMODEL + 1e-6f);
    if (OUTBF) {
        unsigned short* yr = (unsigned short*)yv + (size_t)t * DMODEL;
        for (int d = tid; d < DMODEL; d += 256) yr[d] = f2bf(g[d] * xr[d] * scale);
    } else {
        float* yr = (float*)yv + (size_t)t * DMODEL;
        for (int d = tid; d < DMODEL; d += 256) yr[d] = g[d] * xr[d] * scale;
    }
}

// ---------------- fused QKV GEMM + RoPE + hi/lo + V-transpose (B reg-prefetch) ----------------
__global__ __launch_bounds__(256) void gemm_qkv_rope(const unsigned short* __restrict__ xn,
                                                     const float* __restrict__ Wq,
                                                     const float* __restrict__ Wk,
                                                     const float* __restrict__ Wv,
                                                     const float* __restrict__ rc,
                                                     const float* __restrict__ rs,
                                                     unsigned short* __restrict__ Qh,
                                                     unsigned short* __restrict__ Ql,
                                                     unsigned short* __restrict__ Kh,
                                                     unsigned short* __restrict__ Kl,
                                                     unsigned short* __restrict__ Vtb) {
    __shared__ unsigned short As[128 * 64];   // 16 KB
    __shared__ unsigned int Bp[64 * 32];      // 8 KB
    const int mat = blockIdx.x >> 4;
    const int h = blockIdx.x & 15;
    const float* B = ((mat == 0) ? Wq : (mat == 1) ? Wk : Wv) + h * 64;
    const int by = blockIdx.y * 128;
    const int tid = threadIdx.x, l = tid & 63, wid = tid >> 6;
    const int g = l >> 4;
    const int kp = tid >> 3;
    const int nc = tid & 7;
    const int chunk = kp >> 2, within = kp & 3;

    f32x4 acc[2][4] = {};

    const float* Brow = B + (size_t)(2 * kp) * 1024 + nc * 8;
    float4 a0 = *(const float4*)(Brow);
    float4 a1 = *(const float4*)(Brow + 4);
    float4 b0 = *(const float4*)(Brow + 1024);
    float4 b1 = *(const float4*)(Brow + 1028);

    for (int k0 = 0; k0 < 1024; k0 += 64) {
        #pragma unroll
        for (int i = 0; i < 4; i++) {
            int c = i * 256 + tid;
            int row = c >> 3, sl = c & 7, gs = sl ^ (row & 7);
            gload16(xn + (size_t)(by + row) * 1024 + k0 + gs * 8, &As[c * 8]);
        }
        unsigned int p[8];
        p[0] = pkbf(a0.x, b0.x); p[1] = pkbf(a0.y, b0.y);
        p[2] = pkbf(a0.z, b0.z); p[3] = pkbf(a0.w, b0.w);
        p[4] = pkbf(a1.x, b1.x); p[5] = pkbf(a1.y, b1.y);
        p[6] = pkbf(a1.z, b1.z); p[7] = pkbf(a1.w, b1.w);
        #pragma unroll
        for (int i = 0; i < 8; i++) {
            int n_loc = nc * 8 + i;
            int idx = n_loc * 32 + ((chunk ^ (n_loc & 7)) << 2) + within;
            Bp[idx] = p[i];
        }
        __syncthreads();
        if (k0 + 64 < 1024) {
            const float* Bn = B + (size_t)(k0 + 64 + 2 * kp) * 1024 + nc * 8;
            a0 = *(const float4*)(Bn);
            a1 = *(const float4*)(Bn + 4);
            b0 = *(const float4*)(Bn + 1024);
            b1 = *(const float4*)(Bn + 1028);
        }
        #pragma unroll
        for (int ks = 0; ks < 2; ks++) {
            bf16x8 af[2];
            #pragma unroll
            for (int m = 0; m < 2; m++) {
                int row = wid * 32 + m * 16 + (l & 15);
                int sl = (ks * 4 + g) ^ (row & 7);
                af[m] = *(const bf16x8*)&As[row * 64 + sl * 8];
            }
            #pragma unroll
            for (int nf = 0; nf < 4; nf++) {
                int n_loc = nf * 16 + (l & 15);
                int base = n_loc * 32 + (((ks * 4 + g) ^ (n_loc & 7)) << 2);
                bf16x8 bfr = *(const bf16x8*)&Bp[base];
                #pragma unroll
                for (int m = 0; m < 2; m++)
                    acc[m][nf] = __builtin_amdgcn_mfma_f32_16x16x32_bf16(af[m], bfr, acc[m][nf], 0, 0, 0);
            }
        }
        __syncthreads();
    }

    if (mat < 2) {
        unsigned short* Dh = (mat == 0) ? Qh : Kh;
        unsigned short* Dl = (mat == 0) ? Ql : Kl;
        float scale = (mat == 0) ? 0.125f : 1.0f;
        #pragma unroll
        for (int m = 0; m < 2; m++)
            #pragma unroll
            for (int r = 0; r < 4; r++) {
                int t = by + wid * 32 + m * 16 + g * 4 + r;
                int b = t >> 10, s = t & 1023;
                size_t ob = ((size_t)(b * 16 + h) * 1024 + s) * 64;
                #pragma unroll
                for (int pr = 0; pr < 2; pr++) {
                    int i = pr * 16 + (l & 15);
                    float c = rc[s * 32 + i], sn = rs[s * 32 + i];
                    float a = acc[m][pr][r], bb = acc[m][pr + 2][r];
                    float v0 = (a * c - bb * sn) * scale;
                    float v1 = (bb * c + a * sn) * scale;
                    unsigned short h0 = f2bf(v0), h1 = f2bf(v1);
                    Dh[ob + i] = h0;      Dl[ob + i] = f2bf(v0 - bf2f(h0));
                    Dh[ob + i + 32] = h1; Dl[ob + i + 32] = f2bf(v1 - bf2f(h1));
                }
            }
    } else {
        #pragma unroll
        for (int m = 0; m < 2; m++) {
            int t0 = by + wid * 32 + m * 16 + g * 4;
            int b = t0 >> 10, s0 = t0 & 1023;
            #pragma unroll
            for (int nf = 0; nf < 4; nf++) {
                int d = nf * 16 + (l & 15);
                unsigned short tmp[4];
                #pragma unroll
                for (int r = 0; r < 4; r++) tmp[r] = f2bf(acc[m][nf][r]);
                *(uint2*)&Vtb[((size_t)(b * 16 + h) * 64 + d) * 1024 + s0] = *(uint2*)tmp;
            }
        }
    }
}

// ---------------- generic fused GEMM: C(f32) = A(bf16) @ B(f32), B reg-prefetch ----------------
template <int RES>
__global__ __launch_bounds__(256) void gemm_bf32(const unsigned short* __restrict__ A,
                                                 const float* __restrict__ B,
                                                 const float* __restrict__ Rr,
                                                 float* __restrict__ C,
                                                 int K, int lda,
                                                 long long sA, long long sB, long long sC) {
    __shared__ unsigned short As[128 * 64];   // 16 KB
    __shared__ unsigned int Bp[32 * 32];      // 4 KB
    A += (long long)blockIdx.z * sA + (long long)blockIdx.y * 128 * lda;
    B += (long long)blockIdx.z * sB;
    C += (long long)blockIdx.z * sC + (long long)blockIdx.y * 128 * 1024;
    const float* Rp = RES ? (Rr + (long long)blockIdx.y * 128 * 1024) : nullptr;
    const int bx = blockIdx.x * 32;
    const int tid = threadIdx.x, l = tid & 63, wid = tid >> 6;
    const int g = l >> 4;
    const int kp = tid >> 3;
    const int nc = tid & 7;
    const int chunk = kp >> 2, within = kp & 3;

    f32x4 acc[2][2] = {};

    const float* Brow = B + (size_t)(2 * kp) * 1024 + bx + nc * 4;
    float4 a0 = *(const float4*)(Brow);
    float4 a1 = *(const float4*)(Brow + 1024);

    for (int k0 = 0; k0 < K; k0 += 64) {
        #pragma unroll
        for (int i = 0; i < 4; i++) {
            int c = i * 256 + tid;
            int row = c >> 3, sl = c & 7, gs = sl ^ (row & 7);
            gload16(A + (size_t)row * lda + k0 + gs * 8, &As[c * 8]);
        }
        unsigned int p1[4];
        p1[0] = pkbf(a0.x, a1.x); p1[1] = pkbf(a0.y, a1.y);
        p1[2] = pkbf(a0.z, a1.z); p1[3] = pkbf(a0.w, a1.w);
        #pragma unroll
        for (int i = 0; i < 4; i++) {
            int n_loc = nc * 4 + i;
            int idx = n_loc * 32 + ((chunk ^ (n_loc & 7)) << 2) + within;
            Bp[idx] = p1[i];
        }
        __syncthreads();
        if (k0 + 64 < K) {
            const float* Bn = B + (size_t)(k0 + 64 + 2 * kp) * 1024 + bx + nc * 4;
            a0 = *(const float4*)(Bn);
            a1 = *(const float4*)(Bn + 1024);
        }
        #pragma unroll
        for (int ks = 0; ks < 2; ks++) {
            bf16x8 af[2];
            #pragma unroll
            for (int m = 0; m < 2; m++) {
                int row = wid * 32 + m * 16 + (l & 15);
                int sl = (ks * 4 + g) ^ (row & 7);
                af[m] = *(const bf16x8*)&As[row * 64 + sl * 8];
            }
            #pragma unroll
            for (int nf = 0; nf < 2; nf++) {
                int n_loc = nf * 16 + (l & 15);
                int base = n_loc * 32 + (((ks * 4 + g) ^ (n_loc & 7)) << 2);
                bf16x8 bfr = *(const bf16x8*)&Bp[base];
                #pragma unroll
                for (int m = 0; m < 2; m++)
                    acc[m][nf] = __builtin_amdgcn_mfma_f32_16x16x32_bf16(af[m], bfr, acc[m][nf], 0, 0, 0);
            }
        }
        __syncthreads();
    }
    #pragma unroll
    for (int m = 0; m < 2; m++) {
        int row0 = wid * 32 + m * 16 + g * 4;
        #pragma unroll
        for (int nf = 0; nf < 2; nf++) {
            int col = bx + nf * 16 + (l & 15);
            #pragma unroll
            for (int r = 0; r < 4; r++) {
                size_t idx = (size_t)(row0 + r) * 1024 + col;
                float v = acc[m][nf][r];
                if (RES) v += Rp[idx];
                C[idx] = v;
            }
        }
    }
}

// ---------------- fused MoE W1 GEMM + SwiGLU (B reg-prefetch) ----------------
__global__ __launch_bounds__(256) void gemm_w1_fused(const unsigned short* __restrict__ tok,
                                                     const float* __restrict__ W1,
                                                     unsigned short* __restrict__ act) {
    __shared__ unsigned short As[256 * 64];   // 32 KB
    __shared__ unsigned int B1p[32 * 32];     // 4 KB
    __shared__ unsigned int B2p[32 * 32];     // 4 KB
    const int e = blockIdx.y;
    const int bx = blockIdx.x * 32;
    const unsigned short* A = tok + (size_t)e * CAP * DMODEL;
    const float* B = W1 + (size_t)e * DMODEL * (2 * DFF);
    unsigned short* C = act + (size_t)e * CAP * DFF;
    const int tid = threadIdx.x, l = tid & 63, wid = tid >> 6;
    const int g = l >> 4;
    const int kp = tid >> 3;
    const int nc = tid & 7;
    const int chunk = kp >> 2, within = kp & 3;

    f32x4 acc1[4][2] = {};
    f32x4 acc2[4][2] = {};

    const float* Brow = B + (size_t)(2 * kp) * 8192 + bx + nc * 4;
    float4 a0 = *(const float4*)(Brow);
    float4 a1 = *(const float4*)(Brow + 8192);
    float4 c0 = *(const float4*)(Brow + 4096);
    float4 c1 = *(const float4*)(Brow + 4096 + 8192);

    for (int k0 = 0; k0 < DMODEL; k0 += 64) {
        #pragma unroll
        for (int i = 0; i < 8; i++) {
            int c = i * 256 + tid;
            int row = c >> 3, sl = c & 7, gs = sl ^ (row & 7);
            gload16(A + (size_t)row * DMODEL + k0 + gs * 8, &As[c * 8]);
        }
        unsigned int p1[4], p2[4];
        p1[0] = pkbf(a0.x, a1.x); p1[1] = pkbf(a0.y, a1.y);
        p1[2] = pkbf(a0.z, a1.z); p1[3] = pkbf(a0.w, a1.w);
        p2[0] = pkbf(c0.x, c1.x); p2[1] = pkbf(c0.y, c1.y);
        p2[2] = pkbf(c0.z, c1.z); p2[3] = pkbf(c0.w, c1.w);
        #pragma unroll
        for (int i = 0; i < 4; i++) {
            int n_loc = nc * 4 + i;
            int idx = n_loc * 32 + ((chunk ^ (n_loc & 7)) << 2) + within;
            B1p[idx] = p1[i];
            B2p[idx] = p2[i];
        }
        __syncthreads();
        if (k0 + 64 < DMODEL) {
            const float* Bn = B + (size_t)(k0 + 64 + 2 * kp) * 8192 + bx + nc * 4;
            a0 = *(const float4*)(Bn);
            a1 = *(const float4*)(Bn + 8192);
            c0 = *(const float4*)(Bn + 4096);
            c1 = *(const float4*)(Bn + 4096 + 8192);
        }
        #pragma unroll
        for (int ks = 0; ks < 2; ks++) {
            bf16x8 af[4];
            #pragma unroll
            for (int m = 0; m < 4; m++) {
                int row = wid * 64 + m * 16 + (l & 15);
                int sl = (ks * 4 + g) ^ (row & 7);
                af[m] = *(const bf16x8*)&As[row * 64 + sl * 8];
            }
            #pragma unroll
            for (int nf = 0; nf < 2; nf++) {
                int n_loc = nf * 16 + (l & 15);
                int base = n_loc * 32 + (((ks * 4 + g) ^ (n_loc & 7)) << 2);
                bf16x8 b1 = *(const bf16x8*)&B1p[base];
                bf16x8 b2 = *(const bf16x8*)&B2p[base];
                #pragma unroll
                for (int m = 0; m < 4; m++) {
                    acc1[m][nf] = __builtin_amdgcn_mfma_f32_16x16x32_bf16(af[m], b1, acc1[m][nf], 0, 0, 0);
                    acc2[m][nf] = __builtin_amdgcn_mfma_f32_16x16x32_bf16(af[m], b2, acc2[m][nf], 0, 0, 0);
                }
            }
        }
        __syncthreads();
    }
    #pragma unroll
    for (int m = 0; m < 4; m++) {
        int row0 = wid * 64 + m * 16 + g * 4;
        #pragma unroll
        for (int nf = 0; nf < 2; nf++) {
            int col = bx + nf * 16 + (l & 15);
            #pragma unroll
            for (int r = 0; r < 4; r++) {
                float h1 = acc1[m][nf][r], h2 = acc2[m][nf][r];
                float sil = h2 / (1.0f + __expf(-h2));
                C[(size_t)(row0 + r) * DFF + col] = f2bf(h1 * sil);
            }
        }
    }
}

// ---------------- flash-style MFMA attention, double-buffered K/V + setprio ----------------
__global__ __launch_bounds__(256) void attn_mfma_kernel(const unsigned short* __restrict__ Qh,
                                                        const unsigned short* __restrict__ Ql,
                                                        const unsigned short* __restrict__ Kh,
                                                        const unsigned short* __restrict__ Kl,
                                                        const unsigned short* __restrict__ Vtb,
                                                        const int* __restrict__ gtm,
                                                        unsigned short* __restrict__ o) {
    __shared__ unsigned short Ksh[2][64 * 64];
    __shared__ unsigned short Ksl[2][64 * 64];
    __shared__ unsigned short Vs[2][64 * 64];
    __shared__ unsigned short Pl[4][16 * 64];
    const int qt = blockIdx.x, h = blockIdx.y, b = blockIdx.z;
    const int bh = b * 16 + h;
    const int tid = threadIdx.x, l = tid & 63, w = tid >> 6;
    const int q0 = qt * 64 + w * 16;
    const unsigned short* Qhb = Qh + (size_t)bh * 1024 * 64;
    const unsigned short* Qlb = Ql + (size_t)bh * 1024 * 64;
    const unsigned short* Khb = Kh + (size_t)bh * 1024 * 64;
    const unsigned short* Klb = Kl + (size_t)bh * 1024 * 64;
    const unsigned short* Vbh = Vtb + (size_t)bh * 64 * 1024;
    const int* gb = gtm + b * 1024;

    bf16x8 afh[2], afl[2];
    #pragma unroll
    for (int ks = 0; ks < 2; ks++) {
        size_t off = (size_t)(q0 + (l & 15)) * 64 + ks * 32 + (l >> 4) * 8;
        afh[ks] = *(const bf16x8*)(Qhb + off);
        afl[ks] = *(const bf16x8*)(Qlb + off);
    }

    int gqm = 0;
    #pragma unroll
    for (int r = 0; r < 4; r++)
        gqm |= (gb[q0 + (l >> 4) * 4 + r] ? 1 : 0) << r;

    f32x4 acc_o[4] = {};
    float m_run[4], l_run[4];
    #pragma unroll
    for (int r = 0; r < 4; r++) { m_run[r] = -1e30f; l_run[r] = 0.f; }

    // prologue: issue tile 0 into buffer 0
    {
        #pragma unroll
        for (int i = 0; i < 2; i++) {
            int c = i * 256 + tid, row = c >> 3, sl = c & 7, gs = sl ^ (row & 7);
            gload16(Khb + (size_t)row * 64 + gs * 8, &Ksh[0][c * 8]);
            gload16(Klb + (size_t)row * 64 + gs * 8, &Ksl[0][c * 8]);
            gload16(Vbh + (size_t)row * 1024 + gs * 8, &Vs[0][c * 8]);
        }
    }
    int cur = 0;

    for (int jt = 0; jt < 16; jt++) {
        const int j0 = jt * 64;
        __syncthreads();   // drains vmcnt: buf[cur] ready; prior reads of buf[cur^1] done

        if (jt < 15) {
            const int jn = j0 + 64;
            int nb = cur ^ 1;
            #pragma unroll
            for (int i = 0; i < 2; i++) {
                int c = i * 256 + tid, row = c >> 3, sl = c & 7, gs = sl ^ (row & 7);
                gload16(Khb + (size_t)(jn + row) * 64 + gs * 8, &Ksh[nb][c * 8]);
                gload16(Klb + (size_t)(jn + row) * 64 + gs * 8, &Ksl[nb][c * 8]);
                gload16(Vbh + (size_t)row * 1024 + jn + gs * 8, &Vs[nb][c * 8]);
            }
        }

        f32x4 sv[4] = {};
        __builtin_amdgcn_s_setprio(1);
        #pragma unroll
        for (int n = 0; n < 4; n++) {
            #pragma unroll
            for (int ks = 0; ks < 2; ks++) {
                int row = n * 16 + (l & 15);
                int sl = (ks * 4 + (l >> 4)) ^ (row & 7);
                bf16x8 khf = *(const bf16x8*)&Ksh[cur][row * 64 + sl * 8];
                bf16x8 klf = *(const bf16x8*)&Ksl[cur][row * 64 + sl * 8];
                sv[n] = __builtin_amdgcn_mfma_f32_16x16x32_bf16(afl[ks], khf, sv[n], 0, 0, 0);
                sv[n] = __builtin_amdgcn_mfma_f32_16x16x32_bf16(afh[ks], klf, sv[n], 0, 0, 0);
                sv[n] = __builtin_amdgcn_mfma_f32_16x16x32_bf16(afh[ks], khf, sv[n], 0, 0, 0);
            }
        }
        __builtin_amdgcn_s_setprio(0);

        int gk[4];
        #pragma unroll
        for (int n = 0; n < 4; n++) gk[n] = gb[j0 + n * 16 + (l & 15)];

        #pragma unroll
        for (int n = 0; n < 4; n++)
            #pragma unroll
            for (int r = 0; r < 4; r++) {
                int q = q0 + (l >> 4) * 4 + r;
                int k = j0 + n * 16 + (l & 15);
                bool allowed = ((gqm >> r) & 1) || gk[n] || ((k <= q) && (q - k < 256));
                if (!allowed) sv[n][r] = -1e30f;
            }

        {
            float tm[4], corr[4], rsum[4];
            #pragma unroll
            for (int r = 0; r < 4; r++)
                tm[r] = fmaxf(fmaxf(sv[0][r], sv[1][r]), fmaxf(sv[2][r], sv[3][r]));
            #pragma unroll
            for (int wd = 1; wd <= 8; wd <<= 1)
                #pragma unroll
                for (int r = 0; r < 4; r++) tm[r] = fmaxf(tm[r], __shfl_xor(tm[r], wd, 64));
            #pragma unroll
            for (int r = 0; r < 4; r++) {
                float mn = fmaxf(m_run[r], tm[r]);
                corr[r] = __expf(m_run[r] - mn);
                m_run[r] = mn;
                rsum[r] = 0.f;
            }
            #pragma unroll
            for (int n = 0; n < 4; n++)
                #pragma unroll
                for (int r = 0; r < 4; r++) {
                    float p = __expf(sv[n][r] - m_run[r]);
                    sv[n][r] = p;
                    rsum[r] += p;
                }
            #pragma unroll
            for (int wd = 1; wd <= 8; wd <<= 1)
                #pragma unroll
                for (int r = 0; r < 4; r++) rsum[r] += __shfl_xor(rsum[r], wd, 64);
            #pragma unroll
            for (int r = 0; r < 4; r++) l_run[r] = l_run[r] * corr[r] + rsum[r];
            #pragma unroll
            for (int nd = 0; nd < 4; nd++)
                #pragma unroll
                for (int r = 0; r < 4; r++) acc_o[nd][r] *= corr[r];
            #pragma unroll
            for (int n = 0; n < 4; n++)
                #pragma unroll
                for (int r = 0; r < 4; r++) {
                    int qr = (l >> 4) * 4 + r;
                    int kc = n * 16 + (l & 15);
                    int byte = (qr * 128 + kc * 2) ^ ((qr & 7) << 4);
                    Pl[w][byte >> 1] = f2bf(sv[n][r]);
                }
        }

        asm volatile("s_waitcnt lgkmcnt(0)" ::: "memory");
        __builtin_amdgcn_sched_barrier(0);

        __builtin_amdgcn_s_setprio(1);
        #pragma unroll
        for (int ks = 0; ks < 2; ks++) {
            int prow = l & 15;
            int psl = (ks * 4 + (l >> 4)) ^ (prow & 7);
            bf16x8 pa = *(const bf16x8*)&Pl[w][prow * 64 + psl * 8];
            #pragma unroll
            for (int nd = 0; nd < 4; nd++) {
                int row = nd * 16 + (l & 15);
                int sl = (ks * 4 + (l >> 4)) ^ (row & 7);
                bf16x8 vf = *(const bf16x8*)&Vs[cur][row * 64 + sl * 8];
                acc_o[nd] = __builtin_amdgcn_mfma_f32_16x16x32_bf16(pa, vf, acc_o[nd], 0, 0, 0);
            }
        }
        __builtin_amdgcn_s_setprio(0);
        cur ^= 1;
    }

    #pragma unroll
    for (int r = 0; r < 4; r++) {
        float inv = 1.0f / l_run[r];
        int t_ = b * 1024 + q0 + (l >> 4) * 4 + r;
        #pragma unroll
        for (int nd = 0; nd < 4; nd++) {
            int col = h * 64 + nd * 16 + (l & 15);
            o[(size_t)t_ * 1024 + col] = f2bf(acc_o[nd][r] * inv);
        }
    }
}

// ---------------- gate: one wave per token; writes all 8 wfull + slot=-1 ----------------
__global__ __launch_bounds__(256) void gate_kernel(const float* __restrict__ hn,
                                                   const float* __restrict__ Wgate,
                                                   float* __restrict__ wfull,
                                                   int* __restrict__ slot,
                                                   float* __restrict__ gate_sum) {
    int tid = threadIdx.x;
    int w = tid >> 6, l = tid & 63;
    int t = blockIdx.x * 4 + w;
    int e = l & 7, g = l >> 3;
    const float* xr = hn + (size_t)t * DMODEL;
    const float* wp = Wgate + l;
    float acc = 0.f;
    #pragma unroll 8
    for (int kk = 0; kk < 128; kk++)
        acc += xr[g + 8 * kk] * wp[64 * kk];
    #pragma unroll
    for (int o = 8; o < 64; o <<= 1) acc += __shfl_xor(acc, o, 64);
    float m = acc;
    #pragma unroll
    for (int o = 1; o < 8; o <<= 1) m = fmaxf(m, __shfl_xor(m, o, 64));
    float p = __expf(acc - m);
    float s = p;
    #pragma unroll
    for (int o = 1; o < 8; o <<= 1) s += __shfl_xor(s, o, 64);
    float pr = p / s;
    unsigned long long key = ((unsigned long long)__float_as_uint(pr) << 32) | (unsigned)(7 - e);
    unsigned long long k1 = key;
    #pragma unroll
    for (int o = 1; o < 8; o <<= 1) { unsigned long long t2 = __shfl_xor(k1, o, 64); if (t2 > k1) k1 = t2; }
    int e1 = 7 - (int)(k1 & 7);
    unsigned long long key2 = (e == e1) ? 0ull : key;
    unsigned long long k2 = key2;
    #pragma unroll
    for (int o = 1; o < 8; o <<= 1) { unsigned long long t2 = __shfl_xor(k2, o, 64); if (t2 > k2) k2 = t2; }
    int e2 = 7 - (int)(k2 & 7);
    if (l < 8) {
        wfull[t * 8 + e] = (e == e1 || e == e2) ? pr : 0.f;
        slot[t * 8 + e] = -1;
        atomicAdd(&gate_sum[e], pr);
    }
}

// ---------------- per-expert top-CAP via bitonic sort ----------------
__global__ __launch_bounds__(1024) void expert_select_kernel(const float* __restrict__ wfull,
                                                             float* __restrict__ sw,
                                                             int* __restrict__ sidx,
                                                             int* __restrict__ slot) {
    __shared__ unsigned long long keys[2048];
    int e = blockIdx.x;
    int t = threadIdx.x;
    for (int i = t; i < 2048; i += 1024) {
        float w = wfull[i * 8 + e];
        unsigned int wb = __float_as_uint(w);
        keys[i] = ((unsigned long long)wb << 32) | (unsigned long long)(0xFFFFFFFFu - (unsigned int)i);
    }
    __syncthreads();
    for (int k = 2; k <= 2048; k <<= 1) {
        for (int j = k >> 1; j > 0; j >>= 1) {
            for (int i = t; i < 2048; i += 1024) {
                int ixj = i ^ j;
                if (ixj > i) {
                    bool desc = ((i & k) == 0);
                    unsigned long long a = keys[i], b = keys[ixj];
                    if ((a < b) == desc) { keys[i] = b; keys[ixj] = a; }
                }
            }
            __syncthreads();
        }
    }
    if (t < CAP) {
        unsigned long long kk = keys[t];
        float w = __uint_as_float((unsigned int)(kk >> 32));
        int idx = (int)(0xFFFFFFFFu - (unsigned int)(kk & 0xFFFFFFFFu));
        sw[e * CAP + t] = w;
        sidx[e * CAP + t] = idx;
        if (w > 0.f) slot[idx * 8 + e] = t;
    }
}

// ---------------- gather tokens -> bf16 ----------------
__global__ __launch_bounds__(256) void gather_tok_kernel(const float* __restrict__ hn,
                                                         const int* __restrict__ sidx,
                                                         const float* __restrict__ sw,
                                                         unsigned short* __restrict__ tok) {
    int ec = blockIdx.x;
    int tid = threadIdx.x;
    float w = sw[ec];
    int src = sidx[ec];
    const float* s = hn + (size_t)src * DMODEL;
    unsigned short* d = tok + (size_t)ec * DMODEL;
    for (int i = tid; i < DMODEL; i += 256) d[i] = (w > 0.f) ? f2bf(s[i]) : 0;
}

// ---------------- final combine ----------------
__global__ __launch_bounds__(256) void combine_kernel(const float* __restrict__ h,
                                                      const float* __restrict__ out_e,
                                                      const int* __restrict__ slot,
                                                      const float* __restrict__ wfull,
                                                      const float* __restrict__ gate_sum,
                                                      float* __restrict__ out) {
    int t = blockIdx.x;
    int tid = threadIdx.x;
    for (int d = tid; d < DMODEL; d += 256) {
        float acc = h[(size_t)t * DMODEL + d];
        #pragma unroll
        for (int e = 0; e < 8; e++) {
            int c = slot[t * 8 + e];
            if (c >= 0) acc += wfull[t * 8 + e] * out_e[((size_t)(e * CAP + c)) * DMODEL + d];
        }
        out[(size_t)t * DMODEL + d] = acc;
    }
    if (t == 0 && tid == 0) {
        float a = 0.f;
        #pragma unroll
        for (int e = 0; e < 8; e++) { float m = gate_sum[e] / (float)T_TOK; a += m * m; }
        out[(size_t)T_TOK * DMODEL] = 8.0f * a;
    }
}

extern "C" void kernel_launch(void* const* d_in, const int* in_sizes, int n_in,
                              void* d_out, int out_size, void* d_ws, size_t ws_size,
                              hipStream_t stream) {
    const float* x     = (const float*)d_in[0];
    const int*   gtm   = (const int*)d_in[2];
    const float* Wq    = (const float*)d_in[3];
    const float* Wk    = (const float*)d_in[4];
    const float* Wv    = (const float*)d_in[5];
    const float* Wo    = (const float*)d_in[6];
    const float* g1    = (const float*)d_in[7];
    const float* g2    = (const float*)d_in[8];
    const float* Wgate = (const float*)d_in[9];
    const float* W1    = (const float*)d_in[10];
    const float* W2    = (const float*)d_in[11];
    float* out = (float*)d_out;

    char* ws = (char*)d_ws;
    unsigned short* Qh   = (unsigned short*)(ws + 0);           // 4 MB
    unsigned short* Ql   = (unsigned short*)(ws + 4194304);
    unsigned short* Kh   = (unsigned short*)(ws + 8388608);
    unsigned short* Kl   = (unsigned short*)(ws + 12582912);
    unsigned short* Vtb  = (unsigned short*)(ws + 16777216);    // ends 20971520
    unsigned short* act  = (unsigned short*)(ws + 0);           // 16.8 MB (MoE phase; Q/K dead)
    unsigned short* xn   = (unsigned short*)(ws + 20971520);    // 4.2 MB
    unsigned short* attno= (unsigned short*)(ws + 25165824);    // 4.2 MB
    float* hb    = (float*)(ws + 29360128);                     // 8.4 MB
    float* hnb   = (float*)(ws + 37748736);                     // 8.4 MB
    float* oute  = (float*)(ws + 46137344);                     // 8.4 MB
    unsigned short* tok = (unsigned short*)(ws + 54525952);     // 4.2 MB
    float* ropec = (float*)(ws + 58720256);
    float* ropes = (float*)(ws + 58851328);
    float* wfull = (float*)(ws + 58982400);
    int*   slot  = (int*)(ws + 59047936);
    float* sw    = (float*)(ws + 59113472);
    int*   sidx  = (int*)(ws + 59121664);
    float* gsum  = (float*)(ws + 59129856);

    rope_table_kernel<<<S_LEN, 32, 0, stream>>>(ropec, ropes, gsum);
    rmsnorm_kernel<1><<<T_TOK, 256, 0, stream>>>(x, g1, xn);

    gemm_qkv_rope<<<dim3(48, 16, 1), 256, 0, stream>>>(
        xn, Wq, Wk, Wv, ropec, ropes, Qh, Ql, Kh, Kl, Vtb);

    attn_mfma_kernel<<<dim3(16, 16, 2), 256, 0, stream>>>(Qh, Ql, Kh, Kl, Vtb, gtm, attno);

    // h = x + attno @ Wo  (f32 Wo read directly)
    gemm_bf32<1><<<dim3(32, 16, 1), 256, 0, stream>>>(
        attno, Wo, x, hb, 1024, 1024, 0, 0, 0);
    rmsnorm_kernel<0><<<T_TOK, 256, 0, stream>>>(hb, g2, hnb);

    gate_kernel<<<T_TOK / 4, 256, 0, stream>>>(hnb, Wgate, wfull, slot, gsum);
    expert_select_kernel<<<NE, 1024, 0, stream>>>(wfull, sw, sidx, slot);
    gather_tok_kernel<<<NE * CAP, 256, 0, stream>>>(hnb, sidx, sw, tok);

    gemm_w1_fused<<<dim3(128, 8, 1), 256, 0, stream>>>(tok, W1, act);
    gemm_bf32<0><<<dim3(32, 2, 8), 256, 0, stream>>>(
        act, W2, nullptr, oute, 4096, 4096,
        (long long)CAP * DFF, (long long)DFF * 1024, (long long)CAP * 1024);

    combine_kernel<<<T_TOK, 256, 0, stream>>>(hb, oute, slot, wfull, gsum, out);
}